// Round 3
// baseline (740.641 us; speedup 1.0000x reference)
//
#include <hip/hip_runtime.h>

#define EPS 1e-5f

__device__ __forceinline__ float leakyf(float z){ return z >= 0.f ? z : 0.2f*z; }

// ---------------- zero scratch ----------------
__global__ __launch_bounds__(256) void k_zero(float* __restrict__ p, int n){
  int i = blockIdx.x*256 + threadIdx.x;
  if (i < n) p[i] = 0.f;
}

// ---------------- generic NT GEMM: C[m,n] = sum_k A[m,k]*B[n,k] (all f32) ----------------
__global__ __launch_bounds__(256) void k_gemm_nt(
    const float* __restrict__ A, int lda,
    const float* __restrict__ B0, const float* __restrict__ B1, const float* __restrict__ B2,
    int ldb, float* __restrict__ C, int ldc, long cStr, int K)
{
  __shared__ float As[8][128];
  __shared__ float Bs[8][128];
  const int z = blockIdx.z;
  const float* Bb = (z==0 ? B0 : (z==1 ? B1 : B2));
  float* Cb = C + (long)z*cStr;
  const int tid = threadIdx.x;
  const int bm = blockIdx.x*128, bn = blockIdx.y*128;
  const int tx = tid & 15, ty = tid >> 4;
  const int lm = tid >> 1, lk = (tid & 1)*4;
  const float* aptr = A + (long)(bm+lm)*lda + lk;
  const float* bptr = Bb + (long)(bn+lm)*ldb + lk;
  float acc[8][8];
  #pragma unroll
  for (int i=0;i<8;i++)
    #pragma unroll
    for (int j=0;j<8;j++) acc[i][j] = 0.f;
  for (int k0 = 0; k0 < K; k0 += 8){
    float4 av = *(const float4*)(aptr + k0);
    float4 bv = *(const float4*)(bptr + k0);
    As[lk+0][lm]=av.x; As[lk+1][lm]=av.y; As[lk+2][lm]=av.z; As[lk+3][lm]=av.w;
    Bs[lk+0][lm]=bv.x; Bs[lk+1][lm]=bv.y; Bs[lk+2][lm]=bv.z; Bs[lk+3][lm]=bv.w;
    __syncthreads();
    #pragma unroll
    for (int kk=0;kk<8;kk++){
      float a[8], b[8];
      #pragma unroll
      for (int i=0;i<8;i++) a[i] = As[kk][ty*8+i];
      #pragma unroll
      for (int j=0;j<8;j++) b[j] = Bs[kk][tx*8+j];
      #pragma unroll
      for (int i=0;i<8;i++)
        #pragma unroll
        for (int j=0;j<8;j++) acc[i][j] = fmaf(a[i], b[j], acc[i][j]);
    }
    __syncthreads();
  }
  #pragma unroll
  for (int i=0;i<8;i++){
    float* cr = Cb + (long)(bm+ty*8+i)*ldc + bn + tx*8;
    #pragma unroll
    for (int j=0;j<8;j++) cr[j] = acc[i][j];
  }
}

// ---------------- per-channel sum/sumsq over rows (C multiple of 256) ----------------
__global__ __launch_bounds__(256) void k_stats_wide(const float* __restrict__ X, int M, int C, int ld,
    float* __restrict__ buck){
  const int tid = threadIdx.x;
  const int cpt = C >> 8;
  float s[3] = {0,0,0}, q[3] = {0,0,0};
  for (int r = blockIdx.x; r < M; r += gridDim.x){
    const float* row = X + (long)r*ld;
    for (int t=0;t<cpt;t++){ float v = row[t*256+tid]; s[t]+=v; q[t]+=v*v; }
  }
  float* bb = buck + (long)(blockIdx.x & 63)*2*C;
  for (int t=0;t<cpt;t++){
    atomicAdd(&bb[t*256+tid], s[t]);
    atomicAdd(&bb[C + t*256+tid], q[t]);
  }
}

// C==32, f32 contiguous
__global__ __launch_bounds__(256) void k_stats32(const float* __restrict__ X, int total, float* __restrict__ buck){
  int c = threadIdx.x & 31;
  float s=0,q=0;
  for (int e = blockIdx.x*256 + threadIdx.x; e < total; e += gridDim.x*256){ float v=X[e]; s+=v; q+=v*v; }
  float* bb = buck + (long)(blockIdx.x & 63)*64;
  atomicAdd(&bb[c], s); atomicAdd(&bb[32+c], q);
}

__global__ void k_finalize(const float* __restrict__ buck, int C, float invn, float* __restrict__ mr){
  for (int c = threadIdx.x; c < C; c += blockDim.x){
    float s=0,q=0;
    for (int b=0;b<64;b++){ s += buck[(long)b*2*C + c]; q += buck[(long)b*2*C + C + c]; }
    float m = s*invn;
    float v = fmaxf(q*invn - m*m, 0.f);
    mr[c] = m; mr[C+c] = rsqrtf(v + EPS);
  }
}

// ---------------- BN+leaky on raw qkv -> key, q|v, sq ----------------
__global__ __launch_bounds__(256) void k_apply_qkv(const float* __restrict__ raw, const float* __restrict__ mr,
    const float* __restrict__ gq, const float* __restrict__ bq,
    const float* __restrict__ gk, const float* __restrict__ bk,
    const float* __restrict__ gv, const float* __restrict__ bv,
    float* __restrict__ key, float* __restrict__ qv, float* __restrict__ sq, float* __restrict__ flags){
  const int r = blockIdx.x, tid = threadIdx.x;
  __shared__ float red[256];
  const float* row = raw + (long)r*768;
  float zq = row[tid], zk = row[256+tid], zv = row[512+tid];
  if (zq!=zq || zk!=zk || zv!=zv) flags[0] = 1.f;
  float yq = leakyf((zq - mr[tid])*mr[768+tid]*gq[tid] + bq[tid]);
  float yk = leakyf((zk - mr[256+tid])*mr[1024+tid]*gk[tid] + bk[tid]);
  float yv = leakyf((zv - mr[512+tid])*mr[1280+tid]*gv[tid] + bv[tid]);
  qv[(long)r*512 + tid] = yq;
  key[(long)r*256 + tid] = yk;
  qv[(long)r*512 + 256 + tid] = yv;
  red[tid] = yk*yk; __syncthreads();
  for (int off=128; off; off>>=1){ if (tid<off) red[tid] += red[tid+off]; __syncthreads(); }
  if (tid==0) sq[r] = red[0];
}

// ---------------- top-K (K=32) smallest dist per row; one wave per row ----------------
__global__ __launch_bounds__(256) void k_topk(const float* __restrict__ G, const float* __restrict__ sqb,
    int* __restrict__ idxb){
  __shared__ float dist[4][2048];
  const int wv = threadIdx.x >> 6, lane = threadIdx.x & 63;
  const int n = blockIdx.x*4 + wv;
  const float* Grow = G + (long)n*2048;
  const float sqn = sqb[n];
  float lmin = 3.4e38f; int lidx = 0;
  for (int j=0;j<32;j++){
    int m = lane + j*64;
    float d = sqn + sqb[m] - 2.f*Grow[m];
    dist[wv][m] = d;
    if (d < lmin){ lmin = d; lidx = m; }
  }
  int* orow = idxb + n*32;
  for (int t=0;t<32;t++){
    float v = lmin; int i = lidx;
    for (int off=32; off; off>>=1){
      float v2 = __shfl_xor(v, off, 64);
      int i2 = __shfl_xor(i, off, 64);
      if (v2 < v || (v2 == v && i2 < i)){ v = v2; i = i2; }
    }
    if (lane == 0) orow[t] = i;
    if ((i & 63) == lane){
      dist[wv][i] = 3.4e38f;
      lmin = 3.4e38f; lidx = 0;
      for (int j=0;j<32;j++){
        int m = lane + j*64;
        float d = dist[wv][m];
        if (d < lmin){ lmin = d; lidx = m; }
      }
    }
  }
}

// ---------------- stats of z_pb = P[idx]-P[n] ----------------
__global__ __launch_bounds__(256) void k_stats_pb(const float* __restrict__ P, const int* __restrict__ idx,
    float* __restrict__ buck){
  const int c = threadIdx.x;
  float s=0,q=0;
  for (int r = blockIdx.x; r < 4096; r += gridDim.x){
    const long base = (long)(r >> 11) << 11;
    const float pn = P[(long)r*256 + c];
    const int* ir = idx + r*32;
    for (int k=0;k<32;k++){
      int g = ir[k];
      float z = P[(base + g)*256 + c] - pn;
      s += z; q += z*z;
    }
  }
  float* bb = buck + (long)(blockIdx.x & 63)*512;
  atomicAdd(&bb[c], s); atomicAdd(&bb[256+c], q);
}

// ---------------- E1[bn,k,d] = sum_c (key[idx]-q+posb)[c] * We1[d,c] ----------------
__global__ __launch_bounds__(256) void k_e1(
    const float* __restrict__ key, const float* __restrict__ qv, const float* __restrict__ P,
    const int* __restrict__ idx, const float* __restrict__ mrPB,
    const float* __restrict__ gpb, const float* __restrict__ bpb,
    const float* __restrict__ We1, float* __restrict__ E1, float* __restrict__ flags)
{
  __shared__ float Vs[32*257];   // [k][c], stride 257: conflict-free broadcast reads
  __shared__ float W1[128*32];   // half of We1, [c][d]
  const int tid = threadIdx.x;
  const int bn = blockIdx.x;
  const long base = (long)(bn >> 11) << 11;
  {
    const int lane = tid & 63, wv = tid >> 6;
    const int c4 = lane*4;
    float4 q4  = *(const float4*)(qv + (long)bn*512 + c4);
    float4 p4  = *(const float4*)(P + (long)bn*256 + c4);
    float4 mp4 = *(const float4*)(mrPB + c4);
    float4 rp4 = *(const float4*)(mrPB + 256 + c4);
    float4 g4  = *(const float4*)(gpb + c4);
    float4 b4  = *(const float4*)(bpb + c4);
    float qa[4] = {q4.x,q4.y,q4.z,q4.w};
    float pa[4] = {p4.x,p4.y,p4.z,p4.w};
    float ma[4] = {mp4.x,mp4.y,mp4.z,mp4.w};
    float ra[4] = {rp4.x,rp4.y,rp4.z,rp4.w};
    float ga[4] = {g4.x,g4.y,g4.z,g4.w};
    float ba[4] = {b4.x,b4.y,b4.z,b4.w};
    for (int j = 0; j < 8; ++j){
      const int k = wv*8 + j;
      const int g = idx[bn*32 + k];
      float4 kb  = *(const float4*)(key + (base+g)*256 + c4);
      float4 pb4 = *(const float4*)(P + (base+g)*256 + c4);
      float kv[4] = {kb.x,kb.y,kb.z,kb.w};
      float pv[4] = {pb4.x,pb4.y,pb4.z,pb4.w};
      #pragma unroll
      for (int t=0;t<4;t++){
        float zz = pv[t] - pa[t];
        float zh = (zz - ma[t]) * ra[t] * ga[t] + ba[t];
        Vs[k*257 + c4 + t] = kv[t] - qa[t] + leakyf(zh);
      }
    }
  }
  const int k  = tid >> 3;
  const int d4 = (tid & 7) * 4;
  float acc[4] = {0,0,0,0};
  for (int h = 0; h < 2; ++h){
    __syncthreads();
    for (int e = tid; e < 4096; e += 256){
      int c = e >> 5, d = e & 31;
      W1[c*32 + d] = We1[(long)d*256 + h*128 + c];
    }
    __syncthreads();
    const float* vrow = &Vs[k*257 + h*128];
    for (int c = 0; c < 128; ++c){
      float a = vrow[c];
      float4 w4 = *(const float4*)&W1[c*32 + d4];
      acc[0] = fmaf(a, w4.x, acc[0]);
      acc[1] = fmaf(a, w4.y, acc[1]);
      acc[2] = fmaf(a, w4.z, acc[2]);
      acc[3] = fmaf(a, w4.w, acc[3]);
    }
  }
  float chk = acc[0]+acc[1]+acc[2]+acc[3];
  if (chk != chk) flags[1] = 1.f;
  float* o = E1 + (long)bn*1024 + k*32 + d4;
  o[0]=acc[0]; o[1]=acc[1]; o[2]=acc[2]; o[3]=acc[3];
}

// ---------------- E2 = leaky(bn(E1)) @ We2^T, IN PLACE over E1 ----------------
__global__ __launch_bounds__(64) void k_e2(
    float* __restrict__ E, const float* __restrict__ mrE1,
    const float* __restrict__ ge1, const float* __restrict__ be1,
    const float* __restrict__ We2, float* __restrict__ flags)
{
  __shared__ float Ts[32*33];
  __shared__ float W2[32*33];
  const int lane = threadIdx.x;
  const int bn = blockIdx.x;
  for (int i=0;i<16;i++){
    int e = lane + i*64;
    int k = e >> 5, c = e & 31;
    float v = E[(long)bn*1024 + e];
    Ts[k*33 + c] = leakyf((v - mrE1[c]) * mrE1[32+c] * ge1[c] + be1[c]);
    W2[c*33 + k] = We2[e];   // e = d*32+c (d in k slot) => W2[c][d]
  }
  __syncthreads();
  const int k  = lane >> 1;
  const int d0 = (lane & 1)*16;
  float acc[16];
  #pragma unroll
  for (int i=0;i<16;i++) acc[i]=0.f;
  for (int c=0;c<32;c++){
    float a = Ts[k*33+c];
    #pragma unroll
    for (int dd=0;dd<16;dd++) acc[dd] = fmaf(a, W2[c*33 + d0+dd], acc[dd]);
  }
  float chk=0;
  #pragma unroll
  for (int i=0;i<16;i++) chk += acc[i];
  if (chk != chk) flags[2] = 1.f;
  float* o = E + (long)bn*1024 + k*32 + d0;
  #pragma unroll
  for (int dd=0;dd<16;dd++) o[dd] = acc[dd];
}

// ---------------- softmax over k + attention + residual ----------------
__global__ __launch_bounds__(64) void k_attn(
    const float* __restrict__ E2, const float* __restrict__ mrE2,
    const float* __restrict__ ge2, const float* __restrict__ be2,
    const float* __restrict__ qv, const float* __restrict__ P, const int* __restrict__ idx,
    const float* __restrict__ mrPB, const float* __restrict__ gpb, const float* __restrict__ bpb,
    const float* __restrict__ xin, float* __restrict__ x2, float* __restrict__ flags)
{
  __shared__ float L[32][33];
  const int lane = threadIdx.x;
  const int bn = blockIdx.x;
  const long base = (long)(bn >> 11) << 11;
  for (int qq=0; qq<4; qq++){
    int e = lane*16 + qq*4;
    int k = e >> 5, g0 = e & 31;
    float4 v  = *(const float4*)(E2 + (long)bn*1024 + e);
    float4 m4 = *(const float4*)(mrE2 + g0);
    float4 r4 = *(const float4*)(mrE2 + 32 + g0);
    float4 g4 = *(const float4*)(ge2 + g0);
    float4 b4 = *(const float4*)(be2 + g0);
    L[k][g0+0] = leakyf((v.x - m4.x)*r4.x*g4.x + b4.x);
    L[k][g0+1] = leakyf((v.y - m4.y)*r4.y*g4.y + b4.y);
    L[k][g0+2] = leakyf((v.z - m4.z)*r4.z*g4.z + b4.z);
    L[k][g0+3] = leakyf((v.w - m4.w)*r4.w*g4.w + b4.w);
  }
  __syncthreads();
  {
    const int g = lane & 31, h = lane >> 5;
    float mx = -3.4e38f;
    for (int j=0;j<16;j++) mx = fmaxf(mx, L[h*16+j][g]);
    mx = fmaxf(mx, __shfl_xor(mx, 32, 64));
    float sm = 0.f, ev[16];
    for (int j=0;j<16;j++){ float e_ = __expf(L[h*16+j][g] - mx); ev[j] = e_; sm += e_; }
    sm += __shfl_xor(sm, 32, 64);
    float inv = 1.f/sm;
    for (int j=0;j<16;j++) L[h*16+j][g] = ev[j]*inv;
  }
  __syncthreads();
  const int c4 = lane*4, gg = lane >> 1;
  float4 pn4 = *(const float4*)(P + (long)bn*256 + c4);
  float4 mp4 = *(const float4*)(mrPB + c4);
  float4 rp4 = *(const float4*)(mrPB + 256 + c4);
  float4 g4 = *(const float4*)(gpb + c4);
  float4 b4 = *(const float4*)(bpb + c4);
  float pa[4] = {pn4.x,pn4.y,pn4.z,pn4.w};
  float ma[4] = {mp4.x,mp4.y,mp4.z,mp4.w};
  float ra[4] = {rp4.x,rp4.y,rp4.z,rp4.w};
  float ga[4] = {g4.x,g4.y,g4.z,g4.w};
  float ba[4] = {b4.x,b4.y,b4.z,b4.w};
  float accv[4] = {0,0,0,0};
  const int* ir = idx + bn*32;
  for (int k=0;k<32;k++){
    int gi = ir[k];
    float4 vv = *(const float4*)(qv + (long)(base+gi)*512 + 256 + c4);
    float4 pp = *(const float4*)(P + (base+gi)*256 + c4);
    float w = L[k][gg];
    float va[4]={vv.x,vv.y,vv.z,vv.w}, pq[4]={pp.x,pp.y,pp.z,pp.w};
    #pragma unroll
    for (int t=0;t<4;t++){
      float zz = pq[t]-pa[t];
      float zh = (zz - ma[t])*ra[t]*ga[t] + ba[t];
      accv[t] = fmaf(va[t] + leakyf(zh), w, accv[t]);
    }
  }
  float chk = accv[0]+accv[1]+accv[2]+accv[3];
  if (chk != chk) flags[3] = 1.f;
  float4 x4 = *(const float4*)(xin + (long)bn*256 + c4);
  float4 o;
  o.x = x4.x + accv[0]; o.y = x4.y + accv[1];
  o.z = x4.z + accv[2]; o.w = x4.w + accv[3];
  *(float4*)(x2 + (long)bn*256 + c4) = o;
}

// ---------------- BN + SiLU in place ----------------
__global__ __launch_bounds__(256) void k_bnsilu(float* __restrict__ Zm, const float* __restrict__ mr,
    const float* __restrict__ gm, const float* __restrict__ bm, int C){
  const int r = blockIdx.x, tid = threadIdx.x;
  float* row = Zm + (long)r*C;
  for (int c = tid; c < C; c += 256){
    float z = row[c];
    float y = (z - mr[c])*mr[C+c]*gm[c] + bm[c];
    row[c] = y / (1.f + __expf(-y));
  }
}

// ---------------- final: out = x2 + silu(bn(Zm2)) with diagnostics ----------------
__global__ __launch_bounds__(256) void k_final(const float* __restrict__ x2, const float* __restrict__ Zm2,
    const float* __restrict__ mr, const float* __restrict__ gm, const float* __restrict__ bm,
    const float* __restrict__ flags, float* __restrict__ out){
  const int r = blockIdx.x, c = threadIdx.x;
  float xv = x2[(long)r*256 + c];
  float z = Zm2[(long)r*256 + c];
  float y = (z - mr[c])*mr[256+c]*gm[c] + bm[c];
  float s = y / (1.f + __expf(-y));
  float rr = xv + s;
  float f0 = flags[0], f1 = flags[1], f2 = flags[2], f3 = flags[3];
  if (f0 != 0.f) rr = 100.f;
  else if (f1 != 0.f) rr = 200.f;
  else if (f2 != 0.f) rr = 300.f;
  else if (f3 != 0.f) rr = 400.f;
  else if (xv != xv) rr = 500.f;
  else if (rr != rr) rr = 600.f;
  out[(long)r*256 + c] = rr;
}

extern "C" void kernel_launch(void* const* d_in, const int* in_sizes, int n_in,
                              void* d_out, int out_size, void* d_ws, size_t ws_size,
                              hipStream_t stream){
  (void)in_sizes; (void)n_in; (void)out_size; (void)ws_size;
  const float* x   = (const float*)d_in[0];
  const float* pos = (const float*)d_in[1];
  const float* Wq  = (const float*)d_in[2];
  const float* gq  = (const float*)d_in[3];
  const float* bq  = (const float*)d_in[4];
  const float* Wk  = (const float*)d_in[5];
  const float* gk  = (const float*)d_in[6];
  const float* bk  = (const float*)d_in[7];
  const float* Wv  = (const float*)d_in[8];
  const float* gv  = (const float*)d_in[9];
  const float* bv  = (const float*)d_in[10];
  const float* Wpb = (const float*)d_in[11];
  const float* gpb = (const float*)d_in[12];
  const float* bpb = (const float*)d_in[13];
  const float* We1 = (const float*)d_in[14];
  const float* ge1 = (const float*)d_in[15];
  const float* be1 = (const float*)d_in[16];
  const float* We2 = (const float*)d_in[17];
  const float* ge2 = (const float*)d_in[18];
  const float* be2 = (const float*)d_in[19];
  const float* Wm1 = (const float*)d_in[20];
  const float* gm1 = (const float*)d_in[21];
  const float* bm1 = (const float*)d_in[22];
  const float* Wm2 = (const float*)d_in[23];
  const float* gm2 = (const float*)d_in[24];
  const float* bm2 = (const float*)d_in[25];

  // workspace layout (float offsets), total 9,813,696 floats = 39.3 MB
  float* w     = (float*)d_ws;
  float* arena = w;                       // 4,194,304: rawQKV / G / E1->E2 (in place) / Zm1+Zm2
  float* key   = w + 4194304;             // 1,048,576
  float* P     = w + 5242880;             // 1,048,576
  float* x2    = w + 6291456;             // 1,048,576
  float* qv    = w + 7340032;             // 2,097,152 (q|v per row, 512 apart)
  float* sq    = w + 9437184;             // 4,096
  int*   idx   = (int*)(w + 9441280);     // 131,072 ints
  float* buck  = w + 9572352;             // 237,568
  float* mr    = w + 9809920;             // 3,712
  float* flags = w + 9813632;             // 64
  float* bQKV = buck;            float* bPB = buck + 98304;  float* bE1 = buck + 131072;
  float* bE2  = buck + 135168;   float* bM1 = buck + 139264; float* bM2 = buck + 204800;
  float* mrQKV = mr;        float* mrPB = mr + 1536; float* mrE1 = mr + 2048;
  float* mrE2  = mr + 2112; float* mrM1 = mr + 2176; float* mrM2 = mr + 3200;
  float* Zm1 = arena;                     // 4096*512 (E1/E2 dead by then)
  float* Zm2 = arena + 2097152;           // 4096*256

  k_zero<<<944,256,0,stream>>>(buck, 241408);   // buckets + mr + flags
  // raw qkv = x @ {Wq,Wk,Wv}^T  (ldc 768)
  k_gemm_nt<<<dim3(32,2,3),256,0,stream>>>(x,256, Wq,Wk,Wv,256, arena,768,256, 256);
  // P = pos @ Wpb^T
  k_gemm_nt<<<dim3(32,2,1),256,0,stream>>>(pos,256, Wpb,Wpb,Wpb,256, P,256,0, 256);
  k_stats_wide<<<512,256,0,stream>>>(arena, 4096, 768, 768, bQKV);
  k_finalize<<<1,256,0,stream>>>(bQKV, 768, 1.f/4096.f, mrQKV);
  k_apply_qkv<<<4096,256,0,stream>>>(arena, mrQKV, gq,bq,gk,bk,gv,bv, key, qv, sq, flags);
  // per-batch Gram + topk (arena reused as 2048x2048 G)
  k_gemm_nt<<<dim3(16,16,1),256,0,stream>>>(key,256, key,key,key,256, arena,2048,0, 256);
  k_topk<<<512,256,0,stream>>>(arena, sq, idx);
  k_gemm_nt<<<dim3(16,16,1),256,0,stream>>>(key+524288,256, key+524288,key+524288,key+524288,256, arena,2048,0, 256);
  k_topk<<<512,256,0,stream>>>(arena, sq+2048, idx+65536);
  k_stats_pb<<<256,256,0,stream>>>(P, idx, bPB);
  k_finalize<<<1,256,0,stream>>>(bPB, 256, 1.f/131072.f, mrPB);
  k_e1<<<4096,256,0,stream>>>(key, qv, P, idx, mrPB, gpb, bpb, We1, arena, flags);
  k_stats32<<<512,256,0,stream>>>(arena, 4194304, bE1);
  k_finalize<<<1,256,0,stream>>>(bE1, 32, 1.f/131072.f, mrE1);
  k_e2<<<4096,64,0,stream>>>(arena, mrE1, ge1, be1, We2, flags);
  k_stats32<<<512,256,0,stream>>>(arena, 4194304, bE2);
  k_finalize<<<1,256,0,stream>>>(bE2, 32, 1.f/131072.f, mrE2);
  k_attn<<<4096,64,0,stream>>>(arena, mrE2, ge2, be2, qv, P, idx, mrPB, gpb, bpb, x, x2, flags);
  // MLP
  k_gemm_nt<<<dim3(32,4,1),256,0,stream>>>(x2,256, Wm1,Wm1,Wm1,256, Zm1,512,0, 256);
  k_stats_wide<<<512,256,0,stream>>>(Zm1, 4096, 512, 512, bM1);
  k_finalize<<<1,256,0,stream>>>(bM1, 512, 1.f/4096.f, mrM1);
  k_bnsilu<<<4096,256,0,stream>>>(Zm1, mrM1, gm1, bm1, 512);
  k_gemm_nt<<<dim3(32,2,1),256,0,stream>>>(Zm1,512, Wm2,Wm2,Wm2,512, Zm2,256,0, 512);
  k_stats_wide<<<512,256,0,stream>>>(Zm2, 4096, 256, 256, bM2);
  k_finalize<<<1,256,0,stream>>>(bM2, 256, 1.f/4096.f, mrM2);
  k_final<<<4096,256,0,stream>>>(x2, Zm2, mrM2, gm2, bm2, flags, (float*)d_out);
}

// Round 4
// 695.004 us; speedup vs baseline: 1.0657x; 1.0657x over previous
//
#include <hip/hip_runtime.h>

#define EPS 1e-5f

__device__ __forceinline__ float leakyf(float z){ return z >= 0.f ? z : 0.2f*z; }
__device__ __forceinline__ float siluf(float y){ return y / (1.f + __expf(-y)); }
__device__ __forceinline__ unsigned f2bfu(float f){
  unsigned u = __float_as_uint(f);
  return (u + 0x7FFFu + ((u>>16)&1u)) >> 16;
}
__device__ __forceinline__ float bflo(unsigned p){ return __uint_as_float(p << 16); }
__device__ __forceinline__ float bfhi(unsigned p){ return __uint_as_float(p & 0xffff0000u); }

// ---------------- zero scratch ----------------
__global__ __launch_bounds__(256) void k_zero(float* __restrict__ p, int n){
  int i = blockIdx.x*256 + threadIdx.x;
  if (i < n) p[i] = 0.f;
}

// ------- generic NT GEMM: C[m,n] = sum_k A'[m,k]*B[n,k], optional A bn+silu, optional stats epilogue -------
template<bool TRANSA, bool STATS>
__global__ __launch_bounds__(256) void k_gemm(
    const float* __restrict__ A, int lda,
    const float* __restrict__ tA, const float* __restrict__ gA, const float* __restrict__ bA, int CA,
    const float* __restrict__ B0, const float* __restrict__ B1, const float* __restrict__ B2,
    int ldb, float* __restrict__ C, int ldc, long cStr, int K,
    float* __restrict__ buck, int statC, int statChanStr)
{
  __shared__ float As[8][128];
  __shared__ float Bs[8][128];
  const int z = blockIdx.z;
  const float* Bb = (z==0 ? B0 : (z==1 ? B1 : B2));
  float* Cb = C + (long)z*cStr;
  const int tid = threadIdx.x;
  const int bm = blockIdx.x*128, bn = blockIdx.y*128;
  const int tx = tid & 15, ty = tid >> 4;
  const int lm = tid >> 1, lk = (tid & 1)*4;
  const float* aptr = A + (long)(bm+lm)*lda + lk;
  const float* bptr = Bb + (long)(bn+lm)*ldb + lk;
  float acc[8][8];
  #pragma unroll
  for (int i=0;i<8;i++)
    #pragma unroll
    for (int j=0;j<8;j++) acc[i][j] = 0.f;
  for (int k0 = 0; k0 < K; k0 += 8){
    float4 av = *(const float4*)(aptr + k0);
    float4 bv = *(const float4*)(bptr + k0);
    if (TRANSA){
      const int kk = k0 + lk;
      float4 m4 = *(const float4*)(tA + kk);
      float4 r4 = *(const float4*)(tA + CA + kk);
      float4 g4 = *(const float4*)(gA + kk);
      float4 b4 = *(const float4*)(bA + kk);
      av.x = siluf((av.x - m4.x)*r4.x*g4.x + b4.x);
      av.y = siluf((av.y - m4.y)*r4.y*g4.y + b4.y);
      av.z = siluf((av.z - m4.z)*r4.z*g4.z + b4.z);
      av.w = siluf((av.w - m4.w)*r4.w*g4.w + b4.w);
    }
    As[lk+0][lm]=av.x; As[lk+1][lm]=av.y; As[lk+2][lm]=av.z; As[lk+3][lm]=av.w;
    Bs[lk+0][lm]=bv.x; Bs[lk+1][lm]=bv.y; Bs[lk+2][lm]=bv.z; Bs[lk+3][lm]=bv.w;
    __syncthreads();
    #pragma unroll
    for (int kk=0;kk<8;kk++){
      float a[8], b[8];
      #pragma unroll
      for (int i=0;i<8;i++) a[i] = As[kk][ty*8+i];
      #pragma unroll
      for (int j=0;j<8;j++) b[j] = Bs[kk][tx*8+j];
      #pragma unroll
      for (int i=0;i<8;i++)
        #pragma unroll
        for (int j=0;j<8;j++) acc[i][j] = fmaf(a[i], b[j], acc[i][j]);
    }
    __syncthreads();
  }
  #pragma unroll
  for (int i=0;i<8;i++){
    float* cr = Cb + (long)(bm+ty*8+i)*ldc + bn + tx*8;
    #pragma unroll
    for (int j=0;j<8;j++) cr[j] = acc[i][j];
  }
  if (STATS){
    float* S0 = &As[0][0];
    float* S1 = &Bs[0][0];
    // pass 1: sums
    float cs[8];
    #pragma unroll
    for (int j=0;j<8;j++){ float s=0.f;
      #pragma unroll
      for (int i=0;i<8;i++) s += acc[i][j];
      cs[j]=s; }
    #pragma unroll
    for (int j=0;j<8;j++) (ty<8 ? S0 : S1)[(ty&7)*128 + tx*8 + j] = cs[j];
    __syncthreads();
    if (tid < 128){
      float s=0.f;
      #pragma unroll
      for (int t=0;t<16;t++) s += (t<8 ? S0 : S1)[(t&7)*128 + tid];
      int chan = statChanStr*z + bn + tid;
      atomicAdd(&buck[(long)(blockIdx.x & 63)*2*statC + chan], s);
    }
    __syncthreads();
    // pass 2: sum of squares
    #pragma unroll
    for (int j=0;j<8;j++){ float s=0.f;
      #pragma unroll
      for (int i=0;i<8;i++) s += acc[i][j]*acc[i][j];
      cs[j]=s; }
    #pragma unroll
    for (int j=0;j<8;j++) (ty<8 ? S0 : S1)[(ty&7)*128 + tx*8 + j] = cs[j];
    __syncthreads();
    if (tid < 128){
      float s=0.f;
      #pragma unroll
      for (int t=0;t<16;t++) s += (t<8 ? S0 : S1)[(t&7)*128 + tid];
      int chan = statChanStr*z + bn + tid;
      atomicAdd(&buck[(long)(blockIdx.x & 63)*2*statC + statC + chan], s);
    }
  }
}

__global__ void k_finalize(const float* __restrict__ buck, int C, float invn, float* __restrict__ mr){
  for (int c = threadIdx.x; c < C; c += blockDim.x){
    float s=0,q=0;
    for (int b=0;b<64;b++){ s += buck[(long)b*2*C + c]; q += buck[(long)b*2*C + C + c]; }
    float m = s*invn;
    float v = fmaxf(q*invn - m*m, 0.f);
    mr[c] = m; mr[C+c] = rsqrtf(v + EPS);
  }
}

// ---------------- BN+leaky on raw qkv -> key, q|v, sq ----------------
__global__ __launch_bounds__(256) void k_apply_qkv(const float* __restrict__ raw, const float* __restrict__ mr,
    const float* __restrict__ gq, const float* __restrict__ bq,
    const float* __restrict__ gk, const float* __restrict__ bk,
    const float* __restrict__ gv, const float* __restrict__ bv,
    float* __restrict__ key, float* __restrict__ qv, float* __restrict__ sq){
  const int r = blockIdx.x, tid = threadIdx.x;
  __shared__ float red[256];
  const float* row = raw + (long)r*768;
  float zq = row[tid], zk = row[256+tid], zv = row[512+tid];
  float yq = leakyf((zq - mr[tid])*mr[768+tid]*gq[tid] + bq[tid]);
  float yk = leakyf((zk - mr[256+tid])*mr[1024+tid]*gk[tid] + bk[tid]);
  float yv = leakyf((zv - mr[512+tid])*mr[1280+tid]*gv[tid] + bv[tid]);
  qv[(long)r*512 + tid] = yq;
  key[(long)r*256 + tid] = yk;
  qv[(long)r*512 + 256 + tid] = yv;
  red[tid] = yk*yk; __syncthreads();
  for (int off=128; off; off>>=1){ if (tid<off) red[tid] += red[tid+off]; __syncthreads(); }
  if (tid==0) sq[r] = red[0];
}

// ---------------- top-K (K=32) smallest dist per row; one wave per row ----------------
__global__ __launch_bounds__(256) void k_topk(const float* __restrict__ G, const float* __restrict__ sqb,
    int* __restrict__ idxb){
  __shared__ float dist[4][2048];
  const int wv = threadIdx.x >> 6, lane = threadIdx.x & 63;
  const int n = blockIdx.x*4 + wv;
  const float* Grow = G + (long)n*2048;
  const float sqn = sqb[n];
  float lmin = 3.4e38f; int lidx = 0;
  for (int j=0;j<32;j++){
    int m = lane + j*64;
    float d = sqn + sqb[m] - 2.f*Grow[m];
    dist[wv][m] = d;
    if (d < lmin){ lmin = d; lidx = m; }
  }
  int* orow = idxb + n*32;
  for (int t=0;t<32;t++){
    float v = lmin; int i = lidx;
    for (int off=32; off; off>>=1){
      float v2 = __shfl_xor(v, off, 64);
      int i2 = __shfl_xor(i, off, 64);
      if (v2 < v || (v2 == v && i2 < i)){ v = v2; i = i2; }
    }
    if (lane == 0) orow[t] = i;
    if ((i & 63) == lane){
      dist[wv][i] = 3.4e38f;
      lmin = 3.4e38f; lidx = 0;
      for (int j=0;j<32;j++){
        int m = lane + j*64;
        float d = dist[wv][m];
        if (d < lmin){ lmin = d; lidx = m; }
      }
    }
  }
}

// ---------------- stats of z_pb = P[idx]-P[n] ----------------
__global__ __launch_bounds__(256) void k_stats_pb(const float* __restrict__ P, const int* __restrict__ idx,
    float* __restrict__ buck){
  const int c = threadIdx.x;
  float s=0,q=0;
  for (int r = blockIdx.x; r < 4096; r += gridDim.x){
    const long base = (long)(r >> 11) << 11;
    const float pn = P[(long)r*256 + c];
    const int* ir = idx + r*32;
    for (int k=0;k<32;k++){
      int g = ir[k];
      float z = P[(base + g)*256 + c] - pn;
      s += z; q += z*z;
    }
  }
  float* bb = buck + (long)(blockIdx.x & 63)*512;
  atomicAdd(&bb[c], s); atomicAdd(&bb[256+c], q);
}

// ---------------- KW = key@We1^T, QW = q@We1^T  (R[z][4096][32]) ----------------
__global__ __launch_bounds__(256) void k_kwqw(const float* __restrict__ key, const float* __restrict__ qv,
    const float* __restrict__ We1, float* __restrict__ KWQW){
  __shared__ float Wt[256*33];   // [c][d] padded
  __shared__ float Rs[8*260];
  const int tid = threadIdx.x;
  const int z = blockIdx.y;
  const float* src = z ? qv : key;
  const int ld = z ? 512 : 256;
  for (int e = tid*4; e < 8192; e += 1024){
    float4 w4 = *(const float4*)(We1 + e);
    int d = e >> 8, c = e & 255;
    Wt[(c+0)*33+d]=w4.x; Wt[(c+1)*33+d]=w4.y; Wt[(c+2)*33+d]=w4.z; Wt[(c+3)*33+d]=w4.w;
  }
  const int rbase = blockIdx.x*16;
  for (int h=0; h<2; h++){
    __syncthreads();
    for (int e = tid*4; e < 2048; e += 1024){
      int r = e >> 8, c = e & 255;
      *(float4*)&Rs[r*260+c] = *(const float4*)(src + (long)(rbase + h*8 + r)*ld + c);
    }
    __syncthreads();
    const int rl = tid>>5, d = tid&31;
    float acc=0.f;
    for (int c=0;c<256;c++) acc = fmaf(Rs[rl*260+c], Wt[c*33+d], acc);
    KWQW[(long)z*131072 + (long)(rbase+h*8+rl)*32 + d] = acc;
  }
}

// ---------------- E1[bn,kk,d] = posb@We1^T + KW[g] - QW[n]; fused stats ----------------
__global__ __launch_bounds__(256) void k_e1(
    const float* __restrict__ P, const int* __restrict__ idx, const float* __restrict__ KWQW,
    const float* __restrict__ mrPB, const float* __restrict__ gpb, const float* __restrict__ bpb,
    const float* __restrict__ We1, float* __restrict__ E1, float* __restrict__ buckE1)
{
  __shared__ float Vs[16*260];     // posb rows [k][c] stride 260
  __shared__ unsigned Wp[16*260];  // bf16 pairs: Wp[t][c] = (bf16 W[2t][c]) | (bf16 W[2t+1][c] << 16)
  const int tid = threadIdx.x;
  const int bn = blockIdx.x >> 1;
  const int kh = (blockIdx.x & 1)*16;
  const long base = (long)(bn >> 11) << 11;
  for (int e = tid; e < 4096; e += 256){
    int t = e >> 8, c = e & 255;
    unsigned u0 = f2bfu(We1[(long)(2*t)*256 + c]);
    unsigned u1 = f2bfu(We1[(long)(2*t+1)*256 + c]);
    Wp[t*260 + c] = u0 | (u1 << 16);
  }
  {
    const int lane = tid & 63, wv = tid >> 6;
    const int c4 = lane*4;
    float4 p4  = *(const float4*)(P + (long)bn*256 + c4);
    float4 mp4 = *(const float4*)(mrPB + c4);
    float4 rp4 = *(const float4*)(mrPB + 256 + c4);
    float4 g4  = *(const float4*)(gpb + c4);
    float4 b4  = *(const float4*)(bpb + c4);
    for (int j = 0; j < 4; ++j){
      const int kl = wv*4 + j;
      const int g = idx[bn*32 + kh + kl];
      float4 pb4 = *(const float4*)(P + (base+g)*256 + c4);
      float4 o;
      o.x = leakyf((pb4.x - p4.x - mp4.x)*rp4.x*g4.x + b4.x);
      o.y = leakyf((pb4.y - p4.y - mp4.y)*rp4.y*g4.y + b4.y);
      o.z = leakyf((pb4.z - p4.z - mp4.z)*rp4.z*g4.z + b4.z);
      o.w = leakyf((pb4.w - p4.w - mp4.w)*rp4.w*g4.w + b4.w);
      *(float4*)&Vs[kl*260 + c4] = o;
    }
  }
  __syncthreads();
  const int t = tid & 15, kl = tid >> 4;
  const int g2 = idx[bn*32 + kh + kl];
  float acc0=0.f, acc1=0.f;
  const float* vrow = &Vs[kl*260];
  const unsigned* wrow = &Wp[t*260];
  for (int c = 0; c < 256; c += 2){
    float2 a2 = *(const float2*)(vrow + c);
    unsigned w0 = wrow[c], w1 = wrow[c+1];
    acc0 = fmaf(a2.x, bflo(w0), acc0); acc1 = fmaf(a2.x, bfhi(w0), acc1);
    acc0 = fmaf(a2.y, bflo(w1), acc0); acc1 = fmaf(a2.y, bfhi(w1), acc1);
  }
  const float* kwr = KWQW + (long)(base+g2)*32;
  const float* qwr = KWQW + 131072 + (long)bn*32;
  const int d0 = 2*t;
  float o0 = acc0 + kwr[d0]   - qwr[d0];
  float o1 = acc1 + kwr[d0+1] - qwr[d0+1];
  float2 o2; o2.x = o0; o2.y = o1;
  *(float2*)(E1 + ((long)bn*32 + kh + kl)*32 + d0) = o2;
  // fused stats
  __syncthreads();
  float* Sm = Vs;
  Sm[kl*34 + d0] = o0; Sm[kl*34 + d0+1] = o1;
  __syncthreads();
  if (tid < 32){
    float s=0.f, q=0.f;
    for (int k2=0;k2<16;k2++){ float v = Sm[k2*34 + tid]; s += v; q += v*v; }
    float* bb = buckE1 + (long)(blockIdx.x & 63)*64;
    atomicAdd(&bb[tid], s); atomicAdd(&bb[32+tid], q);
  }
}

// ---------------- E2 = leaky(bn(E1)) @ We2^T, IN PLACE; fused stats ----------------
__global__ __launch_bounds__(64) void k_e2(
    float* __restrict__ E, const float* __restrict__ mrE1,
    const float* __restrict__ ge1, const float* __restrict__ be1,
    const float* __restrict__ We2, float* __restrict__ buckE2)
{
  __shared__ float Ts[32*33];
  __shared__ float W2[32*33];
  const int lane = threadIdx.x;
  const int bn = blockIdx.x;
  for (int i=0;i<16;i++){
    int e = lane + i*64;
    int k = e >> 5, c = e & 31;
    float v = E[(long)bn*1024 + e];
    Ts[k*33 + c] = leakyf((v - mrE1[c]) * mrE1[32+c] * ge1[c] + be1[c]);
    W2[c*33 + k] = We2[e];
  }
  __syncthreads();
  const int k  = lane >> 1;
  const int d0 = (lane & 1)*16;
  float acc[16];
  #pragma unroll
  for (int i=0;i<16;i++) acc[i]=0.f;
  for (int c=0;c<32;c++){
    float a = Ts[k*33+c];
    #pragma unroll
    for (int dd=0;dd<16;dd++) acc[dd] = fmaf(a, W2[c*33 + d0+dd], acc[dd]);
  }
  float* o = E + (long)bn*1024 + k*32 + d0;
  #pragma unroll
  for (int dd=0;dd<16;dd++) o[dd] = acc[dd];
  // fused stats
  __syncthreads();
  #pragma unroll
  for (int dd=0;dd<16;dd++) Ts[k*33 + d0+dd] = acc[dd];
  __syncthreads();
  if (lane < 32){
    float s=0.f, q=0.f;
    for (int k2=0;k2<32;k2++){ float v = Ts[k2*33 + lane]; s += v; q += v*v; }
    float* bb = buckE2 + (long)(blockIdx.x & 63)*64;
    atomicAdd(&bb[lane], s); atomicAdd(&bb[32+lane], q);
  }
}

// ---------------- softmax over k + attention + residual ----------------
__global__ __launch_bounds__(64) void k_attn(
    const float* __restrict__ E2, const float* __restrict__ mrE2,
    const float* __restrict__ ge2, const float* __restrict__ be2,
    const float* __restrict__ qv, const float* __restrict__ P, const int* __restrict__ idx,
    const float* __restrict__ mrPB, const float* __restrict__ gpb, const float* __restrict__ bpb,
    const float* __restrict__ xin, float* __restrict__ x2)
{
  __shared__ float L[32][33];
  const int lane = threadIdx.x;
  const int bn = blockIdx.x;
  const long base = (long)(bn >> 11) << 11;
  for (int qq=0; qq<4; qq++){
    int e = lane*16 + qq*4;
    int k = e >> 5, g0 = e & 31;
    float4 v  = *(const float4*)(E2 + (long)bn*1024 + e);
    float4 m4 = *(const float4*)(mrE2 + g0);
    float4 r4 = *(const float4*)(mrE2 + 32 + g0);
    float4 g4 = *(const float4*)(ge2 + g0);
    float4 b4 = *(const float4*)(be2 + g0);
    L[k][g0+0] = leakyf((v.x - m4.x)*r4.x*g4.x + b4.x);
    L[k][g0+1] = leakyf((v.y - m4.y)*r4.y*g4.y + b4.y);
    L[k][g0+2] = leakyf((v.z - m4.z)*r4.z*g4.z + b4.z);
    L[k][g0+3] = leakyf((v.w - m4.w)*r4.w*g4.w + b4.w);
  }
  __syncthreads();
  {
    const int g = lane & 31, h = lane >> 5;
    float mx = -3.4e38f;
    for (int j=0;j<16;j++) mx = fmaxf(mx, L[h*16+j][g]);
    mx = fmaxf(mx, __shfl_xor(mx, 32, 64));
    float sm = 0.f, ev[16];
    for (int j=0;j<16;j++){ float e_ = __expf(L[h*16+j][g] - mx); ev[j] = e_; sm += e_; }
    sm += __shfl_xor(sm, 32, 64);
    float inv = 1.f/sm;
    for (int j=0;j<16;j++) L[h*16+j][g] = ev[j]*inv;
  }
  __syncthreads();
  const int c4 = lane*4, gg = lane >> 1;
  float4 pn4 = *(const float4*)(P + (long)bn*256 + c4);
  float4 mp4 = *(const float4*)(mrPB + c4);
  float4 rp4 = *(const float4*)(mrPB + 256 + c4);
  float4 g4 = *(const float4*)(gpb + c4);
  float4 b4 = *(const float4*)(bpb + c4);
  float accv[4] = {0,0,0,0};
  const int* ir = idx + bn*32;
  for (int k=0;k<32;k++){
    int gi = ir[k];
    float4 vv = *(const float4*)(qv + (long)(base+gi)*512 + 256 + c4);
    float4 pp = *(const float4*)(P + (base+gi)*256 + c4);
    float w = L[k][gg];
    float zh0 = (pp.x - pn4.x - mp4.x)*rp4.x*g4.x + b4.x;
    float zh1 = (pp.y - pn4.y - mp4.y)*rp4.y*g4.y + b4.y;
    float zh2 = (pp.z - pn4.z - mp4.z)*rp4.z*g4.z + b4.z;
    float zh3 = (pp.w - pn4.w - mp4.w)*rp4.w*g4.w + b4.w;
    accv[0] = fmaf(vv.x + leakyf(zh0), w, accv[0]);
    accv[1] = fmaf(vv.y + leakyf(zh1), w, accv[1]);
    accv[2] = fmaf(vv.z + leakyf(zh2), w, accv[2]);
    accv[3] = fmaf(vv.w + leakyf(zh3), w, accv[3]);
  }
  float4 x4 = *(const float4*)(xin + (long)bn*256 + c4);
  float4 o;
  o.x = x4.x + accv[0]; o.y = x4.y + accv[1];
  o.z = x4.z + accv[2]; o.w = x4.w + accv[3];
  *(float4*)(x2 + (long)bn*256 + c4) = o;
}

// ---------------- final: out = x2 + silu(bn(Zm2)) ----------------
__global__ __launch_bounds__(256) void k_final(const float* __restrict__ x2, const float* __restrict__ Zm2,
    const float* __restrict__ mr, const float* __restrict__ gm, const float* __restrict__ bm,
    float* __restrict__ out){
  const int r = blockIdx.x, c = threadIdx.x;
  float z = Zm2[(long)r*256 + c];
  float y = (z - mr[c])*mr[256+c]*gm[c] + bm[c];
  out[(long)r*256 + c] = x2[(long)r*256 + c] + siluf(y);
}

extern "C" void kernel_launch(void* const* d_in, const int* in_sizes, int n_in,
                              void* d_out, int out_size, void* d_ws, size_t ws_size,
                              hipStream_t stream){
  (void)in_sizes; (void)n_in; (void)out_size; (void)ws_size;
  const float* x   = (const float*)d_in[0];
  const float* pos = (const float*)d_in[1];
  const float* Wq  = (const float*)d_in[2];
  const float* gq  = (const float*)d_in[3];
  const float* bq  = (const float*)d_in[4];
  const float* Wk  = (const float*)d_in[5];
  const float* gk  = (const float*)d_in[6];
  const float* bk  = (const float*)d_in[7];
  const float* Wv  = (const float*)d_in[8];
  const float* gv  = (const float*)d_in[9];
  const float* bv  = (const float*)d_in[10];
  const float* Wpb = (const float*)d_in[11];
  const float* gpb = (const float*)d_in[12];
  const float* bpb = (const float*)d_in[13];
  const float* We1 = (const float*)d_in[14];
  const float* ge1 = (const float*)d_in[15];
  const float* be1 = (const float*)d_in[16];
  const float* We2 = (const float*)d_in[17];
  const float* ge2 = (const float*)d_in[18];
  const float* be2 = (const float*)d_in[19];
  const float* Wm1 = (const float*)d_in[20];
  const float* gm1 = (const float*)d_in[21];
  const float* bm1 = (const float*)d_in[22];
  const float* Wm2 = (const float*)d_in[23];
  const float* gm2 = (const float*)d_in[24];
  const float* bm2 = (const float*)d_in[25];

  // workspace (float offsets) — same 39.3 MB envelope as the passing round
  float* w     = (float*)d_ws;
  float* arena = w;                       // 4,194,304: rawQKV / G / E1->E2 / Zm1+Zm2
  float* key   = w + 4194304;             // 1,048,576
  float* P     = w + 5242880;             // 1,048,576
  float* x2    = w + 6291456;             // 1,048,576 (KWQW aliases here pre-attn)
  float* qv    = w + 7340032;             // 2,097,152 (q|v per row, stride 512)
  float* sq    = w + 9437184;             // 4,096
  int*   idx   = (int*)(w + 9441280);     // 131,072 ints
  float* buck  = w + 9572352;             // 237,568
  float* mr    = w + 9809920;             // 3,712
  float* KWQW  = x2;                      // [2][4096][32] = 262,144 floats, dead before x2 written
  float* bQKV = buck;            float* bPB = buck + 98304;  float* bE1 = buck + 131072;
  float* bE2  = buck + 135168;   float* bM1 = buck + 139264; float* bM2 = buck + 204800;
  float* mrQKV = mr;        float* mrPB = mr + 1536; float* mrE1 = mr + 2048;
  float* mrE2  = mr + 2112; float* mrM1 = mr + 2176; float* mrM2 = mr + 3200;
  float* Zm1 = arena;
  float* Zm2 = arena + 2097152;

  k_zero<<<943,256,0,stream>>>(buck, 241280);
  // raw qkv = x @ {Wq,Wk,Wv}^T, stats fused
  k_gemm<false,true><<<dim3(32,2,3),256,0,stream>>>(x,256, nullptr,nullptr,nullptr,0,
      Wq,Wk,Wv,256, arena,768,256, 256, bQKV,768,256);
  // P = pos @ Wpb^T
  k_gemm<false,false><<<dim3(32,2,1),256,0,stream>>>(pos,256, nullptr,nullptr,nullptr,0,
      Wpb,Wpb,Wpb,256, P,256,0, 256, nullptr,0,0);
  k_finalize<<<1,256,0,stream>>>(bQKV, 768, 1.f/4096.f, mrQKV);
  k_apply_qkv<<<4096,256,0,stream>>>(arena, mrQKV, gq,bq,gk,bk,gv,bv, key, qv, sq);
  // per-batch Gram + topk
  k_gemm<false,false><<<dim3(16,16,1),256,0,stream>>>(key,256, nullptr,nullptr,nullptr,0,
      key,key,key,256, arena,2048,0, 256, nullptr,0,0);
  k_topk<<<512,256,0,stream>>>(arena, sq, idx);
  k_gemm<false,false><<<dim3(16,16,1),256,0,stream>>>(key+524288,256, nullptr,nullptr,nullptr,0,
      key+524288,key+524288,key+524288,256, arena,2048,0, 256, nullptr,0,0);
  k_topk<<<512,256,0,stream>>>(arena, sq+2048, idx+65536);
  k_stats_pb<<<256,256,0,stream>>>(P, idx, bPB);
  k_finalize<<<1,256,0,stream>>>(bPB, 256, 1.f/131072.f, mrPB);
  k_kwqw<<<dim3(256,2),256,0,stream>>>(key, qv, We1, KWQW);
  k_e1<<<8192,256,0,stream>>>(P, idx, KWQW, mrPB, gpb, bpb, We1, arena, bE1);
  k_finalize<<<1,256,0,stream>>>(bE1, 32, 1.f/131072.f, mrE1);
  k_e2<<<4096,64,0,stream>>>(arena, mrE1, ge1, be1, We2, bE2);
  k_finalize<<<1,256,0,stream>>>(bE2, 32, 1.f/131072.f, mrE2);
  k_attn<<<4096,64,0,stream>>>(arena, mrE2, ge2, be2, qv, P, idx, mrPB, gpb, bpb, x, x2);
  // MLP
  k_gemm<false,true><<<dim3(32,4,1),256,0,stream>>>(x2,256, nullptr,nullptr,nullptr,0,
      Wm1,Wm1,Wm1,256, Zm1,512,0, 256, bM1,512,0);
  k_finalize<<<1,256,0,stream>>>(bM1, 512, 1.f/4096.f, mrM1);
  k_gemm<true,true><<<dim3(32,2,1),256,0,stream>>>(Zm1,512, mrM1,gm1,bm1,512,
      Wm2,Wm2,Wm2,512, Zm2,256,0, 512, bM2,256,0);
  k_finalize<<<1,256,0,stream>>>(bM2, 256, 1.f/4096.f, mrM2);
  k_final<<<4096,256,0,stream>>>(x2, Zm2, mrM2, gm2, bm2, (float*)d_out);
}

// Round 5
// 562.888 us; speedup vs baseline: 1.3158x; 1.2347x over previous
//
#include <hip/hip_runtime.h>

#define EPS 1e-5f

typedef __attribute__((ext_vector_type(8))) short s8v;
typedef __attribute__((ext_vector_type(4))) float f4v;

__device__ __forceinline__ float leakyf(float z){ return z >= 0.f ? z : 0.2f*z; }
__device__ __forceinline__ float siluf(float y){ return y / (1.f + __expf(-y)); }
__device__ __forceinline__ unsigned f2bfu(float f){
  unsigned u = __float_as_uint(f);
  return (u + 0x7FFFu + ((u>>16)&1u)) >> 16;
}
__device__ __forceinline__ unsigned short bfr(float f){ return (unsigned short)f2bfu(f); }
__device__ __forceinline__ float bf2f16(unsigned short s){ return __uint_as_float(((unsigned)s)<<16); }
__device__ __forceinline__ float bflo(unsigned p){ return __uint_as_float(p << 16); }
__device__ __forceinline__ float bfhi(unsigned p){ return __uint_as_float(p & 0xffff0000u); }

// ---------------- zero scratch ----------------
__global__ __launch_bounds__(256) void k_zero(float* __restrict__ p, int n){
  int i = blockIdx.x*256 + threadIdx.x;
  if (i < n) p[i] = 0.f;
}

// ------- NT GEMM via split-bf16 MFMA (4 products = f32 fidelity) -------
// C[m,n] = sum_k A'[m,k]*B[n,k]; optional bn+silu on A load; optional column-stats epilogue.
template<bool TRANSA, bool STATS>
__global__ __launch_bounds__(256) void k_gemm(
    const float* __restrict__ A, int lda,
    const float* __restrict__ tA, const float* __restrict__ gA, const float* __restrict__ bA, int CA,
    const float* __restrict__ B0, const float* __restrict__ B1, const float* __restrict__ B2,
    int ldb, float* __restrict__ C, int ldc, long cStr, int K,
    float* __restrict__ buck, int statC, int statChanStr)
{
  // fragment-major planes: element (row, k) -> [((row>>4)*4 + k>>3)*16 + (row&15)]*8 + (k&7)
  __shared__ unsigned short Ah[4096], Al[4096], Bh[4096], Bl[4096];
  __shared__ float Ssum[128], Ssq[128];
  const int z = blockIdx.z;
  const float* Bb = (z==0?B0:(z==1?B1:B2));
  float* Cb = C + (long)z*cStr;
  const int tid = threadIdx.x;
  const int bm = blockIdx.x*128, bn = blockIdx.y*128;
  const int wv = tid>>6, lane = tid&63;
  const int wr = wv>>1, wc = wv&1;
  const int lm = lane&15, quad = lane>>4;
  if (STATS && tid<128){ Ssum[tid]=0.f; Ssq[tid]=0.f; }
  f4v acc[4][4];
  #pragma unroll
  for (int i=0;i<4;i++)
    #pragma unroll
    for (int j=0;j<4;j++) acc[i][j] = (f4v){0.f,0.f,0.f,0.f};

  for (int k0=0; k0<K; k0+=32){
    #pragma unroll
    for (int it=0; it<4; it++){
      const int e = tid + it*256;          // 1024 float4 slots = 128 rows x 8 kgroups
      const int row = e>>3, kg = e&7;
      const int off = (((row>>4)*4 + (kg>>1))*16 + (row&15))*8 + (kg&1)*4;
      float4 av = *(const float4*)(A + (long)(bm+row)*lda + k0 + kg*4);
      if (TRANSA){
        const float* tm = tA + k0 + kg*4;
        float4 m4 = *(const float4*)tm;
        float4 r4 = *(const float4*)(tm + CA);
        float4 g4 = *(const float4*)(gA + k0 + kg*4);
        float4 b4 = *(const float4*)(bA + k0 + kg*4);
        av.x = siluf((av.x - m4.x)*r4.x*g4.x + b4.x);
        av.y = siluf((av.y - m4.y)*r4.y*g4.y + b4.y);
        av.z = siluf((av.z - m4.z)*r4.z*g4.z + b4.z);
        av.w = siluf((av.w - m4.w)*r4.w*g4.w + b4.w);
      }
      ushort4 h4, l4;
      h4.x = bfr(av.x); l4.x = bfr(av.x - bf2f16(h4.x));
      h4.y = bfr(av.y); l4.y = bfr(av.y - bf2f16(h4.y));
      h4.z = bfr(av.z); l4.z = bfr(av.z - bf2f16(h4.z));
      h4.w = bfr(av.w); l4.w = bfr(av.w - bf2f16(h4.w));
      *(ushort4*)&Ah[off] = h4;
      *(ushort4*)&Al[off] = l4;
      float4 bv = *(const float4*)(Bb + (long)(bn+row)*ldb + k0 + kg*4);
      h4.x = bfr(bv.x); l4.x = bfr(bv.x - bf2f16(h4.x));
      h4.y = bfr(bv.y); l4.y = bfr(bv.y - bf2f16(h4.y));
      h4.z = bfr(bv.z); l4.z = bfr(bv.z - bf2f16(h4.z));
      h4.w = bfr(bv.w); l4.w = bfr(bv.w - bf2f16(h4.w));
      *(ushort4*)&Bh[off] = h4;
      *(ushort4*)&Bl[off] = l4;
    }
    __syncthreads();
    s8v ah[4], am[4], bh[4], bm_[4];
    #pragma unroll
    for (int i=0;i<4;i++){
      const int ao = (((wr*4+i)*4 + quad)*16 + lm)*8;
      ah[i] = *(const s8v*)&Ah[ao];
      am[i] = *(const s8v*)&Al[ao];
      const int bo = (((wc*4+i)*4 + quad)*16 + lm)*8;
      bh[i]  = *(const s8v*)&Bh[bo];
      bm_[i] = *(const s8v*)&Bl[bo];
    }
    #pragma unroll
    for (int i=0;i<4;i++)
      #pragma unroll
      for (int j=0;j<4;j++){
        acc[i][j] = __builtin_amdgcn_mfma_f32_16x16x32_bf16(ah[i], bh[j],  acc[i][j], 0,0,0);
        acc[i][j] = __builtin_amdgcn_mfma_f32_16x16x32_bf16(ah[i], bm_[j], acc[i][j], 0,0,0);
        acc[i][j] = __builtin_amdgcn_mfma_f32_16x16x32_bf16(am[i], bh[j],  acc[i][j], 0,0,0);
        acc[i][j] = __builtin_amdgcn_mfma_f32_16x16x32_bf16(am[i], bm_[j], acc[i][j], 0,0,0);
      }
    __syncthreads();
  }
  // C write: row = quad*4+reg (A side), col = lane&15 (B side)
  #pragma unroll
  for (int i=0;i<4;i++){
    #pragma unroll
    for (int rr=0;rr<4;rr++){
      float* cr = Cb + (long)(bm + wr*64 + i*16 + quad*4 + rr)*ldc + bn + wc*64 + lm;
      #pragma unroll
      for (int j=0;j<4;j++) cr[j*16] = acc[i][j][rr];
    }
  }
  if (STATS){
    #pragma unroll
    for (int j=0;j<4;j++){
      float s=0.f, q=0.f;
      #pragma unroll
      for (int i=0;i<4;i++)
        #pragma unroll
        for (int rr=0;rr<4;rr++){ float v = acc[i][j][rr]; s += v; q += v*v; }
      atomicAdd(&Ssum[wc*64 + j*16 + lm], s);
      atomicAdd(&Ssq [wc*64 + j*16 + lm], q);
    }
    __syncthreads();
    if (tid < 128){
      int chan = statChanStr*z + bn + tid;
      float* bb = buck + (long)(blockIdx.x & 63)*2*statC;
      atomicAdd(&bb[chan], Ssum[tid]);
      atomicAdd(&bb[statC + chan], Ssq[tid]);
    }
  }
}

__global__ void k_finalize(const float* __restrict__ buck, int C, float invn, float* __restrict__ mr){
  for (int c = threadIdx.x; c < C; c += blockDim.x){
    float s=0,q=0;
    for (int b=0;b<64;b++){ s += buck[(long)b*2*C + c]; q += buck[(long)b*2*C + C + c]; }
    float m = s*invn;
    float v = fmaxf(q*invn - m*m, 0.f);
    mr[c] = m; mr[C+c] = rsqrtf(v + EPS);
  }
}

// ---------------- BN+leaky on raw qkv -> key, q|v, sq ----------------
__global__ __launch_bounds__(256) void k_apply_qkv(const float* __restrict__ raw, const float* __restrict__ mr,
    const float* __restrict__ gq, const float* __restrict__ bq,
    const float* __restrict__ gk, const float* __restrict__ bk,
    const float* __restrict__ gv, const float* __restrict__ bv,
    float* __restrict__ key, float* __restrict__ qv, float* __restrict__ sq){
  const int r = blockIdx.x, tid = threadIdx.x;
  __shared__ float red[256];
  const float* row = raw + (long)r*768;
  float zq = row[tid], zk = row[256+tid], zv = row[512+tid];
  float yq = leakyf((zq - mr[tid])*mr[768+tid]*gq[tid] + bq[tid]);
  float yk = leakyf((zk - mr[256+tid])*mr[1024+tid]*gk[tid] + bk[tid]);
  float yv = leakyf((zv - mr[512+tid])*mr[1280+tid]*gv[tid] + bv[tid]);
  qv[(long)r*512 + tid] = yq;
  key[(long)r*256 + tid] = yk;
  qv[(long)r*512 + 256 + tid] = yv;
  red[tid] = yk*yk; __syncthreads();
  for (int off=128; off; off>>=1){ if (tid<off) red[tid] += red[tid+off]; __syncthreads(); }
  if (tid==0) sq[r] = red[0];
}

// ---------------- top-K (K=32) smallest dist per row; one wave per row ----------------
__global__ __launch_bounds__(256) void k_topk(const float* __restrict__ G, const float* __restrict__ sqb,
    int* __restrict__ idxb){
  __shared__ float dist[4][2048];
  const int wv = threadIdx.x >> 6, lane = threadIdx.x & 63;
  const int n = blockIdx.x*4 + wv;
  const float* Grow = G + (long)n*2048;
  const float sqn = sqb[n];
  float lmin = 3.4e38f; int lidx = 0;
  for (int j=0;j<32;j++){
    int m = lane + j*64;
    float d = sqn + sqb[m] - 2.f*Grow[m];
    dist[wv][m] = d;
    if (d < lmin){ lmin = d; lidx = m; }
  }
  int* orow = idxb + n*32;
  for (int t=0;t<32;t++){
    float v = lmin; int i = lidx;
    for (int off=32; off; off>>=1){
      float v2 = __shfl_xor(v, off, 64);
      int i2 = __shfl_xor(i, off, 64);
      if (v2 < v || (v2 == v && i2 < i)){ v = v2; i = i2; }
    }
    if (lane == 0) orow[t] = i;
    if ((i & 63) == lane){
      dist[wv][i] = 3.4e38f;
      lmin = 3.4e38f; lidx = 0;
      for (int j=0;j<32;j++){
        int m = lane + j*64;
        float d = dist[wv][m];
        if (d < lmin){ lmin = d; lidx = m; }
      }
    }
  }
}

// ---------------- stats of z_pb = P[idx]-P[n] ----------------
__global__ __launch_bounds__(256) void k_stats_pb(const float* __restrict__ P, const int* __restrict__ idx,
    float* __restrict__ buck){
  const int c = threadIdx.x;
  float s=0,q=0;
  for (int r = blockIdx.x; r < 4096; r += gridDim.x){
    const long base = (long)(r >> 11) << 11;
    const float pn = P[(long)r*256 + c];
    const int* ir = idx + r*32;
    for (int k=0;k<32;k++){
      int g = ir[k];
      float z = P[(base + g)*256 + c] - pn;
      s += z; q += z*z;
    }
  }
  float* bb = buck + (long)(blockIdx.x & 63)*512;
  atomicAdd(&bb[c], s); atomicAdd(&bb[256+c], q);
}

// ---------------- KW = key@We1^T, QW = q@We1^T  (R[z][4096][32]) ----------------
__global__ __launch_bounds__(256) void k_kwqw(const float* __restrict__ key, const float* __restrict__ qv,
    const float* __restrict__ We1, float* __restrict__ KWQW){
  __shared__ float Wt[256*33];   // [c][d] padded
  __shared__ float Rs[8*260];
  const int tid = threadIdx.x;
  const int z = blockIdx.y;
  const float* src = z ? qv : key;
  const int ld = z ? 512 : 256;
  for (int e = tid*4; e < 8192; e += 1024){
    float4 w4 = *(const float4*)(We1 + e);
    int d = e >> 8, c = e & 255;
    Wt[(c+0)*33+d]=w4.x; Wt[(c+1)*33+d]=w4.y; Wt[(c+2)*33+d]=w4.z; Wt[(c+3)*33+d]=w4.w;
  }
  const int rbase = blockIdx.x*16;
  for (int h=0; h<2; h++){
    __syncthreads();
    for (int e = tid*4; e < 2048; e += 1024){
      int r = e >> 8, c = e & 255;
      *(float4*)&Rs[r*260+c] = *(const float4*)(src + (long)(rbase + h*8 + r)*ld + c);
    }
    __syncthreads();
    const int rl = tid>>5, d = tid&31;
    float acc=0.f;
    for (int c=0;c<256;c++) acc = fmaf(Rs[rl*260+c], Wt[c*33+d], acc);
    KWQW[(long)z*131072 + (long)(rbase+h*8+rl)*32 + d] = acc;
  }
}

// ---------------- E1[bn,kk,d] = posb@We1^T + KW[g] - QW[n]; fused stats ----------------
__global__ __launch_bounds__(256) void k_e1(
    const float* __restrict__ P, const int* __restrict__ idx, const float* __restrict__ KWQW,
    const float* __restrict__ mrPB, const float* __restrict__ gpb, const float* __restrict__ bpb,
    const float* __restrict__ We1, float* __restrict__ E1, float* __restrict__ buckE1)
{
  __shared__ float Vs[16*260];     // posb rows [k][c] stride 260
  __shared__ unsigned Wp[16*260];  // bf16 pairs: Wp[t][c] = (bf16 W[2t][c]) | (bf16 W[2t+1][c] << 16)
  const int tid = threadIdx.x;
  const int bn = blockIdx.x >> 1;
  const int kh = (blockIdx.x & 1)*16;
  const long base = (long)(bn >> 11) << 11;
  for (int e = tid; e < 4096; e += 256){
    int t = e >> 8, c = e & 255;
    unsigned u0 = f2bfu(We1[(long)(2*t)*256 + c]);
    unsigned u1 = f2bfu(We1[(long)(2*t+1)*256 + c]);
    Wp[t*260 + c] = u0 | (u1 << 16);
  }
  {
    const int lane = tid & 63, wv = tid >> 6;
    const int c4 = lane*4;
    float4 p4  = *(const float4*)(P + (long)bn*256 + c4);
    float4 mp4 = *(const float4*)(mrPB + c4);
    float4 rp4 = *(const float4*)(mrPB + 256 + c4);
    float4 g4  = *(const float4*)(gpb + c4);
    float4 b4  = *(const float4*)(bpb + c4);
    for (int j = 0; j < 4; ++j){
      const int kl = wv*4 + j;
      const int g = idx[bn*32 + kh + kl];
      float4 pb4 = *(const float4*)(P + (base+g)*256 + c4);
      float4 o;
      o.x = leakyf((pb4.x - p4.x - mp4.x)*rp4.x*g4.x + b4.x);
      o.y = leakyf((pb4.y - p4.y - mp4.y)*rp4.y*g4.y + b4.y);
      o.z = leakyf((pb4.z - p4.z - mp4.z)*rp4.z*g4.z + b4.z);
      o.w = leakyf((pb4.w - p4.w - mp4.w)*rp4.w*g4.w + b4.w);
      *(float4*)&Vs[kl*260 + c4] = o;
    }
  }
  __syncthreads();
  const int t = tid & 15, kl = tid >> 4;
  const int g2 = idx[bn*32 + kh + kl];
  float acc0=0.f, acc1=0.f;
  const float* vrow = &Vs[kl*260];
  const unsigned* wrow = &Wp[t*260];
  for (int c = 0; c < 256; c += 2){
    float2 a2 = *(const float2*)(vrow + c);
    unsigned w0 = wrow[c], w1 = wrow[c+1];
    acc0 = fmaf(a2.x, bflo(w0), acc0); acc1 = fmaf(a2.x, bfhi(w0), acc1);
    acc0 = fmaf(a2.y, bflo(w1), acc0); acc1 = fmaf(a2.y, bfhi(w1), acc1);
  }
  const float* kwr = KWQW + (long)(base+g2)*32;
  const float* qwr = KWQW + 131072 + (long)bn*32;
  const int d0 = 2*t;
  float o0 = acc0 + kwr[d0]   - qwr[d0];
  float o1 = acc1 + kwr[d0+1] - qwr[d0+1];
  float2 o2; o2.x = o0; o2.y = o1;
  *(float2*)(E1 + ((long)bn*32 + kh + kl)*32 + d0) = o2;
  // fused stats
  __syncthreads();
  float* Sm = Vs;
  Sm[kl*34 + d0] = o0; Sm[kl*34 + d0+1] = o1;
  __syncthreads();
  if (tid < 32){
    float s=0.f, q=0.f;
    for (int k2=0;k2<16;k2++){ float v = Sm[k2*34 + tid]; s += v; q += v*v; }
    float* bb = buckE1 + (long)(blockIdx.x & 63)*64;
    atomicAdd(&bb[tid], s); atomicAdd(&bb[32+tid], q);
  }
}

// ---------------- E2 = leaky(bn(E1)) @ We2^T, IN PLACE; fused stats ----------------
__global__ __launch_bounds__(64) void k_e2(
    float* __restrict__ E, const float* __restrict__ mrE1,
    const float* __restrict__ ge1, const float* __restrict__ be1,
    const float* __restrict__ We2, float* __restrict__ buckE2)
{
  __shared__ float Ts[32*33];
  __shared__ float W2[32*33];
  const int lane = threadIdx.x;
  const int bn = blockIdx.x;
  for (int i=0;i<16;i++){
    int e = lane + i*64;
    int k = e >> 5, c = e & 31;
    float v = E[(long)bn*1024 + e];
    Ts[k*33 + c] = leakyf((v - mrE1[c]) * mrE1[32+c] * ge1[c] + be1[c]);
    W2[c*33 + k] = We2[e];
  }
  __syncthreads();
  const int k  = lane >> 1;
  const int d0 = (lane & 1)*16;
  float acc[16];
  #pragma unroll
  for (int i=0;i<16;i++) acc[i]=0.f;
  for (int c=0;c<32;c++){
    float a = Ts[k*33+c];
    #pragma unroll
    for (int dd=0;dd<16;dd++) acc[dd] = fmaf(a, W2[c*33 + d0+dd], acc[dd]);
  }
  float* o = E + (long)bn*1024 + k*32 + d0;
  #pragma unroll
  for (int dd=0;dd<16;dd++) o[dd] = acc[dd];
  // fused stats
  __syncthreads();
  #pragma unroll
  for (int dd=0;dd<16;dd++) Ts[k*33 + d0+dd] = acc[dd];
  __syncthreads();
  if (lane < 32){
    float s=0.f, q=0.f;
    for (int k2=0;k2<32;k2++){ float v = Ts[k2*33 + lane]; s += v; q += v*v; }
    float* bb = buckE2 + (long)(blockIdx.x & 63)*64;
    atomicAdd(&bb[lane], s); atomicAdd(&bb[32+lane], q);
  }
}

// ---------------- softmax over k + attention + residual ----------------
__global__ __launch_bounds__(64) void k_attn(
    const float* __restrict__ E2, const float* __restrict__ mrE2,
    const float* __restrict__ ge2, const float* __restrict__ be2,
    const float* __restrict__ qv, const float* __restrict__ P, const int* __restrict__ idx,
    const float* __restrict__ mrPB, const float* __restrict__ gpb, const float* __restrict__ bpb,
    const float* __restrict__ xin, float* __restrict__ x2)
{
  __shared__ float L[32][33];
  const int lane = threadIdx.x;
  const int bn = blockIdx.x;
  const long base = (long)(bn >> 11) << 11;
  for (int qq=0; qq<4; qq++){
    int e = lane*16 + qq*4;
    int k = e >> 5, g0 = e & 31;
    float4 v  = *(const float4*)(E2 + (long)bn*1024 + e);
    float4 m4 = *(const float4*)(mrE2 + g0);
    float4 r4 = *(const float4*)(mrE2 + 32 + g0);
    float4 g4 = *(const float4*)(ge2 + g0);
    float4 b4 = *(const float4*)(be2 + g0);
    L[k][g0+0] = leakyf((v.x - m4.x)*r4.x*g4.x + b4.x);
    L[k][g0+1] = leakyf((v.y - m4.y)*r4.y*g4.y + b4.y);
    L[k][g0+2] = leakyf((v.z - m4.z)*r4.z*g4.z + b4.z);
    L[k][g0+3] = leakyf((v.w - m4.w)*r4.w*g4.w + b4.w);
  }
  __syncthreads();
  {
    const int g = lane & 31, h = lane >> 5;
    float mx = -3.4e38f;
    for (int j=0;j<16;j++) mx = fmaxf(mx, L[h*16+j][g]);
    mx = fmaxf(mx, __shfl_xor(mx, 32, 64));
    float sm = 0.f, ev[16];
    for (int j=0;j<16;j++){ float e_ = __expf(L[h*16+j][g] - mx); ev[j] = e_; sm += e_; }
    sm += __shfl_xor(sm, 32, 64);
    float inv = 1.f/sm;
    for (int j=0;j<16;j++) L[h*16+j][g] = ev[j]*inv;
  }
  __syncthreads();
  const int c4 = lane*4, gg = lane >> 1;
  float4 pn4 = *(const float4*)(P + (long)bn*256 + c4);
  float4 mp4 = *(const float4*)(mrPB + c4);
  float4 rp4 = *(const float4*)(mrPB + 256 + c4);
  float4 g4 = *(const float4*)(gpb + c4);
  float4 b4 = *(const float4*)(bpb + c4);
  float accv[4] = {0,0,0,0};
  const int* ir = idx + bn*32;
  for (int k=0;k<32;k++){
    int gi = ir[k];
    float4 vv = *(const float4*)(qv + (long)(base+gi)*512 + 256 + c4);
    float4 pp = *(const float4*)(P + (base+gi)*256 + c4);
    float w = L[k][gg];
    float zh0 = (pp.x - pn4.x - mp4.x)*rp4.x*g4.x + b4.x;
    float zh1 = (pp.y - pn4.y - mp4.y)*rp4.y*g4.y + b4.y;
    float zh2 = (pp.z - pn4.z - mp4.z)*rp4.z*g4.z + b4.z;
    float zh3 = (pp.w - pn4.w - mp4.w)*rp4.w*g4.w + b4.w;
    accv[0] = fmaf(vv.x + leakyf(zh0), w, accv[0]);
    accv[1] = fmaf(vv.y + leakyf(zh1), w, accv[1]);
    accv[2] = fmaf(vv.z + leakyf(zh2), w, accv[2]);
    accv[3] = fmaf(vv.w + leakyf(zh3), w, accv[3]);
  }
  float4 x4 = *(const float4*)(xin + (long)bn*256 + c4);
  float4 o;
  o.x = x4.x + accv[0]; o.y = x4.y + accv[1];
  o.z = x4.z + accv[2]; o.w = x4.w + accv[3];
  *(float4*)(x2 + (long)bn*256 + c4) = o;
}

// ---------------- final: out = x2 + silu(bn(Zm2)) ----------------
__global__ __launch_bounds__(256) void k_final(const float* __restrict__ x2, const float* __restrict__ Zm2,
    const float* __restrict__ mr, const float* __restrict__ gm, const float* __restrict__ bm,
    float* __restrict__ out){
  const int r = blockIdx.x, c = threadIdx.x;
  float z = Zm2[(long)r*256 + c];
  float y = (z - mr[c])*mr[256+c]*gm[c] + bm[c];
  out[(long)r*256 + c] = x2[(long)r*256 + c] + siluf(y);
}

extern "C" void kernel_launch(void* const* d_in, const int* in_sizes, int n_in,
                              void* d_out, int out_size, void* d_ws, size_t ws_size,
                              hipStream_t stream){
  (void)in_sizes; (void)n_in; (void)out_size; (void)ws_size;
  const float* x   = (const float*)d_in[0];
  const float* pos = (const float*)d_in[1];
  const float* Wq  = (const float*)d_in[2];
  const float* gq  = (const float*)d_in[3];
  const float* bq  = (const float*)d_in[4];
  const float* Wk  = (const float*)d_in[5];
  const float* gk  = (const float*)d_in[6];
  const float* bk  = (const float*)d_in[7];
  const float* Wv  = (const float*)d_in[8];
  const float* gv  = (const float*)d_in[9];
  const float* bv  = (const float*)d_in[10];
  const float* Wpb = (const float*)d_in[11];
  const float* gpb = (const float*)d_in[12];
  const float* bpb = (const float*)d_in[13];
  const float* We1 = (const float*)d_in[14];
  const float* ge1 = (const float*)d_in[15];
  const float* be1 = (const float*)d_in[16];
  const float* We2 = (const float*)d_in[17];
  const float* ge2 = (const float*)d_in[18];
  const float* be2 = (const float*)d_in[19];
  const float* Wm1 = (const float*)d_in[20];
  const float* gm1 = (const float*)d_in[21];
  const float* bm1 = (const float*)d_in[22];
  const float* Wm2 = (const float*)d_in[23];
  const float* gm2 = (const float*)d_in[24];
  const float* bm2 = (const float*)d_in[25];

  // workspace (float offsets) — same 39.3 MB envelope as the passing rounds
  float* w     = (float*)d_ws;
  float* arena = w;                       // 4,194,304: rawQKV / G / E1->E2 / Zm1+Zm2
  float* key   = w + 4194304;             // 1,048,576
  float* P     = w + 5242880;             // 1,048,576
  float* x2    = w + 6291456;             // 1,048,576 (KWQW aliases here pre-attn)
  float* qv    = w + 7340032;             // 2,097,152 (q|v per row, stride 512)
  float* sq    = w + 9437184;             // 4,096
  int*   idx   = (int*)(w + 9441280);     // 131,072 ints
  float* buck  = w + 9572352;             // 237,568
  float* mr    = w + 9809920;             // 3,712
  float* KWQW  = x2;                      // [2][4096][32] = 262,144 floats, dead before x2 written
  float* bQKV = buck;            float* bPB = buck + 98304;  float* bE1 = buck + 131072;
  float* bE2  = buck + 135168;   float* bM1 = buck + 139264; float* bM2 = buck + 204800;
  float* mrQKV = mr;        float* mrPB = mr + 1536; float* mrE1 = mr + 2048;
  float* mrE2  = mr + 2112; float* mrM1 = mr + 2176; float* mrM2 = mr + 3200;
  float* Zm1 = arena;
  float* Zm2 = arena + 2097152;

  k_zero<<<943,256,0,stream>>>(buck, 241280);
  // raw qkv = x @ {Wq,Wk,Wv}^T, stats fused
  k_gemm<false,true><<<dim3(32,2,3),256,0,stream>>>(x,256, nullptr,nullptr,nullptr,0,
      Wq,Wk,Wv,256, arena,768,256, 256, bQKV,768,256);
  // P = pos @ Wpb^T
  k_gemm<false,false><<<dim3(32,2,1),256,0,stream>>>(pos,256, nullptr,nullptr,nullptr,0,
      Wpb,Wpb,Wpb,256, P,256,0, 256, nullptr,0,0);
  k_finalize<<<1,256,0,stream>>>(bQKV, 768, 1.f/4096.f, mrQKV);
  k_apply_qkv<<<4096,256,0,stream>>>(arena, mrQKV, gq,bq,gk,bk,gv,bv, key, qv, sq);
  // per-batch Gram + topk
  k_gemm<false,false><<<dim3(16,16,1),256,0,stream>>>(key,256, nullptr,nullptr,nullptr,0,
      key,key,key,256, arena,2048,0, 256, nullptr,0,0);
  k_topk<<<512,256,0,stream>>>(arena, sq, idx);
  k_gemm<false,false><<<dim3(16,16,1),256,0,stream>>>(key+524288,256, nullptr,nullptr,nullptr,0,
      key+524288,key+524288,key+524288,256, arena,2048,0, 256, nullptr,0,0);
  k_topk<<<512,256,0,stream>>>(arena, sq+2048, idx+65536);
  k_stats_pb<<<256,256,0,stream>>>(P, idx, bPB);
  k_finalize<<<1,256,0,stream>>>(bPB, 256, 1.f/131072.f, mrPB);
  k_kwqw<<<dim3(256,2),256,0,stream>>>(key, qv, We1, KWQW);
  k_e1<<<8192,256,0,stream>>>(P, idx, KWQW, mrPB, gpb, bpb, We1, arena, bE1);
  k_finalize<<<1,256,0,stream>>>(bE1, 32, 1.f/131072.f, mrE1);
  k_e2<<<4096,64,0,stream>>>(arena, mrE1, ge1, be1, We2, bE2);
  k_finalize<<<1,256,0,stream>>>(bE2, 32, 1.f/131072.f, mrE2);
  k_attn<<<4096,64,0,stream>>>(arena, mrE2, ge2, be2, qv, P, idx, mrPB, gpb, bpb, x, x2);
  // MLP
  k_gemm<false,true><<<dim3(32,4,1),256,0,stream>>>(x2,256, nullptr,nullptr,nullptr,0,
      Wm1,Wm1,Wm1,256, Zm1,512,0, 256, bM1,512,0);
  k_finalize<<<1,256,0,stream>>>(bM1, 512, 1.f/4096.f, mrM1);
  k_gemm<true,true><<<dim3(32,2,1),256,0,stream>>>(Zm1,512, mrM1,gm1,bm1,512,
      Wm2,Wm2,Wm2,512, Zm2,256,0, 512, bM2,256,0);
  k_finalize<<<1,256,0,stream>>>(bM2, 256, 1.f/4096.f, mrM2);
  k_final<<<4096,256,0,stream>>>(x2, Zm2, mrM2, gm2, bm2, (float*)d_out);
}

// Round 6
// 490.359 us; speedup vs baseline: 1.5104x; 1.1479x over previous
//
#include <hip/hip_runtime.h>

#define EPS 1e-5f

typedef __attribute__((ext_vector_type(8))) short s8v;
typedef __attribute__((ext_vector_type(4))) float f4v;

__device__ __forceinline__ float leakyf(float z){ return z >= 0.f ? z : 0.2f*z; }
__device__ __forceinline__ float siluf(float y){ return y / (1.f + __expf(-y)); }
__device__ __forceinline__ unsigned f2bfu(float f){
  unsigned u = __float_as_uint(f);
  return (u + 0x7FFFu + ((u>>16)&1u)) >> 16;
}
__device__ __forceinline__ unsigned short bfr(float f){ return (unsigned short)f2bfu(f); }
__device__ __forceinline__ float bf2f16(unsigned short s){ return __uint_as_float(((unsigned)s)<<16); }

// ---------------- zero scratch ----------------
__global__ __launch_bounds__(256) void k_zero(float* __restrict__ p, int n){
  int i = blockIdx.x*256 + threadIdx.x;
  if (i < n) p[i] = 0.f;
}

// ------- NT GEMM via split-bf16 MFMA (4 products = f32 fidelity) -------
template<bool TRANSA, bool STATS>
__global__ __launch_bounds__(256) void k_gemm(
    const float* __restrict__ A, int lda,
    const float* __restrict__ tA, const float* __restrict__ gA, const float* __restrict__ bA, int CA,
    const float* __restrict__ B0, const float* __restrict__ B1, const float* __restrict__ B2,
    int ldb, float* __restrict__ C, int ldc, long cStr, int K,
    float* __restrict__ buck, int statC, int statChanStr)
{
  __shared__ unsigned short Ah[4096], Al[4096], Bh[4096], Bl[4096];
  __shared__ float Ssum[128], Ssq[128];
  const int z = blockIdx.z;
  const float* Bb = (z==0?B0:(z==1?B1:B2));
  float* Cb = C + (long)z*cStr;
  const int tid = threadIdx.x;
  const int bm = blockIdx.x*128, bn = blockIdx.y*128;
  const int wv = tid>>6, lane = tid&63;
  const int wr = wv>>1, wc = wv&1;
  const int lm = lane&15, quad = lane>>4;
  if (STATS && tid<128){ Ssum[tid]=0.f; Ssq[tid]=0.f; }
  f4v acc[4][4];
  #pragma unroll
  for (int i=0;i<4;i++)
    #pragma unroll
    for (int j=0;j<4;j++) acc[i][j] = (f4v){0.f,0.f,0.f,0.f};

  for (int k0=0; k0<K; k0+=32){
    #pragma unroll
    for (int it=0; it<4; it++){
      const int e = tid + it*256;
      const int row = e>>3, kg = e&7;
      const int off = (((row>>4)*4 + (kg>>1))*16 + (row&15))*8 + (kg&1)*4;
      float4 av = *(const float4*)(A + (long)(bm+row)*lda + k0 + kg*4);
      if (TRANSA){
        const float* tm = tA + k0 + kg*4;
        float4 m4 = *(const float4*)tm;
        float4 r4 = *(const float4*)(tm + CA);
        float4 g4 = *(const float4*)(gA + k0 + kg*4);
        float4 b4 = *(const float4*)(bA + k0 + kg*4);
        av.x = siluf((av.x - m4.x)*r4.x*g4.x + b4.x);
        av.y = siluf((av.y - m4.y)*r4.y*g4.y + b4.y);
        av.z = siluf((av.z - m4.z)*r4.z*g4.z + b4.z);
        av.w = siluf((av.w - m4.w)*r4.w*g4.w + b4.w);
      }
      ushort4 h4, l4;
      h4.x = bfr(av.x); l4.x = bfr(av.x - bf2f16(h4.x));
      h4.y = bfr(av.y); l4.y = bfr(av.y - bf2f16(h4.y));
      h4.z = bfr(av.z); l4.z = bfr(av.z - bf2f16(h4.z));
      h4.w = bfr(av.w); l4.w = bfr(av.w - bf2f16(h4.w));
      *(ushort4*)&Ah[off] = h4;
      *(ushort4*)&Al[off] = l4;
      float4 bv = *(const float4*)(Bb + (long)(bn+row)*ldb + k0 + kg*4);
      h4.x = bfr(bv.x); l4.x = bfr(bv.x - bf2f16(h4.x));
      h4.y = bfr(bv.y); l4.y = bfr(bv.y - bf2f16(h4.y));
      h4.z = bfr(bv.z); l4.z = bfr(bv.z - bf2f16(h4.z));
      h4.w = bfr(bv.w); l4.w = bfr(bv.w - bf2f16(h4.w));
      *(ushort4*)&Bh[off] = h4;
      *(ushort4*)&Bl[off] = l4;
    }
    __syncthreads();
    s8v ah[4], am[4], bh[4], bm_[4];
    #pragma unroll
    for (int i=0;i<4;i++){
      const int ao = (((wr*4+i)*4 + quad)*16 + lm)*8;
      ah[i] = *(const s8v*)&Ah[ao];
      am[i] = *(const s8v*)&Al[ao];
      const int bo = (((wc*4+i)*4 + quad)*16 + lm)*8;
      bh[i]  = *(const s8v*)&Bh[bo];
      bm_[i] = *(const s8v*)&Bl[bo];
    }
    #pragma unroll
    for (int i=0;i<4;i++)
      #pragma unroll
      for (int j=0;j<4;j++){
        acc[i][j] = __builtin_amdgcn_mfma_f32_16x16x32_bf16(ah[i], bh[j],  acc[i][j], 0,0,0);
        acc[i][j] = __builtin_amdgcn_mfma_f32_16x16x32_bf16(ah[i], bm_[j], acc[i][j], 0,0,0);
        acc[i][j] = __builtin_amdgcn_mfma_f32_16x16x32_bf16(am[i], bh[j],  acc[i][j], 0,0,0);
        acc[i][j] = __builtin_amdgcn_mfma_f32_16x16x32_bf16(am[i], bm_[j], acc[i][j], 0,0,0);
      }
    __syncthreads();
  }
  #pragma unroll
  for (int i=0;i<4;i++){
    #pragma unroll
    for (int rr=0;rr<4;rr++){
      float* cr = Cb + (long)(bm + wr*64 + i*16 + quad*4 + rr)*ldc + bn + wc*64 + lm;
      #pragma unroll
      for (int j=0;j<4;j++) cr[j*16] = acc[i][j][rr];
    }
  }
  if (STATS){
    #pragma unroll
    for (int j=0;j<4;j++){
      float s=0.f, q=0.f;
      #pragma unroll
      for (int i=0;i<4;i++)
        #pragma unroll
        for (int rr=0;rr<4;rr++){ float v = acc[i][j][rr]; s += v; q += v*v; }
      atomicAdd(&Ssum[wc*64 + j*16 + lm], s);
      atomicAdd(&Ssq [wc*64 + j*16 + lm], q);
    }
    __syncthreads();
    if (tid < 128){
      int chan = statChanStr*z + bn + tid;
      float* bb = buck + (long)(blockIdx.x & 63)*2*statC;
      atomicAdd(&bb[chan], Ssum[tid]);
      atomicAdd(&bb[statC + chan], Ssq[tid]);
    }
  }
}

__global__ void k_finalize(const float* __restrict__ buck, int C, float invn, float* __restrict__ mr){
  int c = blockIdx.x*256 + threadIdx.x;
  if (c < C){
    float s=0,q=0;
    for (int b=0;b<64;b++){ s += buck[(long)b*2*C + c]; q += buck[(long)b*2*C + C + c]; }
    float m = s*invn;
    float v = fmaxf(q*invn - m*m, 0.f);
    mr[c] = m; mr[C+c] = rsqrtf(v + EPS);
  }
}

// ---------------- BN+leaky on raw qkv -> key, q|v, sq ----------------
__global__ __launch_bounds__(256) void k_apply_qkv(const float* __restrict__ raw, const float* __restrict__ mr,
    const float* __restrict__ gq, const float* __restrict__ bq,
    const float* __restrict__ gk, const float* __restrict__ bk,
    const float* __restrict__ gv, const float* __restrict__ bv,
    float* __restrict__ key, float* __restrict__ qv, float* __restrict__ sq){
  const int r = blockIdx.x, tid = threadIdx.x;
  __shared__ float red[256];
  const float* row = raw + (long)r*768;
  float zq = row[tid], zk = row[256+tid], zv = row[512+tid];
  float yq = leakyf((zq - mr[tid])*mr[768+tid]*gq[tid] + bq[tid]);
  float yk = leakyf((zk - mr[256+tid])*mr[1024+tid]*gk[tid] + bk[tid]);
  float yv = leakyf((zv - mr[512+tid])*mr[1280+tid]*gv[tid] + bv[tid]);
  qv[(long)r*512 + tid] = yq;
  key[(long)r*256 + tid] = yk;
  qv[(long)r*512 + 256 + tid] = yv;
  red[tid] = yk*yk; __syncthreads();
  for (int off=128; off; off>>=1){ if (tid<off) red[tid] += red[tid+off]; __syncthreads(); }
  if (tid==0) sq[r] = red[0];
}

// ---------------- top-K (K=32) smallest dist per row; one wave per row ----------------
__global__ __launch_bounds__(256) void k_topk(const float* __restrict__ G, const float* __restrict__ sqb,
    int* __restrict__ idxb){
  __shared__ float dist[4][2048];
  const int wv = threadIdx.x >> 6, lane = threadIdx.x & 63;
  const int n = blockIdx.x*4 + wv;
  const float* Grow = G + (long)n*2048;
  const float sqn = sqb[n];
  float lmin = 3.4e38f; int lidx = 0;
  for (int j=0;j<32;j++){
    int m = lane + j*64;
    float d = sqn + sqb[m] - 2.f*Grow[m];
    dist[wv][m] = d;
    if (d < lmin){ lmin = d; lidx = m; }
  }
  int* orow = idxb + n*32;
  for (int t=0;t<32;t++){
    float v = lmin; int i = lidx;
    for (int off=32; off; off>>=1){
      float v2 = __shfl_xor(v, off, 64);
      int i2 = __shfl_xor(i, off, 64);
      if (v2 < v || (v2 == v && i2 < i)){ v = v2; i = i2; }
    }
    if (lane == 0) orow[t] = i;
    if ((i & 63) == lane){
      dist[wv][i] = 3.4e38f;
      lmin = 3.4e38f; lidx = 0;
      for (int j=0;j<32;j++){
        int m = lane + j*64;
        float d = dist[wv][m];
        if (d < lmin){ lmin = d; lidx = m; }
      }
    }
  }
}

// ---------------- stats of z_pb = P[idx]-P[n] ----------------
__global__ __launch_bounds__(256) void k_stats_pb(const float* __restrict__ P, const int* __restrict__ idx,
    float* __restrict__ buck){
  const int c = threadIdx.x;
  float s=0,q=0;
  for (int r = blockIdx.x; r < 4096; r += gridDim.x){
    const long base = (long)(r >> 11) << 11;
    const float pn = P[(long)r*256 + c];
    const int* ir = idx + r*32;
    for (int k=0;k<32;k++){
      int g = ir[k];
      float z = P[(base + g)*256 + c] - pn;
      s += z; q += z*z;
    }
  }
  float* bb = buck + (long)(blockIdx.x & 63)*512;
  atomicAdd(&bb[c], s); atomicAdd(&bb[256+c], q);
}

// ---------------- E1 = (key[g]-q[n]+posb) @ We1^T via MFMA; fused stats ----------------
// Block: 256 thr / 4 waves, 2 bn (64 rows). A: bf16 frag-major, slot swizzle m^2ks^quad.
__global__ __launch_bounds__(256) void k_e1m(
    const float* __restrict__ key, const float* __restrict__ qv, const float* __restrict__ P,
    const int* __restrict__ idx, const float* __restrict__ mrPB,
    const float* __restrict__ gpb, const float* __restrict__ bpb,
    const float* __restrict__ We1, float* __restrict__ E1, float* __restrict__ buckE1)
{
  __shared__ unsigned short Ab[16384];  // 64 rows x 256 k (32 KB)
  __shared__ unsigned short Wb[8192];   // 32 d x 256 k (16 KB)
  __shared__ float Ssum[32], Ssq[32];
  const int tid = threadIdx.x;
  const int wv = tid>>6, lane = tid&63;
  const int quad = lane>>4, lm = lane&15;
  const int bn0 = blockIdx.x*2;
  if (tid < 32){ Ssum[tid]=0.f; Ssq[tid]=0.f; }
  // stage weights (unswizzled slots)
  for (int e = tid; e < 8192; e += 256){
    int d = e >> 8, c = e & 255;
    int off = (((d>>4)*8 + (c>>5))*4 + ((c>>3)&3))*128 + (d&15)*8 + (c&7);
    Wb[off] = bfr(We1[e]);
  }
  // stage A: wave wv -> local rows wv*16 .. +15
  {
    const int bn = bn0 + (wv>>1);
    const long base = (long)(bn >> 11) << 11;
    const int c4 = lane*4;
    float4 q4  = *(const float4*)(qv + (long)bn*512 + c4);
    float4 pn4 = *(const float4*)(P + (long)bn*256 + c4);
    float4 mp4 = *(const float4*)(mrPB + c4);
    float4 rp4 = *(const float4*)(mrPB + 256 + c4);
    float4 g4  = *(const float4*)(gpb + c4);
    float4 b4  = *(const float4*)(bpb + c4);
    const int ksc = c4>>5, quadc = (c4>>3)&3, jc = c4&7;
    for (int j = 0; j < 16; ++j){
      const int rloc = wv*16 + j;
      const int kk = rloc & 31;
      const int g = idx[bn*32 + kk];
      float4 kb = *(const float4*)(key + (base+g)*256 + c4);
      float4 pb = *(const float4*)(P + (base+g)*256 + c4);
      float o0 = kb.x - q4.x + leakyf((pb.x - pn4.x - mp4.x)*rp4.x*g4.x + b4.x);
      float o1 = kb.y - q4.y + leakyf((pb.y - pn4.y - mp4.y)*rp4.y*g4.y + b4.y);
      float o2 = kb.z - q4.z + leakyf((pb.z - pn4.z - mp4.z)*rp4.z*g4.z + b4.z);
      float o3 = kb.w - q4.w + leakyf((pb.w - pn4.w - mp4.w)*rp4.w*g4.w + b4.w);
      const int atile = rloc >> 4;   // == wv
      const int slot = ((rloc & 15) ^ (ksc<<1) ^ quadc) & 15;
      const int off = ((atile*8 + ksc)*4 + quadc)*128 + slot*8 + jc;
      ushort4 u; u.x = bfr(o0); u.y = bfr(o1); u.z = bfr(o2); u.w = bfr(o3);
      *(ushort4*)&Ab[off] = u;
    }
  }
  __syncthreads();
  // MFMA: wave's tile = wv (rows wv*16..+15), both n-tiles, 8 k-steps
  f4v acc0 = (f4v){0,0,0,0}, acc1 = (f4v){0,0,0,0};
  #pragma unroll
  for (int ks=0; ks<8; ks++){
    const int aslot = (lm ^ (ks<<1) ^ quad) & 15;
    s8v a  = *(const s8v*)&Ab[((wv*8 + ks)*4 + quad)*128 + aslot*8];
    s8v b0 = *(const s8v*)&Wb[((ks)*4 + quad)*128 + lm*8];
    s8v b1 = *(const s8v*)&Wb[((8 + ks)*4 + quad)*128 + lm*8];
    acc0 = __builtin_amdgcn_mfma_f32_16x16x32_bf16(a, b0, acc0, 0,0,0);
    acc1 = __builtin_amdgcn_mfma_f32_16x16x32_bf16(a, b1, acc1, 0,0,0);
  }
  // write out: D row = quad*4+rr (k-row within tile), col = lm (d)
  {
    const int bn = bn0 + (wv>>1);
    const int mt = wv & 1;
    #pragma unroll
    for (int rr=0; rr<4; rr++){
      int krow = mt*16 + quad*4 + rr;
      float* o = E1 + ((long)bn*32 + krow)*32;
      o[lm]      = acc0[rr];
      o[16 + lm] = acc1[rr];
    }
  }
  // stats
  float s0=0,q0=0,s1=0,q1=0;
  #pragma unroll
  for (int rr=0; rr<4; rr++){
    s0 += acc0[rr]; q0 += acc0[rr]*acc0[rr];
    s1 += acc1[rr]; q1 += acc1[rr]*acc1[rr];
  }
  s0 += __shfl_xor(s0,16,64); s0 += __shfl_xor(s0,32,64);
  q0 += __shfl_xor(q0,16,64); q0 += __shfl_xor(q0,32,64);
  s1 += __shfl_xor(s1,16,64); s1 += __shfl_xor(s1,32,64);
  q1 += __shfl_xor(q1,16,64); q1 += __shfl_xor(q1,32,64);
  if (quad == 0){
    atomicAdd(&Ssum[lm], s0);      atomicAdd(&Ssq[lm], q0);
    atomicAdd(&Ssum[16+lm], s1);   atomicAdd(&Ssq[16+lm], q1);
  }
  __syncthreads();
  if (tid < 32){
    float* bb = buckE1 + (long)(blockIdx.x & 63)*64;
    atomicAdd(&bb[tid], Ssum[tid]); atomicAdd(&bb[32+tid], Ssq[tid]);
  }
}

// ---------------- E2 = leaky(bn(E1)) @ We2^T via MFMA, in place; fused stats ----------------
// Block: 256 thr / 4 waves, 256 rows. K=32 (single k-step).
__global__ __launch_bounds__(256) void k_e2m(
    float* __restrict__ E, const float* __restrict__ mrE1,
    const float* __restrict__ ge1, const float* __restrict__ be1,
    const float* __restrict__ We2, float* __restrict__ buckE2)
{
  __shared__ unsigned short Ab[8192];   // 256 rows x 32 c (16 KB)
  __shared__ unsigned short Wb[1024];   // 32 d x 32 c (2 KB)
  __shared__ float Ssum[32], Ssq[32];
  const int tid = threadIdx.x;
  const int wv = tid>>6, lane = tid&63;
  const int quad = lane>>4, lm = lane&15;
  const long r0 = (long)blockIdx.x*256;
  if (tid < 32){ Ssum[tid]=0.f; Ssq[tid]=0.f; }
  for (int e = tid; e < 1024; e += 256){
    int d = e>>5, c = e&31;
    int off = ((d>>4)*4 + ((c>>3)&3))*128 + (d&15)*8 + (c&7);
    Wb[off] = bfr(We2[e]);
  }
  #pragma unroll
  for (int it=0; it<8; it++){
    int e = (tid + it*256)*4;
    int row = e>>5, c = e&31;
    float4 v = *(const float4*)(E + (r0 + row)*32 + c);
    float4 m4 = *(const float4*)(mrE1 + c);
    float4 r4 = *(const float4*)(mrE1 + 32 + c);
    float4 g4 = *(const float4*)(ge1 + c);
    float4 b4 = *(const float4*)(be1 + c);
    float o0 = leakyf((v.x - m4.x)*r4.x*g4.x + b4.x);
    float o1 = leakyf((v.y - m4.y)*r4.y*g4.y + b4.y);
    float o2 = leakyf((v.z - m4.z)*r4.z*g4.z + b4.z);
    float o3 = leakyf((v.w - m4.w)*r4.w*g4.w + b4.w);
    int quadc = (c>>3)&3, jc = c&7;
    int slot = ((row&15) ^ quadc) & 15;
    int off = ((row>>4)*4 + quadc)*128 + slot*8 + jc;
    ushort4 u; u.x=bfr(o0); u.y=bfr(o1); u.z=bfr(o2); u.w=bfr(o3);
    *(ushort4*)&Ab[off] = u;
  }
  __syncthreads();
  f4v acc0[4], acc1[4];
  #pragma unroll
  for (int i=0;i<4;i++){ acc0[i]=(f4v){0,0,0,0}; acc1[i]=(f4v){0,0,0,0}; }
  const int aslot = (lm ^ quad) & 15;
  s8v b0 = *(const s8v*)&Wb[(quad)*128 + lm*8];
  s8v b1 = *(const s8v*)&Wb[(4 + quad)*128 + lm*8];
  #pragma unroll
  for (int i=0;i<4;i++){
    const int atile = wv*4 + i;
    s8v a = *(const s8v*)&Ab[(atile*4 + quad)*128 + aslot*8];
    acc0[i] = __builtin_amdgcn_mfma_f32_16x16x32_bf16(a, b0, acc0[i], 0,0,0);
    acc1[i] = __builtin_amdgcn_mfma_f32_16x16x32_bf16(a, b1, acc1[i], 0,0,0);
  }
  __syncthreads();   // all reads done before in-place writes
  float s0=0,q0=0,s1=0,q1=0;
  #pragma unroll
  for (int i=0;i<4;i++){
    const int atile = wv*4 + i;
    #pragma unroll
    for (int rr=0; rr<4; rr++){
      long row = r0 + atile*16 + quad*4 + rr;
      float* o = E + row*32;
      o[lm]      = acc0[i][rr];
      o[16 + lm] = acc1[i][rr];
      s0 += acc0[i][rr]; q0 += acc0[i][rr]*acc0[i][rr];
      s1 += acc1[i][rr]; q1 += acc1[i][rr]*acc1[i][rr];
    }
  }
  s0 += __shfl_xor(s0,16,64); s0 += __shfl_xor(s0,32,64);
  q0 += __shfl_xor(q0,16,64); q0 += __shfl_xor(q0,32,64);
  s1 += __shfl_xor(s1,16,64); s1 += __shfl_xor(s1,32,64);
  q1 += __shfl_xor(q1,16,64); q1 += __shfl_xor(q1,32,64);
  if (quad == 0){
    atomicAdd(&Ssum[lm], s0);    atomicAdd(&Ssq[lm], q0);
    atomicAdd(&Ssum[16+lm], s1); atomicAdd(&Ssq[16+lm], q1);
  }
  __syncthreads();
  if (tid < 32){
    float* bb = buckE2 + (long)(blockIdx.x & 63)*64;
    atomicAdd(&bb[tid], Ssum[tid]); atomicAdd(&bb[32+tid], Ssq[tid]);
  }
}

// ---------------- softmax over k + attention + residual ----------------
__global__ __launch_bounds__(64) void k_attn(
    const float* __restrict__ E2, const float* __restrict__ mrE2,
    const float* __restrict__ ge2, const float* __restrict__ be2,
    const float* __restrict__ qv, const float* __restrict__ P, const int* __restrict__ idx,
    const float* __restrict__ mrPB, const float* __restrict__ gpb, const float* __restrict__ bpb,
    const float* __restrict__ xin, float* __restrict__ x2)
{
  __shared__ float L[32][33];
  const int lane = threadIdx.x;
  const int bn = blockIdx.x;
  const long base = (long)(bn >> 11) << 11;
  for (int qq=0; qq<4; qq++){
    int e = lane*16 + qq*4;
    int k = e >> 5, g0 = e & 31;
    float4 v  = *(const float4*)(E2 + (long)bn*1024 + e);
    float4 m4 = *(const float4*)(mrE2 + g0);
    float4 r4 = *(const float4*)(mrE2 + 32 + g0);
    float4 g4 = *(const float4*)(ge2 + g0);
    float4 b4 = *(const float4*)(be2 + g0);
    L[k][g0+0] = leakyf((v.x - m4.x)*r4.x*g4.x + b4.x);
    L[k][g0+1] = leakyf((v.y - m4.y)*r4.y*g4.y + b4.y);
    L[k][g0+2] = leakyf((v.z - m4.z)*r4.z*g4.z + b4.z);
    L[k][g0+3] = leakyf((v.w - m4.w)*r4.w*g4.w + b4.w);
  }
  __syncthreads();
  {
    const int g = lane & 31, h = lane >> 5;
    float mx = -3.4e38f;
    for (int j=0;j<16;j++) mx = fmaxf(mx, L[h*16+j][g]);
    mx = fmaxf(mx, __shfl_xor(mx, 32, 64));
    float sm = 0.f, ev[16];
    for (int j=0;j<16;j++){ float e_ = __expf(L[h*16+j][g] - mx); ev[j] = e_; sm += e_; }
    sm += __shfl_xor(sm, 32, 64);
    float inv = 1.f/sm;
    for (int j=0;j<16;j++) L[h*16+j][g] = ev[j]*inv;
  }
  __syncthreads();
  const int c4 = lane*4, gg = lane >> 1;
  float4 pn4 = *(const float4*)(P + (long)bn*256 + c4);
  float4 mp4 = *(const float4*)(mrPB + c4);
  float4 rp4 = *(const float4*)(mrPB + 256 + c4);
  float4 g4 = *(const float4*)(gpb + c4);
  float4 b4 = *(const float4*)(bpb + c4);
  float accv[4] = {0,0,0,0};
  const int* ir = idx + bn*32;
  for (int k=0;k<32;k++){
    int gi = ir[k];
    float4 vv = *(const float4*)(qv + (long)(base+gi)*512 + 256 + c4);
    float4 pp = *(const float4*)(P + (base+gi)*256 + c4);
    float w = L[k][gg];
    float zh0 = (pp.x - pn4.x - mp4.x)*rp4.x*g4.x + b4.x;
    float zh1 = (pp.y - pn4.y - mp4.y)*rp4.y*g4.y + b4.y;
    float zh2 = (pp.z - pn4.z - mp4.z)*rp4.z*g4.z + b4.z;
    float zh3 = (pp.w - pn4.w - mp4.w)*rp4.w*g4.w + b4.w;
    accv[0] = fmaf(vv.x + leakyf(zh0), w, accv[0]);
    accv[1] = fmaf(vv.y + leakyf(zh1), w, accv[1]);
    accv[2] = fmaf(vv.z + leakyf(zh2), w, accv[2]);
    accv[3] = fmaf(vv.w + leakyf(zh3), w, accv[3]);
  }
  float4 x4 = *(const float4*)(xin + (long)bn*256 + c4);
  float4 o;
  o.x = x4.x + accv[0]; o.y = x4.y + accv[1];
  o.z = x4.z + accv[2]; o.w = x4.w + accv[3];
  *(float4*)(x2 + (long)bn*256 + c4) = o;
}

// ---------------- final: out = x2 + silu(bn(Zm2)) ----------------
__global__ __launch_bounds__(256) void k_final(const float* __restrict__ x2, const float* __restrict__ Zm2,
    const float* __restrict__ mr, const float* __restrict__ gm, const float* __restrict__ bm,
    float* __restrict__ out){
  const int r = blockIdx.x, c = threadIdx.x;
  float z = Zm2[(long)r*256 + c];
  float y = (z - mr[c])*mr[256+c]*gm[c] + bm[c];
  out[(long)r*256 + c] = x2[(long)r*256 + c] + siluf(y);
}

extern "C" void kernel_launch(void* const* d_in, const int* in_sizes, int n_in,
                              void* d_out, int out_size, void* d_ws, size_t ws_size,
                              hipStream_t stream){
  (void)in_sizes; (void)n_in; (void)out_size; (void)ws_size;
  const float* x   = (const float*)d_in[0];
  const float* pos = (const float*)d_in[1];
  const float* Wq  = (const float*)d_in[2];
  const float* gq  = (const float*)d_in[3];
  const float* bq  = (const float*)d_in[4];
  const float* Wk  = (const float*)d_in[5];
  const float* gk  = (const float*)d_in[6];
  const float* bk  = (const float*)d_in[7];
  const float* Wv  = (const float*)d_in[8];
  const float* gv  = (const float*)d_in[9];
  const float* bv  = (const float*)d_in[10];
  const float* Wpb = (const float*)d_in[11];
  const float* gpb = (const float*)d_in[12];
  const float* bpb = (const float*)d_in[13];
  const float* We1 = (const float*)d_in[14];
  const float* ge1 = (const float*)d_in[15];
  const float* be1 = (const float*)d_in[16];
  const float* We2 = (const float*)d_in[17];
  const float* ge2 = (const float*)d_in[18];
  const float* be2 = (const float*)d_in[19];
  const float* Wm1 = (const float*)d_in[20];
  const float* gm1 = (const float*)d_in[21];
  const float* bm1 = (const float*)d_in[22];
  const float* Wm2 = (const float*)d_in[23];
  const float* gm2 = (const float*)d_in[24];
  const float* bm2 = (const float*)d_in[25];

  float* w     = (float*)d_ws;
  float* arena = w;                       // 4,194,304: rawQKV / G / E1->E2 / Zm1+Zm2
  float* key   = w + 4194304;             // 1,048,576
  float* P     = w + 5242880;             // 1,048,576
  float* x2    = w + 6291456;             // 1,048,576
  float* qv    = w + 7340032;             // 2,097,152 (q|v per row, stride 512)
  float* sq    = w + 9437184;             // 4,096
  int*   idx   = (int*)(w + 9441280);     // 131,072 ints
  float* buck  = w + 9572352;             // 237,568
  float* mr    = w + 9809920;             // 3,712
  float* bQKV = buck;            float* bPB = buck + 98304;  float* bE1 = buck + 131072;
  float* bE2  = buck + 135168;   float* bM1 = buck + 139264; float* bM2 = buck + 204800;
  float* mrQKV = mr;        float* mrPB = mr + 1536; float* mrE1 = mr + 2048;
  float* mrE2  = mr + 2112; float* mrM1 = mr + 2176; float* mrM2 = mr + 3200;
  float* Zm1 = arena;
  float* Zm2 = arena + 2097152;

  k_zero<<<943,256,0,stream>>>(buck, 241280);
  k_gemm<false,true><<<dim3(32,2,3),256,0,stream>>>(x,256, nullptr,nullptr,nullptr,0,
      Wq,Wk,Wv,256, arena,768,256, 256, bQKV,768,256);
  k_gemm<false,false><<<dim3(32,2,1),256,0,stream>>>(pos,256, nullptr,nullptr,nullptr,0,
      Wpb,Wpb,Wpb,256, P,256,0, 256, nullptr,0,0);
  k_finalize<<<3,256,0,stream>>>(bQKV, 768, 1.f/4096.f, mrQKV);
  k_apply_qkv<<<4096,256,0,stream>>>(arena, mrQKV, gq,bq,gk,bk,gv,bv, key, qv, sq);
  k_gemm<false,false><<<dim3(16,16,1),256,0,stream>>>(key,256, nullptr,nullptr,nullptr,0,
      key,key,key,256, arena,2048,0, 256, nullptr,0,0);
  k_topk<<<512,256,0,stream>>>(arena, sq, idx);
  k_gemm<false,false><<<dim3(16,16,1),256,0,stream>>>(key+524288,256, nullptr,nullptr,nullptr,0,
      key+524288,key+524288,key+524288,256, arena,2048,0, 256, nullptr,0,0);
  k_topk<<<512,256,0,stream>>>(arena, sq+2048, idx+65536);
  k_stats_pb<<<256,256,0,stream>>>(P, idx, bPB);
  k_finalize<<<1,256,0,stream>>>(bPB, 256, 1.f/131072.f, mrPB);
  k_e1m<<<2048,256,0,stream>>>(key, qv, P, idx, mrPB, gpb, bpb, We1, arena, bE1);
  k_finalize<<<1,256,0,stream>>>(bE1, 32, 1.f/131072.f, mrE1);
  k_e2m<<<512,256,0,stream>>>(arena, mrE1, ge1, be1, We2, bE2);
  k_finalize<<<1,256,0,stream>>>(bE2, 32, 1.f/131072.f, mrE2);
  k_attn<<<4096,64,0,stream>>>(arena, mrE2, ge2, be2, qv, P, idx, mrPB, gpb, bpb, x, x2);
  k_gemm<false,true><<<dim3(32,4,1),256,0,stream>>>(x2,256, nullptr,nullptr,nullptr,0,
      Wm1,Wm1,Wm1,256, Zm1,512,0, 256, bM1,512,0);
  k_finalize<<<2,256,0,stream>>>(bM1, 512, 1.f/4096.f, mrM1);
  k_gemm<true,true><<<dim3(32,2,1),256,0,stream>>>(Zm1,512, mrM1,gm1,bm1,512,
      Wm2,Wm2,Wm2,512, Zm2,256,0, 512, bM2,256,0);
  k_finalize<<<1,256,0,stream>>>(bM2, 256, 1.f/4096.f, mrM2);
  k_final<<<4096,256,0,stream>>>(x2, Zm2, mrM2, gm2, bm2, (float*)d_out);
}

// Round 7
// 396.093 us; speedup vs baseline: 1.8699x; 1.2380x over previous
//
#include <hip/hip_runtime.h>

#define EPS 1e-5f

typedef __attribute__((ext_vector_type(8))) short s8v;
typedef __attribute__((ext_vector_type(4))) float f4v;

__device__ __forceinline__ float leakyf(float z){ return z >= 0.f ? z : 0.2f*z; }
__device__ __forceinline__ float siluf(float y){ return y / (1.f + __expf(-y)); }
__device__ __forceinline__ unsigned f2bfu(float f){
  unsigned u = __float_as_uint(f);
  return (u + 0x7FFFu + ((u>>16)&1u)) >> 16;
}
__device__ __forceinline__ unsigned short bfr(float f){ return (unsigned short)f2bfu(f); }
__device__ __forceinline__ float bf2f16(unsigned short s){ return __uint_as_float(((unsigned)s)<<16); }

// ---------------- zero scratch ----------------
__global__ __launch_bounds__(256) void k_zero(float* __restrict__ p, int n){
  int i = blockIdx.x*256 + threadIdx.x;
  if (i < n) p[i] = 0.f;
}

// ------- NT GEMM via split-bf16 MFMA, 64x64 tile, 4 waves, dbuf prefetch -------
// C[m,n] = sum_k A'[m,k]*B[n,k]; optional bn+silu on A; optional column-stats epilogue.
template<bool TRANSA, bool STATS>
__global__ __launch_bounds__(256) void k_gemm(
    const float* __restrict__ A, int lda,
    const float* __restrict__ tA, const float* __restrict__ gA, const float* __restrict__ bA, int CA,
    const float* __restrict__ B0, const float* __restrict__ B1, const float* __restrict__ B2,
    int ldb, float* __restrict__ C, int ldc, long cStr, int K,
    float* __restrict__ buck, int statC, int statChanStr)
{
  __shared__ unsigned short Ah[2048], Al[2048], Bh[2048], Bl[2048];
  __shared__ float Ssum[64], Ssq[64];
  const int z = blockIdx.z;
  const float* Bb = (z==0?B0:(z==1?B1:B2));
  float* Cb = C + (long)z*cStr;
  const int tid = threadIdx.x;
  const int bm = blockIdx.x*64, bn = blockIdx.y*64;
  const int wv = tid>>6, lane = tid&63;
  const int lm = lane&15, quad = lane>>4;
  if (STATS && tid<64){ Ssum[tid]=0.f; Ssq[tid]=0.f; }

  // staging: thread handles rows r0 and r0+32 at k-group kg (k = kg*4)
  const int r0 = tid>>3, kg = tid&7;
  const int qk = kg>>1, j0 = (kg&1)*4;
  const int s0 = ((((r0>>4)  )*4 + qk)*16 + ((r0&15)^qk))*8 + j0;
  const int s1 = ((((r0>>4)+2)*4 + qk)*16 + ((r0&15)^qk))*8 + j0;
  const float* aP0 = A  + (long)(bm+r0)*lda + kg*4;
  const float* aP1 = aP0 + (long)32*lda;
  const float* bP0 = Bb + (long)(bn+r0)*ldb + kg*4;
  const float* bP1 = bP0 + (long)32*ldb;

  f4v acc[4];
  #pragma unroll
  for (int j=0;j<4;j++) acc[j] = (f4v){0.f,0.f,0.f,0.f};

  float4 a0 = *(const float4*)(aP0);
  float4 a1 = *(const float4*)(aP1);
  float4 b0 = *(const float4*)(bP0);
  float4 b1 = *(const float4*)(bP1);

  for (int k0=0; k0<K; k0+=32){
    float4 av0 = a0, av1 = a1;
    if (TRANSA){
      const float* tm = tA + k0 + kg*4;
      float4 m4 = *(const float4*)tm;
      float4 r4 = *(const float4*)(tm + CA);
      float4 g4 = *(const float4*)(gA + k0 + kg*4);
      float4 b4 = *(const float4*)(bA + k0 + kg*4);
      av0.x = siluf((av0.x - m4.x)*r4.x*g4.x + b4.x);
      av0.y = siluf((av0.y - m4.y)*r4.y*g4.y + b4.y);
      av0.z = siluf((av0.z - m4.z)*r4.z*g4.z + b4.z);
      av0.w = siluf((av0.w - m4.w)*r4.w*g4.w + b4.w);
      av1.x = siluf((av1.x - m4.x)*r4.x*g4.x + b4.x);
      av1.y = siluf((av1.y - m4.y)*r4.y*g4.y + b4.y);
      av1.z = siluf((av1.z - m4.z)*r4.z*g4.z + b4.z);
      av1.w = siluf((av1.w - m4.w)*r4.w*g4.w + b4.w);
    }
    ushort4 h4, l4;
    h4.x=bfr(av0.x); l4.x=bfr(av0.x-bf2f16(h4.x));
    h4.y=bfr(av0.y); l4.y=bfr(av0.y-bf2f16(h4.y));
    h4.z=bfr(av0.z); l4.z=bfr(av0.z-bf2f16(h4.z));
    h4.w=bfr(av0.w); l4.w=bfr(av0.w-bf2f16(h4.w));
    *(ushort4*)&Ah[s0]=h4; *(ushort4*)&Al[s0]=l4;
    h4.x=bfr(av1.x); l4.x=bfr(av1.x-bf2f16(h4.x));
    h4.y=bfr(av1.y); l4.y=bfr(av1.y-bf2f16(h4.y));
    h4.z=bfr(av1.z); l4.z=bfr(av1.z-bf2f16(h4.z));
    h4.w=bfr(av1.w); l4.w=bfr(av1.w-bf2f16(h4.w));
    *(ushort4*)&Ah[s1]=h4; *(ushort4*)&Al[s1]=l4;
    h4.x=bfr(b0.x); l4.x=bfr(b0.x-bf2f16(h4.x));
    h4.y=bfr(b0.y); l4.y=bfr(b0.y-bf2f16(h4.y));
    h4.z=bfr(b0.z); l4.z=bfr(b0.z-bf2f16(h4.z));
    h4.w=bfr(b0.w); l4.w=bfr(b0.w-bf2f16(h4.w));
    *(ushort4*)&Bh[s0]=h4; *(ushort4*)&Bl[s0]=l4;
    h4.x=bfr(b1.x); l4.x=bfr(b1.x-bf2f16(h4.x));
    h4.y=bfr(b1.y); l4.y=bfr(b1.y-bf2f16(h4.y));
    h4.z=bfr(b1.z); l4.z=bfr(b1.z-bf2f16(h4.z));
    h4.w=bfr(b1.w); l4.w=bfr(b1.w-bf2f16(h4.w));
    *(ushort4*)&Bh[s1]=h4; *(ushort4*)&Bl[s1]=l4;
    __syncthreads();
    if (k0+32 < K){
      a0 = *(const float4*)(aP0 + k0+32);
      a1 = *(const float4*)(aP1 + k0+32);
      b0 = *(const float4*)(bP0 + k0+32);
      b1 = *(const float4*)(bP1 + k0+32);
    }
    const int soA = ((wv*4 + quad)*16 + (lm^quad))*8;
    s8v ah = *(const s8v*)&Ah[soA];
    s8v al = *(const s8v*)&Al[soA];
    #pragma unroll
    for (int j=0;j<4;j++){
      const int soB = ((j*4 + quad)*16 + (lm^quad))*8;
      s8v bh = *(const s8v*)&Bh[soB];
      s8v bl = *(const s8v*)&Bl[soB];
      acc[j] = __builtin_amdgcn_mfma_f32_16x16x32_bf16(ah, bh, acc[j], 0,0,0);
      acc[j] = __builtin_amdgcn_mfma_f32_16x16x32_bf16(ah, bl, acc[j], 0,0,0);
      acc[j] = __builtin_amdgcn_mfma_f32_16x16x32_bf16(al, bh, acc[j], 0,0,0);
      acc[j] = __builtin_amdgcn_mfma_f32_16x16x32_bf16(al, bl, acc[j], 0,0,0);
    }
    __syncthreads();
  }
  // C write: row = bm + wv*16 + quad*4 + rr, col = bn + j*16 + lm
  #pragma unroll
  for (int rr=0;rr<4;rr++){
    float* cr = Cb + (long)(bm + wv*16 + quad*4 + rr)*ldc + bn + lm;
    #pragma unroll
    for (int j=0;j<4;j++) cr[j*16] = acc[j][rr];
  }
  if (STATS){
    #pragma unroll
    for (int j=0;j<4;j++){
      float s=0.f, q=0.f;
      #pragma unroll
      for (int rr=0;rr<4;rr++){ float v = acc[j][rr]; s += v; q += v*v; }
      s += __shfl_xor(s,16,64); s += __shfl_xor(s,32,64);
      q += __shfl_xor(q,16,64); q += __shfl_xor(q,32,64);
      if (quad==0){ atomicAdd(&Ssum[j*16+lm], s); atomicAdd(&Ssq[j*16+lm], q); }
    }
    __syncthreads();
    if (tid < 64){
      int chan = statChanStr*z + bn + tid;
      float* bb = buck + (long)(blockIdx.x & 63)*2*statC;
      atomicAdd(&bb[chan], Ssum[tid]);
      atomicAdd(&bb[statC + chan], Ssq[tid]);
    }
  }
}

__global__ void k_finalize(const float* __restrict__ buck, int C, float invn, float* __restrict__ mr){
  int c = blockIdx.x*256 + threadIdx.x;
  if (c < C){
    float s=0,q=0;
    for (int b=0;b<64;b++){ s += buck[(long)b*2*C + c]; q += buck[(long)b*2*C + C + c]; }
    float m = s*invn;
    float v = fmaxf(q*invn - m*m, 0.f);
    mr[c] = m; mr[C+c] = rsqrtf(v + EPS);
  }
}

// ---------------- BN+leaky on raw qkv -> key, q|v, sq ----------------
__global__ __launch_bounds__(256) void k_apply_qkv(const float* __restrict__ raw, const float* __restrict__ mr,
    const float* __restrict__ gq, const float* __restrict__ bq,
    const float* __restrict__ gk, const float* __restrict__ bk,
    const float* __restrict__ gv, const float* __restrict__ bv,
    float* __restrict__ key, float* __restrict__ qv, float* __restrict__ sq){
  const int r = blockIdx.x, tid = threadIdx.x;
  __shared__ float red[256];
  const float* row = raw + (long)r*768;
  float zq = row[tid], zk = row[256+tid], zv = row[512+tid];
  float yq = leakyf((zq - mr[tid])*mr[768+tid]*gq[tid] + bq[tid]);
  float yk = leakyf((zk - mr[256+tid])*mr[1024+tid]*gk[tid] + bk[tid]);
  float yv = leakyf((zv - mr[512+tid])*mr[1280+tid]*gv[tid] + bv[tid]);
  qv[(long)r*512 + tid] = yq;
  key[(long)r*256 + tid] = yk;
  qv[(long)r*512 + 256 + tid] = yv;
  red[tid] = yk*yk; __syncthreads();
  for (int off=128; off; off>>=1){ if (tid<off) red[tid] += red[tid+off]; __syncthreads(); }
  if (tid==0) sq[r] = red[0];
}

// ---------------- top-K (K=32) smallest dist per row; one wave per row ----------------
__global__ __launch_bounds__(256) void k_topk(const float* __restrict__ G, const float* __restrict__ sqb,
    int* __restrict__ idxb){
  __shared__ float dist[4][2048];
  const int wv = threadIdx.x >> 6, lane = threadIdx.x & 63;
  const int n = blockIdx.x*4 + wv;
  const float* Grow = G + (long)n*2048;
  const float sqn = sqb[n];
  float lmin = 3.4e38f; int lidx = 0;
  for (int j=0;j<32;j++){
    int m = lane + j*64;
    float d = sqn + sqb[m] - 2.f*Grow[m];
    dist[wv][m] = d;
    if (d < lmin){ lmin = d; lidx = m; }
  }
  int* orow = idxb + n*32;
  for (int t=0;t<32;t++){
    float v = lmin; int i = lidx;
    for (int off=32; off; off>>=1){
      float v2 = __shfl_xor(v, off, 64);
      int i2 = __shfl_xor(i, off, 64);
      if (v2 < v || (v2 == v && i2 < i)){ v = v2; i = i2; }
    }
    if (lane == 0) orow[t] = i;
    if ((i & 63) == lane){
      dist[wv][i] = 3.4e38f;
      lmin = 3.4e38f; lidx = 0;
      for (int j=0;j<32;j++){
        int m = lane + j*64;
        float d = dist[wv][m];
        if (d < lmin){ lmin = d; lidx = m; }
      }
    }
  }
}

// ---------------- stats of z_pb = P[idx]-P[n] ----------------
__global__ __launch_bounds__(256) void k_stats_pb(const float* __restrict__ P, const int* __restrict__ idx,
    float* __restrict__ buck){
  const int c = threadIdx.x;
  float s=0,q=0;
  for (int r = blockIdx.x; r < 4096; r += gridDim.x){
    const long base = (long)(r >> 11) << 11;
    const float pn = P[(long)r*256 + c];
    const int* ir = idx + r*32;
    for (int k=0;k<32;k++){
      int g = ir[k];
      float z = P[(base + g)*256 + c] - pn;
      s += z; q += z*z;
    }
  }
  float* bb = buck + (long)(blockIdx.x & 63)*512;
  atomicAdd(&bb[c], s); atomicAdd(&bb[256+c], q);
}

// ---------------- E1 = (key[g]-q[n]+posb) @ We1^T via MFMA; fused stats ----------------
__global__ __launch_bounds__(256) void k_e1m(
    const float* __restrict__ key, const float* __restrict__ qv, const float* __restrict__ P,
    const int* __restrict__ idx, const float* __restrict__ mrPB,
    const float* __restrict__ gpb, const float* __restrict__ bpb,
    const float* __restrict__ We1, float* __restrict__ E1, float* __restrict__ buckE1)
{
  __shared__ unsigned short Ab[16384];  // 64 rows x 256 k (32 KB)
  __shared__ unsigned short Wb[8192];   // 32 d x 256 k (16 KB)
  __shared__ float Ssum[32], Ssq[32];
  const int tid = threadIdx.x;
  const int wv = tid>>6, lane = tid&63;
  const int quad = lane>>4, lm = lane&15;
  const int bn0 = blockIdx.x*2;
  if (tid < 32){ Ssum[tid]=0.f; Ssq[tid]=0.f; }
  for (int e = tid; e < 8192; e += 256){
    int d = e >> 8, c = e & 255;
    int off = (((d>>4)*8 + (c>>5))*4 + ((c>>3)&3))*128 + (d&15)*8 + (c&7);
    Wb[off] = bfr(We1[e]);
  }
  {
    const int bn = bn0 + (wv>>1);
    const long base = (long)(bn >> 11) << 11;
    const int c4 = lane*4;
    float4 q4  = *(const float4*)(qv + (long)bn*512 + c4);
    float4 pn4 = *(const float4*)(P + (long)bn*256 + c4);
    float4 mp4 = *(const float4*)(mrPB + c4);
    float4 rp4 = *(const float4*)(mrPB + 256 + c4);
    float4 g4  = *(const float4*)(gpb + c4);
    float4 b4  = *(const float4*)(bpb + c4);
    const int ksc = c4>>5, quadc = (c4>>3)&3, jc = c4&7;
    for (int j = 0; j < 16; ++j){
      const int rloc = wv*16 + j;
      const int kk = rloc & 31;
      const int g = idx[bn*32 + kk];
      float4 kb = *(const float4*)(key + (base+g)*256 + c4);
      float4 pb = *(const float4*)(P + (base+g)*256 + c4);
      float o0 = kb.x - q4.x + leakyf((pb.x - pn4.x - mp4.x)*rp4.x*g4.x + b4.x);
      float o1 = kb.y - q4.y + leakyf((pb.y - pn4.y - mp4.y)*rp4.y*g4.y + b4.y);
      float o2 = kb.z - q4.z + leakyf((pb.z - pn4.z - mp4.z)*rp4.z*g4.z + b4.z);
      float o3 = kb.w - q4.w + leakyf((pb.w - pn4.w - mp4.w)*rp4.w*g4.w + b4.w);
      const int atile = rloc >> 4;
      const int slot = ((rloc & 15) ^ (ksc<<1) ^ quadc) & 15;
      const int off = ((atile*8 + ksc)*4 + quadc)*128 + slot*8 + jc;
      ushort4 u; u.x = bfr(o0); u.y = bfr(o1); u.z = bfr(o2); u.w = bfr(o3);
      *(ushort4*)&Ab[off] = u;
    }
  }
  __syncthreads();
  f4v acc0 = (f4v){0,0,0,0}, acc1 = (f4v){0,0,0,0};
  #pragma unroll
  for (int ks=0; ks<8; ks++){
    const int aslot = (lm ^ (ks<<1) ^ quad) & 15;
    s8v a  = *(const s8v*)&Ab[((wv*8 + ks)*4 + quad)*128 + aslot*8];
    s8v b0 = *(const s8v*)&Wb[((ks)*4 + quad)*128 + lm*8];
    s8v b1 = *(const s8v*)&Wb[((8 + ks)*4 + quad)*128 + lm*8];
    acc0 = __builtin_amdgcn_mfma_f32_16x16x32_bf16(a, b0, acc0, 0,0,0);
    acc1 = __builtin_amdgcn_mfma_f32_16x16x32_bf16(a, b1, acc1, 0,0,0);
  }
  {
    const int bn = bn0 + (wv>>1);
    const int mt = wv & 1;
    #pragma unroll
    for (int rr=0; rr<4; rr++){
      int krow = mt*16 + quad*4 + rr;
      float* o = E1 + ((long)bn*32 + krow)*32;
      o[lm]      = acc0[rr];
      o[16 + lm] = acc1[rr];
    }
  }
  float s0=0,q0=0,s1=0,q1=0;
  #pragma unroll
  for (int rr=0; rr<4; rr++){
    s0 += acc0[rr]; q0 += acc0[rr]*acc0[rr];
    s1 += acc1[rr]; q1 += acc1[rr]*acc1[rr];
  }
  s0 += __shfl_xor(s0,16,64); s0 += __shfl_xor(s0,32,64);
  q0 += __shfl_xor(q0,16,64); q0 += __shfl_xor(q0,32,64);
  s1 += __shfl_xor(s1,16,64); s1 += __shfl_xor(s1,32,64);
  q1 += __shfl_xor(q1,16,64); q1 += __shfl_xor(q1,32,64);
  if (quad == 0){
    atomicAdd(&Ssum[lm], s0);      atomicAdd(&Ssq[lm], q0);
    atomicAdd(&Ssum[16+lm], s1);   atomicAdd(&Ssq[16+lm], q1);
  }
  __syncthreads();
  if (tid < 32){
    float* bb = buckE1 + (long)(blockIdx.x & 63)*64;
    atomicAdd(&bb[tid], Ssum[tid]); atomicAdd(&bb[32+tid], Ssq[tid]);
  }
}

// ---------------- E2 = leaky(bn(E1)) @ We2^T via MFMA, in place; fused stats ----------------
__global__ __launch_bounds__(256) void k_e2m(
    float* __restrict__ E, const float* __restrict__ mrE1,
    const float* __restrict__ ge1, const float* __restrict__ be1,
    const float* __restrict__ We2, float* __restrict__ buckE2)
{
  __shared__ unsigned short Ab[8192];
  __shared__ unsigned short Wb[1024];
  __shared__ float Ssum[32], Ssq[32];
  const int tid = threadIdx.x;
  const int wv = tid>>6, lane = tid&63;
  const int quad = lane>>4, lm = lane&15;
  const long r0 = (long)blockIdx.x*256;
  if (tid < 32){ Ssum[tid]=0.f; Ssq[tid]=0.f; }
  for (int e = tid; e < 1024; e += 256){
    int d = e>>5, c = e&31;
    int off = ((d>>4)*4 + ((c>>3)&3))*128 + (d&15)*8 + (c&7);
    Wb[off] = bfr(We2[e]);
  }
  #pragma unroll
  for (int it=0; it<8; it++){
    int e = (tid + it*256)*4;
    int row = e>>5, c = e&31;
    float4 v = *(const float4*)(E + (r0 + row)*32 + c);
    float4 m4 = *(const float4*)(mrE1 + c);
    float4 r4 = *(const float4*)(mrE1 + 32 + c);
    float4 g4 = *(const float4*)(ge1 + c);
    float4 b4 = *(const float4*)(be1 + c);
    float o0 = leakyf((v.x - m4.x)*r4.x*g4.x + b4.x);
    float o1 = leakyf((v.y - m4.y)*r4.y*g4.y + b4.y);
    float o2 = leakyf((v.z - m4.z)*r4.z*g4.z + b4.z);
    float o3 = leakyf((v.w - m4.w)*r4.w*g4.w + b4.w);
    int quadc = (c>>3)&3, jc = c&7;
    int slot = ((row&15) ^ quadc) & 15;
    int off = ((row>>4)*4 + quadc)*128 + slot*8 + jc;
    ushort4 u; u.x=bfr(o0); u.y=bfr(o1); u.z=bfr(o2); u.w=bfr(o3);
    *(ushort4*)&Ab[off] = u;
  }
  __syncthreads();
  f4v acc0[4], acc1[4];
  #pragma unroll
  for (int i=0;i<4;i++){ acc0[i]=(f4v){0,0,0,0}; acc1[i]=(f4v){0,0,0,0}; }
  const int aslot = (lm ^ quad) & 15;
  s8v b0 = *(const s8v*)&Wb[(quad)*128 + lm*8];
  s8v b1 = *(const s8v*)&Wb[(4 + quad)*128 + lm*8];
  #pragma unroll
  for (int i=0;i<4;i++){
    const int atile = wv*4 + i;
    s8v a = *(const s8v*)&Ab[(atile*4 + quad)*128 + aslot*8];
    acc0[i] = __builtin_amdgcn_mfma_f32_16x16x32_bf16(a, b0, acc0[i], 0,0,0);
    acc1[i] = __builtin_amdgcn_mfma_f32_16x16x32_bf16(a, b1, acc1[i], 0,0,0);
  }
  __syncthreads();
  float s0=0,q0=0,s1=0,q1=0;
  #pragma unroll
  for (int i=0;i<4;i++){
    const int atile = wv*4 + i;
    #pragma unroll
    for (int rr=0; rr<4; rr++){
      long row = r0 + atile*16 + quad*4 + rr;
      float* o = E + row*32;
      o[lm]      = acc0[i][rr];
      o[16 + lm] = acc1[i][rr];
      s0 += acc0[i][rr]; q0 += acc0[i][rr]*acc0[i][rr];
      s1 += acc1[i][rr]; q1 += acc1[i][rr]*acc1[i][rr];
    }
  }
  s0 += __shfl_xor(s0,16,64); s0 += __shfl_xor(s0,32,64);
  q0 += __shfl_xor(q0,16,64); q0 += __shfl_xor(q0,32,64);
  s1 += __shfl_xor(s1,16,64); s1 += __shfl_xor(s1,32,64);
  q1 += __shfl_xor(q1,16,64); q1 += __shfl_xor(q1,32,64);
  if (quad == 0){
    atomicAdd(&Ssum[lm], s0);    atomicAdd(&Ssq[lm], q0);
    atomicAdd(&Ssum[16+lm], s1); atomicAdd(&Ssq[16+lm], q1);
  }
  __syncthreads();
  if (tid < 32){
    float* bb = buckE2 + (long)(blockIdx.x & 63)*64;
    atomicAdd(&bb[tid], Ssum[tid]); atomicAdd(&bb[32+tid], Ssq[tid]);
  }
}

// ---------------- softmax over k + attention + residual ----------------
__global__ __launch_bounds__(64) void k_attn(
    const float* __restrict__ E2, const float* __restrict__ mrE2,
    const float* __restrict__ ge2, const float* __restrict__ be2,
    const float* __restrict__ qv, const float* __restrict__ P, const int* __restrict__ idx,
    const float* __restrict__ mrPB, const float* __restrict__ gpb, const float* __restrict__ bpb,
    const float* __restrict__ xin, float* __restrict__ x2)
{
  __shared__ float L[32][33];
  const int lane = threadIdx.x;
  const int bn = blockIdx.x;
  const long base = (long)(bn >> 11) << 11;
  for (int qq=0; qq<4; qq++){
    int e = lane*16 + qq*4;
    int k = e >> 5, g0 = e & 31;
    float4 v  = *(const float4*)(E2 + (long)bn*1024 + e);
    float4 m4 = *(const float4*)(mrE2 + g0);
    float4 r4 = *(const float4*)(mrE2 + 32 + g0);
    float4 g4 = *(const float4*)(ge2 + g0);
    float4 b4 = *(const float4*)(be2 + g0);
    L[k][g0+0] = leakyf((v.x - m4.x)*r4.x*g4.x + b4.x);
    L[k][g0+1] = leakyf((v.y - m4.y)*r4.y*g4.y + b4.y);
    L[k][g0+2] = leakyf((v.z - m4.z)*r4.z*g4.z + b4.z);
    L[k][g0+3] = leakyf((v.w - m4.w)*r4.w*g4.w + b4.w);
  }
  __syncthreads();
  {
    const int g = lane & 31, h = lane >> 5;
    float mx = -3.4e38f;
    for (int j=0;j<16;j++) mx = fmaxf(mx, L[h*16+j][g]);
    mx = fmaxf(mx, __shfl_xor(mx, 32, 64));
    float sm = 0.f, ev[16];
    for (int j=0;j<16;j++){ float e_ = __expf(L[h*16+j][g] - mx); ev[j] = e_; sm += e_; }
    sm += __shfl_xor(sm, 32, 64);
    float inv = 1.f/sm;
    for (int j=0;j<16;j++) L[h*16+j][g] = ev[j]*inv;
  }
  __syncthreads();
  const int c4 = lane*4, gg = lane >> 1;
  float4 pn4 = *(const float4*)(P + (long)bn*256 + c4);
  float4 mp4 = *(const float4*)(mrPB + c4);
  float4 rp4 = *(const float4*)(mrPB + 256 + c4);
  float4 g4 = *(const float4*)(gpb + c4);
  float4 b4 = *(const float4*)(bpb + c4);
  float accv[4] = {0,0,0,0};
  const int* ir = idx + bn*32;
  for (int k=0;k<32;k++){
    int gi = ir[k];
    float4 vv = *(const float4*)(qv + (long)(base+gi)*512 + 256 + c4);
    float4 pp = *(const float4*)(P + (base+gi)*256 + c4);
    float w = L[k][gg];
    float zh0 = (pp.x - pn4.x - mp4.x)*rp4.x*g4.x + b4.x;
    float zh1 = (pp.y - pn4.y - mp4.y)*rp4.y*g4.y + b4.y;
    float zh2 = (pp.z - pn4.z - mp4.z)*rp4.z*g4.z + b4.z;
    float zh3 = (pp.w - pn4.w - mp4.w)*rp4.w*g4.w + b4.w;
    accv[0] = fmaf(vv.x + leakyf(zh0), w, accv[0]);
    accv[1] = fmaf(vv.y + leakyf(zh1), w, accv[1]);
    accv[2] = fmaf(vv.z + leakyf(zh2), w, accv[2]);
    accv[3] = fmaf(vv.w + leakyf(zh3), w, accv[3]);
  }
  float4 x4 = *(const float4*)(xin + (long)bn*256 + c4);
  float4 o;
  o.x = x4.x + accv[0]; o.y = x4.y + accv[1];
  o.z = x4.z + accv[2]; o.w = x4.w + accv[3];
  *(float4*)(x2 + (long)bn*256 + c4) = o;
}

// ---------------- final: out = x2 + silu(bn(Zm2)) ----------------
__global__ __launch_bounds__(256) void k_final(const float* __restrict__ x2, const float* __restrict__ Zm2,
    const float* __restrict__ mr, const float* __restrict__ gm, const float* __restrict__ bm,
    float* __restrict__ out){
  const int r = blockIdx.x, c = threadIdx.x;
  float z = Zm2[(long)r*256 + c];
  float y = (z - mr[c])*mr[256+c]*gm[c] + bm[c];
  out[(long)r*256 + c] = x2[(long)r*256 + c] + siluf(y);
}

extern "C" void kernel_launch(void* const* d_in, const int* in_sizes, int n_in,
                              void* d_out, int out_size, void* d_ws, size_t ws_size,
                              hipStream_t stream){
  (void)in_sizes; (void)n_in; (void)out_size; (void)ws_size;
  const float* x   = (const float*)d_in[0];
  const float* pos = (const float*)d_in[1];
  const float* Wq  = (const float*)d_in[2];
  const float* gq  = (const float*)d_in[3];
  const float* bq  = (const float*)d_in[4];
  const float* Wk  = (const float*)d_in[5];
  const float* gk  = (const float*)d_in[6];
  const float* bk  = (const float*)d_in[7];
  const float* Wv  = (const float*)d_in[8];
  const float* gv  = (const float*)d_in[9];
  const float* bv  = (const float*)d_in[10];
  const float* Wpb = (const float*)d_in[11];
  const float* gpb = (const float*)d_in[12];
  const float* bpb = (const float*)d_in[13];
  const float* We1 = (const float*)d_in[14];
  const float* ge1 = (const float*)d_in[15];
  const float* be1 = (const float*)d_in[16];
  const float* We2 = (const float*)d_in[17];
  const float* ge2 = (const float*)d_in[18];
  const float* be2 = (const float*)d_in[19];
  const float* Wm1 = (const float*)d_in[20];
  const float* gm1 = (const float*)d_in[21];
  const float* bm1 = (const float*)d_in[22];
  const float* Wm2 = (const float*)d_in[23];
  const float* gm2 = (const float*)d_in[24];
  const float* bm2 = (const float*)d_in[25];

  float* w     = (float*)d_ws;
  float* arena = w;                       // 4,194,304: rawQKV / G / E1->E2 / Zm1+Zm2
  float* key   = w + 4194304;             // 1,048,576
  float* P     = w + 5242880;             // 1,048,576
  float* x2    = w + 6291456;             // 1,048,576
  float* qv    = w + 7340032;             // 2,097,152 (q|v per row, stride 512)
  float* sq    = w + 9437184;             // 4,096
  int*   idx   = (int*)(w + 9441280);     // 131,072 ints
  float* buck  = w + 9572352;             // 237,568
  float* mr    = w + 9809920;             // 3,712
  float* bQKV = buck;            float* bPB = buck + 98304;  float* bE1 = buck + 131072;
  float* bE2  = buck + 135168;   float* bM1 = buck + 139264; float* bM2 = buck + 204800;
  float* mrQKV = mr;        float* mrPB = mr + 1536; float* mrE1 = mr + 2048;
  float* mrE2  = mr + 2112; float* mrM1 = mr + 2176; float* mrM2 = mr + 3200;
  float* Zm1 = arena;
  float* Zm2 = arena + 2097152;

  k_zero<<<943,256,0,stream>>>(buck, 241280);
  k_gemm<false,true><<<dim3(64,4,3),256,0,stream>>>(x,256, nullptr,nullptr,nullptr,0,
      Wq,Wk,Wv,256, arena,768,256, 256, bQKV,768,256);
  k_gemm<false,false><<<dim3(64,4,1),256,0,stream>>>(pos,256, nullptr,nullptr,nullptr,0,
      Wpb,Wpb,Wpb,256, P,256,0, 256, nullptr,0,0);
  k_finalize<<<3,256,0,stream>>>(bQKV, 768, 1.f/4096.f, mrQKV);
  k_apply_qkv<<<4096,256,0,stream>>>(arena, mrQKV, gq,bq,gk,bk,gv,bv, key, qv, sq);
  k_gemm<false,false><<<dim3(32,32,1),256,0,stream>>>(key,256, nullptr,nullptr,nullptr,0,
      key,key,key,256, arena,2048,0, 256, nullptr,0,0);
  k_topk<<<512,256,0,stream>>>(arena, sq, idx);
  k_gemm<false,false><<<dim3(32,32,1),256,0,stream>>>(key+524288,256, nullptr,nullptr,nullptr,0,
      key+524288,key+524288,key+524288,256, arena,2048,0, 256, nullptr,0,0);
  k_topk<<<512,256,0,stream>>>(arena, sq+2048, idx+65536);
  k_stats_pb<<<256,256,0,stream>>>(P, idx, bPB);
  k_finalize<<<1,256,0,stream>>>(bPB, 256, 1.f/131072.f, mrPB);
  k_e1m<<<2048,256,0,stream>>>(key, qv, P, idx, mrPB, gpb, bpb, We1, arena, bE1);
  k_finalize<<<1,256,0,stream>>>(bE1, 32, 1.f/131072.f, mrE1);
  k_e2m<<<512,256,0,stream>>>(arena, mrE1, ge1, be1, We2, bE2);
  k_finalize<<<1,256,0,stream>>>(bE2, 32, 1.f/131072.f, mrE2);
  k_attn<<<4096,64,0,stream>>>(arena, mrE2, ge2, be2, qv, P, idx, mrPB, gpb, bpb, x, x2);
  k_gemm<false,true><<<dim3(64,8,1),256,0,stream>>>(x2,256, nullptr,nullptr,nullptr,0,
      Wm1,Wm1,Wm1,256, Zm1,512,0, 256, bM1,512,0);
  k_finalize<<<2,256,0,stream>>>(bM1, 512, 1.f/4096.f, mrM1);
  k_gemm<true,true><<<dim3(64,4,1),256,0,stream>>>(Zm1,512, mrM1,gm1,bm1,512,
      Wm2,Wm2,Wm2,512, Zm2,256,0, 512, bM2,256,0);
  k_finalize<<<1,256,0,stream>>>(bM2, 256, 1.f/4096.f, mrM2);
  k_final<<<4096,256,0,stream>>>(x2, Zm2, mrM2, gm2, bm2, (float*)d_out);
}

// Round 8
// 372.586 us; speedup vs baseline: 1.9878x; 1.0631x over previous
//
#include <hip/hip_runtime.h>

#define EPS 1e-5f

typedef __attribute__((ext_vector_type(8))) short s8v;
typedef __attribute__((ext_vector_type(4))) float f4v;

__device__ __forceinline__ float leakyf(float z){ return z >= 0.f ? z : 0.2f*z; }
__device__ __forceinline__ float siluf(float y){ return y / (1.f + __expf(-y)); }
__device__ __forceinline__ unsigned f2bfu(float f){
  unsigned u = __float_as_uint(f);
  return (u + 0x7FFFu + ((u>>16)&1u)) >> 16;
}
__device__ __forceinline__ unsigned short bfr(float f){ return (unsigned short)f2bfu(f); }
__device__ __forceinline__ float bf2f16(unsigned short s){ return __uint_as_float(((unsigned)s)<<16); }

// ---------------- zero scratch ----------------
__global__ __launch_bounds__(256) void k_zero(float* __restrict__ p, int n){
  int i = blockIdx.x*256 + threadIdx.x;
  if (i < n) p[i] = 0.f;
}

// ------- NT GEMM via split-bf16 MFMA, 64x64 tile, 4 waves, register prefetch -------
// z<3 (or z-alt off): C[m,n] = sum_k A'[m,k]*B[n,k]. z==3 with A3: A=A3, C=C3 (P path).
// TRANSA: bn+silu applied to A on load, with BN stats finalized in-kernel from fAbuck.
template<bool TRANSA, bool STATS>
__global__ __launch_bounds__(256) void k_gemm(
    const float* __restrict__ A, int lda,
    const float* __restrict__ A3, int lda3,
    const float* __restrict__ fAbuck, float invnA, int CA,
    const float* __restrict__ gA, const float* __restrict__ bA,
    const float* __restrict__ B0, const float* __restrict__ B1,
    const float* __restrict__ B2, const float* __restrict__ B3, int ldb,
    float* __restrict__ C, int ldc, long cStr,
    float* __restrict__ C3, int ldc3,
    int K, float* __restrict__ buck, int statC, int statChanStr)
{
  __shared__ unsigned short Ah[2048], Al[2048], Bh[2048], Bl[2048];
  __shared__ float Ssum[64], Ssq[64];
  __shared__ float mrA[1024];
  const int z = blockIdx.z;
  const bool zAlt = (A3 != nullptr) && (z == 3);
  const float* Az = zAlt ? A3 : A;
  const int ldaz = zAlt ? lda3 : lda;
  const float* Bb = (z==0?B0 : z==1?B1 : (z==2?B2:B3));
  float* Cb = zAlt ? C3 : (C + (long)z*cStr);
  const int ldcz = zAlt ? ldc3 : ldc;
  const bool doStats = STATS && !zAlt;
  const int tid = threadIdx.x;
  const int bm = blockIdx.x*64, bn = blockIdx.y*64;
  const int wv = tid>>6, lane = tid&63;
  const int lm = lane&15, quad = lane>>4;
  if (doStats && tid<64){ Ssum[tid]=0.f; Ssq[tid]=0.f; }
  if (TRANSA){
    for (int c = tid; c < CA; c += 256){
      float s=0.f, q=0.f;
      for (int b=0;b<64;b++){ s += fAbuck[(long)b*2*CA + c]; q += fAbuck[(long)b*2*CA + CA + c]; }
      float m = s*invnA;
      float v = fmaxf(q*invnA - m*m, 0.f);
      mrA[c] = m; mrA[CA + c] = rsqrtf(v + EPS);
    }
    __syncthreads();
  }

  const int r0 = tid>>3, kg = tid&7;
  const int qk = kg>>1, j0 = (kg&1)*4;
  const int s0 = ((((r0>>4)  )*4 + qk)*16 + ((r0&15)^qk))*8 + j0;
  const int s1 = ((((r0>>4)+2)*4 + qk)*16 + ((r0&15)^qk))*8 + j0;
  const float* aP0 = Az + (long)(bm+r0)*ldaz + kg*4;
  const float* aP1 = aP0 + (long)32*ldaz;
  const float* bP0 = Bb + (long)(bn+r0)*ldb + kg*4;
  const float* bP1 = bP0 + (long)32*ldb;

  f4v acc[4];
  #pragma unroll
  for (int j=0;j<4;j++) acc[j] = (f4v){0.f,0.f,0.f,0.f};

  float4 a0 = *(const float4*)(aP0);
  float4 a1 = *(const float4*)(aP1);
  float4 b0 = *(const float4*)(bP0);
  float4 b1 = *(const float4*)(bP1);

  for (int k0=0; k0<K; k0+=32){
    float4 av0 = a0, av1 = a1;
    if (TRANSA){
      float4 m4 = *(const float4*)&mrA[k0 + kg*4];
      float4 r4 = *(const float4*)&mrA[CA + k0 + kg*4];
      float4 g4 = *(const float4*)(gA + k0 + kg*4);
      float4 b4 = *(const float4*)(bA + k0 + kg*4);
      av0.x = siluf((av0.x - m4.x)*r4.x*g4.x + b4.x);
      av0.y = siluf((av0.y - m4.y)*r4.y*g4.y + b4.y);
      av0.z = siluf((av0.z - m4.z)*r4.z*g4.z + b4.z);
      av0.w = siluf((av0.w - m4.w)*r4.w*g4.w + b4.w);
      av1.x = siluf((av1.x - m4.x)*r4.x*g4.x + b4.x);
      av1.y = siluf((av1.y - m4.y)*r4.y*g4.y + b4.y);
      av1.z = siluf((av1.z - m4.z)*r4.z*g4.z + b4.z);
      av1.w = siluf((av1.w - m4.w)*r4.w*g4.w + b4.w);
    }
    ushort4 h4, l4;
    h4.x=bfr(av0.x); l4.x=bfr(av0.x-bf2f16(h4.x));
    h4.y=bfr(av0.y); l4.y=bfr(av0.y-bf2f16(h4.y));
    h4.z=bfr(av0.z); l4.z=bfr(av0.z-bf2f16(h4.z));
    h4.w=bfr(av0.w); l4.w=bfr(av0.w-bf2f16(h4.w));
    *(ushort4*)&Ah[s0]=h4; *(ushort4*)&Al[s0]=l4;
    h4.x=bfr(av1.x); l4.x=bfr(av1.x-bf2f16(h4.x));
    h4.y=bfr(av1.y); l4.y=bfr(av1.y-bf2f16(h4.y));
    h4.z=bfr(av1.z); l4.z=bfr(av1.z-bf2f16(h4.z));
    h4.w=bfr(av1.w); l4.w=bfr(av1.w-bf2f16(h4.w));
    *(ushort4*)&Ah[s1]=h4; *(ushort4*)&Al[s1]=l4;
    h4.x=bfr(b0.x); l4.x=bfr(b0.x-bf2f16(h4.x));
    h4.y=bfr(b0.y); l4.y=bfr(b0.y-bf2f16(h4.y));
    h4.z=bfr(b0.z); l4.z=bfr(b0.z-bf2f16(h4.z));
    h4.w=bfr(b0.w); l4.w=bfr(b0.w-bf2f16(h4.w));
    *(ushort4*)&Bh[s0]=h4; *(ushort4*)&Bl[s0]=l4;
    h4.x=bfr(b1.x); l4.x=bfr(b1.x-bf2f16(h4.x));
    h4.y=bfr(b1.y); l4.y=bfr(b1.y-bf2f16(h4.y));
    h4.z=bfr(b1.z); l4.z=bfr(b1.z-bf2f16(h4.z));
    h4.w=bfr(b1.w); l4.w=bfr(b1.w-bf2f16(h4.w));
    *(ushort4*)&Bh[s1]=h4; *(ushort4*)&Bl[s1]=l4;
    __syncthreads();
    if (k0+32 < K){
      a0 = *(const float4*)(aP0 + k0+32);
      a1 = *(const float4*)(aP1 + k0+32);
      b0 = *(const float4*)(bP0 + k0+32);
      b1 = *(const float4*)(bP1 + k0+32);
    }
    const int soA = ((wv*4 + quad)*16 + (lm^quad))*8;
    s8v ah = *(const s8v*)&Ah[soA];
    s8v al = *(const s8v*)&Al[soA];
    #pragma unroll
    for (int j=0;j<4;j++){
      const int soB = ((j*4 + quad)*16 + (lm^quad))*8;
      s8v bh = *(const s8v*)&Bh[soB];
      s8v bl = *(const s8v*)&Bl[soB];
      acc[j] = __builtin_amdgcn_mfma_f32_16x16x32_bf16(ah, bh, acc[j], 0,0,0);
      acc[j] = __builtin_amdgcn_mfma_f32_16x16x32_bf16(ah, bl, acc[j], 0,0,0);
      acc[j] = __builtin_amdgcn_mfma_f32_16x16x32_bf16(al, bh, acc[j], 0,0,0);
      acc[j] = __builtin_amdgcn_mfma_f32_16x16x32_bf16(al, bl, acc[j], 0,0,0);
    }
    __syncthreads();
  }
  #pragma unroll
  for (int rr=0;rr<4;rr++){
    float* cr = Cb + (long)(bm + wv*16 + quad*4 + rr)*ldcz + bn + lm;
    #pragma unroll
    for (int j=0;j<4;j++) cr[j*16] = acc[j][rr];
  }
  if (doStats){
    #pragma unroll
    for (int j=0;j<4;j++){
      float s=0.f, q=0.f;
      #pragma unroll
      for (int rr=0;rr<4;rr++){ float v = acc[j][rr]; s += v; q += v*v; }
      s += __shfl_xor(s,16,64); s += __shfl_xor(s,32,64);
      q += __shfl_xor(q,16,64); q += __shfl_xor(q,32,64);
      if (quad==0){ atomicAdd(&Ssum[j*16+lm], s); atomicAdd(&Ssq[j*16+lm], q); }
    }
    __syncthreads();
    if (tid < 64){
      int chan = statChanStr*z + bn + tid;
      float* bb = buck + (long)(blockIdx.x & 63)*2*statC;
      atomicAdd(&bb[chan], Ssum[tid]);
      atomicAdd(&bb[statC + chan], Ssq[tid]);
    }
  }
}

__global__ void k_finalize(const float* __restrict__ buck, int C, float invn, float* __restrict__ mr){
  int c = blockIdx.x*256 + threadIdx.x;
  if (c < C){
    float s=0,q=0;
    for (int b=0;b<64;b++){ s += buck[(long)b*2*C + c]; q += buck[(long)b*2*C + C + c]; }
    float m = s*invn;
    float v = fmaxf(q*invn - m*m, 0.f);
    mr[c] = m; mr[C+c] = rsqrtf(v + EPS);
  }
}

// ---------------- BN+leaky on raw qkv -> key, q|v, sq ----------------
__global__ __launch_bounds__(256) void k_apply_qkv(const float* __restrict__ raw, const float* __restrict__ mr,
    const float* __restrict__ gq, const float* __restrict__ bq,
    const float* __restrict__ gk, const float* __restrict__ bk,
    const float* __restrict__ gv, const float* __restrict__ bv,
    float* __restrict__ key, float* __restrict__ qv, float* __restrict__ sq){
  const int r = blockIdx.x, tid = threadIdx.x;
  __shared__ float red[256];
  const float* row = raw + (long)r*768;
  float zq = row[tid], zk = row[256+tid], zv = row[512+tid];
  float yq = leakyf((zq - mr[tid])*mr[768+tid]*gq[tid] + bq[tid]);
  float yk = leakyf((zk - mr[256+tid])*mr[1024+tid]*gk[tid] + bk[tid]);
  float yv = leakyf((zv - mr[512+tid])*mr[1280+tid]*gv[tid] + bv[tid]);
  qv[(long)r*512 + tid] = yq;
  key[(long)r*256 + tid] = yk;
  qv[(long)r*512 + 256 + tid] = yv;
  red[tid] = yk*yk; __syncthreads();
  for (int off=128; off; off>>=1){ if (tid<off) red[tid] += red[tid+off]; __syncthreads(); }
  if (tid==0) sq[r] = red[0];
}

// ---------------- top-K (K=32) smallest dist per row; one wave per row ----------------
__global__ __launch_bounds__(256) void k_topk(const float* __restrict__ G, const float* __restrict__ sqb,
    int* __restrict__ idxb){
  __shared__ float dist[4][2048];
  const int wv = threadIdx.x >> 6, lane = threadIdx.x & 63;
  const int n = blockIdx.x*4 + wv;
  const float* Grow = G + (long)n*2048;
  const float sqn = sqb[n];
  float lmin = 3.4e38f; int lidx = 0;
  for (int j=0;j<32;j++){
    int m = lane + j*64;
    float d = sqn + sqb[m] - 2.f*Grow[m];
    dist[wv][m] = d;
    if (d < lmin){ lmin = d; lidx = m; }
  }
  int* orow = idxb + n*32;
  for (int t=0;t<32;t++){
    float v = lmin; int i = lidx;
    for (int off=32; off; off>>=1){
      float v2 = __shfl_xor(v, off, 64);
      int i2 = __shfl_xor(i, off, 64);
      if (v2 < v || (v2 == v && i2 < i)){ v = v2; i = i2; }
    }
    if (lane == 0) orow[t] = i;
    if ((i & 63) == lane){
      dist[wv][i] = 3.4e38f;
      lmin = 3.4e38f; lidx = 0;
      for (int j=0;j<32;j++){
        int m = lane + j*64;
        float d = dist[wv][m];
        if (d < lmin){ lmin = d; lidx = m; }
      }
    }
  }
}

// ---------------- stats of z_pb = P[idx]-P[n] ----------------
__global__ __launch_bounds__(256) void k_stats_pb(const float* __restrict__ P, const int* __restrict__ idx,
    float* __restrict__ buck){
  const int c = threadIdx.x;
  float s=0,q=0;
  for (int r = blockIdx.x; r < 4096; r += gridDim.x){
    const long base = (long)(r >> 11) << 11;
    const float pn = P[(long)r*256 + c];
    const int* ir = idx + r*32;
    for (int k=0;k<32;k++){
      int g = ir[k];
      float z = P[(base + g)*256 + c] - pn;
      s += z; q += z*z;
    }
  }
  float* bb = buck + (long)(blockIdx.x & 63)*512;
  atomicAdd(&bb[c], s); atomicAdd(&bb[256+c], q);
}

// ---------------- E1 = (key[g]-q[n]+posb) @ We1^T via MFMA; fused stats ----------------
__global__ __launch_bounds__(256) void k_e1m(
    const float* __restrict__ key, const float* __restrict__ qv, const float* __restrict__ P,
    const int* __restrict__ idx, const float* __restrict__ mrPB,
    const float* __restrict__ gpb, const float* __restrict__ bpb,
    const float* __restrict__ We1, float* __restrict__ E1, float* __restrict__ buckE1)
{
  __shared__ unsigned short Ab[16384];
  __shared__ unsigned short Wb[8192];
  __shared__ float Ssum[32], Ssq[32];
  const int tid = threadIdx.x;
  const int wv = tid>>6, lane = tid&63;
  const int quad = lane>>4, lm = lane&15;
  const int bn0 = blockIdx.x*2;
  if (tid < 32){ Ssum[tid]=0.f; Ssq[tid]=0.f; }
  for (int e = tid; e < 8192; e += 256){
    int d = e >> 8, c = e & 255;
    int off = (((d>>4)*8 + (c>>5))*4 + ((c>>3)&3))*128 + (d&15)*8 + (c&7);
    Wb[off] = bfr(We1[e]);
  }
  {
    const int bn = bn0 + (wv>>1);
    const long base = (long)(bn >> 11) << 11;
    const int c4 = lane*4;
    float4 q4  = *(const float4*)(qv + (long)bn*512 + c4);
    float4 pn4 = *(const float4*)(P + (long)bn*256 + c4);
    float4 mp4 = *(const float4*)(mrPB + c4);
    float4 rp4 = *(const float4*)(mrPB + 256 + c4);
    float4 g4  = *(const float4*)(gpb + c4);
    float4 b4  = *(const float4*)(bpb + c4);
    const int ksc = c4>>5, quadc = (c4>>3)&3, jc = c4&7;
    for (int j = 0; j < 16; ++j){
      const int rloc = wv*16 + j;
      const int kk = rloc & 31;
      const int g = idx[bn*32 + kk];
      float4 kb = *(const float4*)(key + (base+g)*256 + c4);
      float4 pb = *(const float4*)(P + (base+g)*256 + c4);
      float o0 = kb.x - q4.x + leakyf((pb.x - pn4.x - mp4.x)*rp4.x*g4.x + b4.x);
      float o1 = kb.y - q4.y + leakyf((pb.y - pn4.y - mp4.y)*rp4.y*g4.y + b4.y);
      float o2 = kb.z - q4.z + leakyf((pb.z - pn4.z - mp4.z)*rp4.z*g4.z + b4.z);
      float o3 = kb.w - q4.w + leakyf((pb.w - pn4.w - mp4.w)*rp4.w*g4.w + b4.w);
      const int atile = rloc >> 4;
      const int slot = ((rloc & 15) ^ (ksc<<1) ^ quadc) & 15;
      const int off = ((atile*8 + ksc)*4 + quadc)*128 + slot*8 + jc;
      ushort4 u; u.x = bfr(o0); u.y = bfr(o1); u.z = bfr(o2); u.w = bfr(o3);
      *(ushort4*)&Ab[off] = u;
    }
  }
  __syncthreads();
  f4v acc0 = (f4v){0,0,0,0}, acc1 = (f4v){0,0,0,0};
  #pragma unroll
  for (int ks=0; ks<8; ks++){
    const int aslot = (lm ^ (ks<<1) ^ quad) & 15;
    s8v a  = *(const s8v*)&Ab[((wv*8 + ks)*4 + quad)*128 + aslot*8];
    s8v b0 = *(const s8v*)&Wb[((ks)*4 + quad)*128 + lm*8];
    s8v b1 = *(const s8v*)&Wb[((8 + ks)*4 + quad)*128 + lm*8];
    acc0 = __builtin_amdgcn_mfma_f32_16x16x32_bf16(a, b0, acc0, 0,0,0);
    acc1 = __builtin_amdgcn_mfma_f32_16x16x32_bf16(a, b1, acc1, 0,0,0);
  }
  {
    const int bn = bn0 + (wv>>1);
    const int mt = wv & 1;
    #pragma unroll
    for (int rr=0; rr<4; rr++){
      int krow = mt*16 + quad*4 + rr;
      float* o = E1 + ((long)bn*32 + krow)*32;
      o[lm]      = acc0[rr];
      o[16 + lm] = acc1[rr];
    }
  }
  float s0=0,q0=0,s1=0,q1=0;
  #pragma unroll
  for (int rr=0; rr<4; rr++){
    s0 += acc0[rr]; q0 += acc0[rr]*acc0[rr];
    s1 += acc1[rr]; q1 += acc1[rr]*acc1[rr];
  }
  s0 += __shfl_xor(s0,16,64); s0 += __shfl_xor(s0,32,64);
  q0 += __shfl_xor(q0,16,64); q0 += __shfl_xor(q0,32,64);
  s1 += __shfl_xor(s1,16,64); s1 += __shfl_xor(s1,32,64);
  q1 += __shfl_xor(q1,16,64); q1 += __shfl_xor(q1,32,64);
  if (quad == 0){
    atomicAdd(&Ssum[lm], s0);      atomicAdd(&Ssq[lm], q0);
    atomicAdd(&Ssum[16+lm], s1);   atomicAdd(&Ssq[16+lm], q1);
  }
  __syncthreads();
  if (tid < 32){
    float* bb = buckE1 + (long)(blockIdx.x & 63)*64;
    atomicAdd(&bb[tid], Ssum[tid]); atomicAdd(&bb[32+tid], Ssq[tid]);
  }
}

// ---------------- E2 = leaky(bn(E1)) @ We2^T via MFMA, in place; folded E1-finalize; fused stats ----------------
__global__ __launch_bounds__(256) void k_e2m(
    float* __restrict__ E, const float* __restrict__ bE1buck,
    const float* __restrict__ ge1, const float* __restrict__ be1,
    const float* __restrict__ We2, float* __restrict__ buckE2)
{
  __shared__ unsigned short Ab[8192];
  __shared__ unsigned short Wb[1024];
  __shared__ float Ssum[32], Ssq[32];
  __shared__ float mrE1s[64];
  const int tid = threadIdx.x;
  const int wv = tid>>6, lane = tid&63;
  const int quad = lane>>4, lm = lane&15;
  const long r0 = (long)blockIdx.x*256;
  if (tid < 32){
    Ssum[tid]=0.f; Ssq[tid]=0.f;
    float s=0.f, q=0.f;
    for (int b=0;b<64;b++){ s += bE1buck[b*64+tid]; q += bE1buck[b*64+32+tid]; }
    float m = s*(1.f/131072.f);
    float v = fmaxf(q*(1.f/131072.f) - m*m, 0.f);
    mrE1s[tid] = m; mrE1s[32+tid] = rsqrtf(v + EPS);
  }
  for (int e = tid; e < 1024; e += 256){
    int d = e>>5, c = e&31;
    int off = ((d>>4)*4 + ((c>>3)&3))*128 + (d&15)*8 + (c&7);
    Wb[off] = bfr(We2[e]);
  }
  __syncthreads();
  #pragma unroll
  for (int it=0; it<8; it++){
    int e = (tid + it*256)*4;
    int row = e>>5, c = e&31;
    float4 v = *(const float4*)(E + (r0 + row)*32 + c);
    float4 m4 = *(const float4*)&mrE1s[c];
    float4 r4 = *(const float4*)&mrE1s[32+c];
    float4 g4 = *(const float4*)(ge1 + c);
    float4 b4 = *(const float4*)(be1 + c);
    float o0 = leakyf((v.x - m4.x)*r4.x*g4.x + b4.x);
    float o1 = leakyf((v.y - m4.y)*r4.y*g4.y + b4.y);
    float o2 = leakyf((v.z - m4.z)*r4.z*g4.z + b4.z);
    float o3 = leakyf((v.w - m4.w)*r4.w*g4.w + b4.w);
    int quadc = (c>>3)&3, jc = c&7;
    int slot = ((row&15) ^ quadc) & 15;
    int off = ((row>>4)*4 + quadc)*128 + slot*8 + jc;
    ushort4 u; u.x=bfr(o0); u.y=bfr(o1); u.z=bfr(o2); u.w=bfr(o3);
    *(ushort4*)&Ab[off] = u;
  }
  __syncthreads();
  f4v acc0[4], acc1[4];
  #pragma unroll
  for (int i=0;i<4;i++){ acc0[i]=(f4v){0,0,0,0}; acc1[i]=(f4v){0,0,0,0}; }
  const int aslot = (lm ^ quad) & 15;
  s8v b0 = *(const s8v*)&Wb[(quad)*128 + lm*8];
  s8v b1 = *(const s8v*)&Wb[(4 + quad)*128 + lm*8];
  #pragma unroll
  for (int i=0;i<4;i++){
    const int atile = wv*4 + i;
    s8v a = *(const s8v*)&Ab[(atile*4 + quad)*128 + aslot*8];
    acc0[i] = __builtin_amdgcn_mfma_f32_16x16x32_bf16(a, b0, acc0[i], 0,0,0);
    acc1[i] = __builtin_amdgcn_mfma_f32_16x16x32_bf16(a, b1, acc1[i], 0,0,0);
  }
  __syncthreads();
  float s0=0,q0=0,s1=0,q1=0;
  #pragma unroll
  for (int i=0;i<4;i++){
    const int atile = wv*4 + i;
    #pragma unroll
    for (int rr=0; rr<4; rr++){
      long row = r0 + atile*16 + quad*4 + rr;
      float* o = E + row*32;
      o[lm]      = acc0[i][rr];
      o[16 + lm] = acc1[i][rr];
      s0 += acc0[i][rr]; q0 += acc0[i][rr]*acc0[i][rr];
      s1 += acc1[i][rr]; q1 += acc1[i][rr]*acc1[i][rr];
    }
  }
  s0 += __shfl_xor(s0,16,64); s0 += __shfl_xor(s0,32,64);
  q0 += __shfl_xor(q0,16,64); q0 += __shfl_xor(q0,32,64);
  s1 += __shfl_xor(s1,16,64); s1 += __shfl_xor(s1,32,64);
  q1 += __shfl_xor(q1,16,64); q1 += __shfl_xor(q1,32,64);
  if (quad == 0){
    atomicAdd(&Ssum[lm], s0);    atomicAdd(&Ssq[lm], q0);
    atomicAdd(&Ssum[16+lm], s1); atomicAdd(&Ssq[16+lm], q1);
  }
  __syncthreads();
  if (tid < 32){
    float* bb = buckE2 + (long)(blockIdx.x & 63)*64;
    atomicAdd(&bb[tid], Ssum[tid]); atomicAdd(&bb[32+tid], Ssq[tid]);
  }
}

// ---------------- softmax over k + attention + residual (4 bn/block, folded E2-finalize) ----------------
__global__ __launch_bounds__(256) void k_attn(
    const float* __restrict__ E2, const float* __restrict__ bE2buck,
    const float* __restrict__ ge2, const float* __restrict__ be2,
    const float* __restrict__ qv, const float* __restrict__ P, const int* __restrict__ idx,
    const float* __restrict__ mrPB, const float* __restrict__ gpb, const float* __restrict__ bpb,
    const float* __restrict__ xin, float* __restrict__ x2)
{
  __shared__ float L[4][32][33];
  __shared__ float mrE2s[64];
  const int tid = threadIdx.x;
  const int wv = tid>>6, lane = tid&63;
  if (tid < 32){
    float s=0.f, q=0.f;
    for (int b=0;b<64;b++){ s += bE2buck[b*64+tid]; q += bE2buck[b*64+32+tid]; }
    float m = s*(1.f/131072.f);
    float v = fmaxf(q*(1.f/131072.f) - m*m, 0.f);
    mrE2s[tid] = m; mrE2s[32+tid] = rsqrtf(v + EPS);
  }
  __syncthreads();
  const int bn = blockIdx.x*4 + wv;
  const long base = (long)(bn >> 11) << 11;
  for (int qq=0; qq<4; qq++){
    int e = lane*16 + qq*4;
    int k = e >> 5, g0 = e & 31;
    float4 v  = *(const float4*)(E2 + (long)bn*1024 + e);
    float4 m4 = *(const float4*)&mrE2s[g0];
    float4 r4 = *(const float4*)&mrE2s[32+g0];
    float4 g4 = *(const float4*)(ge2 + g0);
    float4 b4 = *(const float4*)(be2 + g0);
    L[wv][k][g0+0] = leakyf((v.x - m4.x)*r4.x*g4.x + b4.x);
    L[wv][k][g0+1] = leakyf((v.y - m4.y)*r4.y*g4.y + b4.y);
    L[wv][k][g0+2] = leakyf((v.z - m4.z)*r4.z*g4.z + b4.z);
    L[wv][k][g0+3] = leakyf((v.w - m4.w)*r4.w*g4.w + b4.w);
  }
  __syncthreads();
  {
    const int g = lane & 31, h = lane >> 5;
    float mx = -3.4e38f;
    for (int j=0;j<16;j++) mx = fmaxf(mx, L[wv][h*16+j][g]);
    mx = fmaxf(mx, __shfl_xor(mx, 32, 64));
    float sm = 0.f, ev[16];
    for (int j=0;j<16;j++){ float e_ = __expf(L[wv][h*16+j][g] - mx); ev[j] = e_; sm += e_; }
    sm += __shfl_xor(sm, 32, 64);
    float inv = 1.f/sm;
    for (int j=0;j<16;j++) L[wv][h*16+j][g] = ev[j]*inv;
  }
  __syncthreads();
  const int c4 = lane*4, gg = lane >> 1;
  float4 pn4 = *(const float4*)(P + (long)bn*256 + c4);
  float4 mp4 = *(const float4*)(mrPB + c4);
  float4 rp4 = *(const float4*)(mrPB + 256 + c4);
  float4 g4 = *(const float4*)(gpb + c4);
  float4 b4 = *(const float4*)(bpb + c4);
  float accv[4] = {0,0,0,0};
  const int* ir = idx + bn*32;
  for (int k=0;k<32;k++){
    int gi = ir[k];
    float4 vv = *(const float4*)(qv + (long)(base+gi)*512 + 256 + c4);
    float4 pp = *(const float4*)(P + (base+gi)*256 + c4);
    float w = L[wv][k][gg];
    float zh0 = (pp.x - pn4.x - mp4.x)*rp4.x*g4.x + b4.x;
    float zh1 = (pp.y - pn4.y - mp4.y)*rp4.y*g4.y + b4.y;
    float zh2 = (pp.z - pn4.z - mp4.z)*rp4.z*g4.z + b4.z;
    float zh3 = (pp.w - pn4.w - mp4.w)*rp4.w*g4.w + b4.w;
    accv[0] = fmaf(vv.x + leakyf(zh0), w, accv[0]);
    accv[1] = fmaf(vv.y + leakyf(zh1), w, accv[1]);
    accv[2] = fmaf(vv.z + leakyf(zh2), w, accv[2]);
    accv[3] = fmaf(vv.w + leakyf(zh3), w, accv[3]);
  }
  float4 x4 = *(const float4*)(xin + (long)bn*256 + c4);
  float4 o;
  o.x = x4.x + accv[0]; o.y = x4.y + accv[1];
  o.z = x4.z + accv[2]; o.w = x4.w + accv[3];
  *(float4*)(x2 + (long)bn*256 + c4) = o;
}

// ---------------- final: out = x2 + silu(bn(Zm2)), folded M2-finalize ----------------
__global__ __launch_bounds__(256) void k_final(const float* __restrict__ x2, const float* __restrict__ Zm2,
    const float* __restrict__ bM2buck, const float* __restrict__ gm, const float* __restrict__ bm,
    float* __restrict__ out){
  __shared__ float mrs[512];
  const int tid = threadIdx.x;
  {
    float s=0.f, q=0.f;
    for (int b=0;b<64;b++){ s += bM2buck[(long)b*512 + tid]; q += bM2buck[(long)b*512 + 256 + tid]; }
    float m = s*(1.f/4096.f);
    float v = fmaxf(q*(1.f/4096.f) - m*m, 0.f);
    mrs[tid] = m; mrs[256+tid] = rsqrtf(v + EPS);
  }
  __syncthreads();
  #pragma unroll
  for (int rr=0; rr<4; rr++){
    long r = (long)blockIdx.x*4 + rr;
    float z = Zm2[r*256 + tid];
    float y = (z - mrs[tid])*mrs[256+tid]*gm[tid] + bm[tid];
    out[r*256 + tid] = x2[r*256 + tid] + siluf(y);
  }
}

extern "C" void kernel_launch(void* const* d_in, const int* in_sizes, int n_in,
                              void* d_out, int out_size, void* d_ws, size_t ws_size,
                              hipStream_t stream){
  (void)in_sizes; (void)n_in; (void)out_size; (void)ws_size;
  const float* x   = (const float*)d_in[0];
  const float* pos = (const float*)d_in[1];
  const float* Wq  = (const float*)d_in[2];
  const float* gq  = (const float*)d_in[3];
  const float* bq  = (const float*)d_in[4];
  const float* Wk  = (const float*)d_in[5];
  const float* gk  = (const float*)d_in[6];
  const float* bk  = (const float*)d_in[7];
  const float* Wv  = (const float*)d_in[8];
  const float* gv  = (const float*)d_in[9];
  const float* bv  = (const float*)d_in[10];
  const float* Wpb = (const float*)d_in[11];
  const float* gpb = (const float*)d_in[12];
  const float* bpb = (const float*)d_in[13];
  const float* We1 = (const float*)d_in[14];
  const float* ge1 = (const float*)d_in[15];
  const float* be1 = (const float*)d_in[16];
  const float* We2 = (const float*)d_in[17];
  const float* ge2 = (const float*)d_in[18];
  const float* be2 = (const float*)d_in[19];
  const float* Wm1 = (const float*)d_in[20];
  const float* gm1 = (const float*)d_in[21];
  const float* bm1 = (const float*)d_in[22];
  const float* Wm2 = (const float*)d_in[23];
  const float* gm2 = (const float*)d_in[24];
  const float* bm2 = (const float*)d_in[25];

  float* w     = (float*)d_ws;
  float* arena = w;                       // 4,194,304: rawQKV / G / E1->E2 / Zm1+Zm2
  float* key   = w + 4194304;             // 1,048,576
  float* P     = w + 5242880;             // 1,048,576
  float* x2    = w + 6291456;             // 1,048,576
  float* qv    = w + 7340032;             // 2,097,152 (q|v per row, stride 512)
  float* sq    = w + 9437184;             // 4,096
  int*   idx   = (int*)(w + 9441280);     // 131,072 ints
  float* buck  = w + 9572352;             // 237,568
  float* mr    = w + 9809920;             // 3,712
  float* bQKV = buck;            float* bPB = buck + 98304;  float* bE1 = buck + 131072;
  float* bE2  = buck + 135168;   float* bM1 = buck + 139264; float* bM2 = buck + 204800;
  float* mrQKV = mr;        float* mrPB = mr + 1536;
  float* Zm1 = arena;
  float* Zm2 = arena + 2097152;

  k_zero<<<928,256,0,stream>>>(buck, 237568);
  // qkv (z=0..2) + P (z=3) in one launch; stats fused for z<3
  k_gemm<false,true><<<dim3(64,4,4),256,0,stream>>>(
      x,256, pos,256, nullptr,0.f,0, nullptr,nullptr,
      Wq,Wk,Wv,Wpb,256, arena,768,256, P,256, 256, bQKV,768,256);
  k_finalize<<<3,256,0,stream>>>(bQKV, 768, 1.f/4096.f, mrQKV);
  k_apply_qkv<<<4096,256,0,stream>>>(arena, mrQKV, gq,bq,gk,bk,gv,bv, key, qv, sq);
  k_gemm<false,false><<<dim3(32,32,1),256,0,stream>>>(
      key,256, nullptr,0, nullptr,0.f,0, nullptr,nullptr,
      key,key,key,nullptr,256, arena,2048,0, nullptr,0, 256, nullptr,0,0);
  k_topk<<<512,256,0,stream>>>(arena, sq, idx);
  k_gemm<false,false><<<dim3(32,32,1),256,0,stream>>>(
      key+524288,256, nullptr,0, nullptr,0.f,0, nullptr,nullptr,
      key+524288,key+524288,key+524288,nullptr,256, arena,2048,0, nullptr,0, 256, nullptr,0,0);
  k_topk<<<512,256,0,stream>>>(arena, sq+2048, idx+65536);
  k_stats_pb<<<1024,256,0,stream>>>(P, idx, bPB);
  k_finalize<<<1,256,0,stream>>>(bPB, 256, 1.f/131072.f, mrPB);
  k_e1m<<<2048,256,0,stream>>>(key, qv, P, idx, mrPB, gpb, bpb, We1, arena, bE1);
  k_e2m<<<512,256,0,stream>>>(arena, bE1, ge1, be1, We2, bE2);
  k_attn<<<1024,256,0,stream>>>(arena, bE2, ge2, be2, qv, P, idx, mrPB, gpb, bpb, x, x2);
  k_gemm<false,true><<<dim3(64,8,1),256,0,stream>>>(
      x2,256, nullptr,0, nullptr,0.f,0, nullptr,nullptr,
      Wm1,Wm1,Wm1,nullptr,256, Zm1,512,0, nullptr,0, 256, bM1,512,0);
  k_gemm<true,true><<<dim3(64,4,1),256,0,stream>>>(
      Zm1,512, nullptr,0, bM1,1.f/4096.f,512, gm1,bm1,
      Wm2,Wm2,Wm2,nullptr,512, Zm2,256,0, nullptr,0, 512, bM2,256,0);
  k_final<<<1024,256,0,stream>>>(x2, Zm2, bM2, gm2, bm2, (float*)d_out);
}

// Round 10
// 358.100 us; speedup vs baseline: 2.0683x; 1.0405x over previous
//
#include <hip/hip_runtime.h>

#define EPS 1e-5f

typedef __attribute__((ext_vector_type(8))) short s8v;
typedef __attribute__((ext_vector_type(4))) float f4v;

__device__ __forceinline__ float leakyf(float z){ return z >= 0.f ? z : 0.2f*z; }
__device__ __forceinline__ float siluf(float y){ return y / (1.f + __expf(-y)); }
__device__ __forceinline__ unsigned f2bfu(float f){
  unsigned u = __float_as_uint(f);
  return (u + 0x7FFFu + ((u>>16)&1u)) >> 16;
}
__device__ __forceinline__ unsigned short bfr(float f){ return (unsigned short)f2bfu(f); }
__device__ __forceinline__ float bf2f16(unsigned short s){ return __uint_as_float(((unsigned)s)<<16); }

// ---------------- zero scratch ----------------
__global__ __launch_bounds__(256) void k_zero(float* __restrict__ p, int n){
  int i = blockIdx.x*256 + threadIdx.x;
  if (i < n) p[i] = 0.f;
}

// ------- NT GEMM via split-bf16 MFMA, 64x64 tile, 4 waves, register prefetch -------
// Az = (z==3 && A3) ? A3 : A + z*aStr ; Bb = {B0..B3}[z] + z*bStr ; Cb per z.
// TRANSA: bn+silu on A-load, stats finalized in-kernel from fAbuck.
// FULL4: include al*bl term (f32-exact — REQUIRED for anything upstream of top-k).
template<bool TRANSA, bool STATS, bool FULL4>
__global__ __launch_bounds__(256) void k_gemm(
    const float* __restrict__ A, int lda, long aStr,
    const float* __restrict__ A3, int lda3,
    const float* __restrict__ fAbuck, float invnA, int CA,
    const float* __restrict__ gA, const float* __restrict__ bA,
    const float* __restrict__ B0, const float* __restrict__ B1,
    const float* __restrict__ B2, const float* __restrict__ B3, int ldb, long bStr,
    float* __restrict__ C, int ldc, long cStr,
    float* __restrict__ C3, int ldc3,
    int K, float* __restrict__ buck, int statC, int statChanStr)
{
  __shared__ unsigned short Ah[2048], Al[2048], Bh[2048], Bl[2048];
  __shared__ float Ssum[STATS?64:4], Ssq[STATS?64:4];
  __shared__ float mrA[TRANSA?1024:4];
  const int z = blockIdx.z;
  const bool zAlt = (A3 != nullptr) && (z == 3);
  const float* Az = zAlt ? A3 : A + (long)z*aStr;
  const int ldaz = zAlt ? lda3 : lda;
  const float* Bb = (z==0?B0 : z==1?B1 : (z==2?B2:B3)) + (long)z*bStr;
  float* Cb = zAlt ? C3 : (C + (long)z*cStr);
  const int ldcz = zAlt ? ldc3 : ldc;
  const bool doStats = STATS && !zAlt;
  const int tid = threadIdx.x;
  const int bm = blockIdx.x*64, bn = blockIdx.y*64;
  const int wv = tid>>6, lane = tid&63;
  const int lm = lane&15, quad = lane>>4;
  if (doStats && tid<64){ Ssum[tid]=0.f; Ssq[tid]=0.f; }
  if (TRANSA){
    for (int c = tid; c < CA; c += 256){
      float s=0.f, q=0.f;
      for (int b=0;b<64;b++){ s += fAbuck[(long)b*2*CA + c]; q += fAbuck[(long)b*2*CA + CA + c]; }
      float m = s*invnA;
      float v = fmaxf(q*invnA - m*m, 0.f);
      mrA[c] = m; mrA[CA + c] = rsqrtf(v + EPS);
    }
    __syncthreads();
  }

  const int r0 = tid>>3, kg = tid&7;
  const int qk = kg>>1, j0 = (kg&1)*4;
  const int s0 = ((((r0>>4)  )*4 + qk)*16 + ((r0&15)^qk))*8 + j0;
  const int s1 = ((((r0>>4)+2)*4 + qk)*16 + ((r0&15)^qk))*8 + j0;
  const float* aP0 = Az + (long)(bm+r0)*ldaz + kg*4;
  const float* aP1 = aP0 + (long)32*ldaz;
  const float* bP0 = Bb + (long)(bn+r0)*ldb + kg*4;
  const float* bP1 = bP0 + (long)32*ldb;

  f4v acc[4];
  #pragma unroll
  for (int j=0;j<4;j++) acc[j] = (f4v){0.f,0.f,0.f,0.f};

  float4 a0 = *(const float4*)(aP0);
  float4 a1 = *(const float4*)(aP1);
  float4 b0 = *(const float4*)(bP0);
  float4 b1 = *(const float4*)(bP1);

  for (int k0=0; k0<K; k0+=32){
    float4 av0 = a0, av1 = a1;
    if (TRANSA){
      float4 m4 = *(const float4*)&mrA[k0 + kg*4];
      float4 r4 = *(const float4*)&mrA[CA + k0 + kg*4];
      float4 g4 = *(const float4*)(gA + k0 + kg*4);
      float4 b4 = *(const float4*)(bA + k0 + kg*4);
      av0.x = siluf((av0.x - m4.x)*r4.x*g4.x + b4.x);
      av0.y = siluf((av0.y - m4.y)*r4.y*g4.y + b4.y);
      av0.z = siluf((av0.z - m4.z)*r4.z*g4.z + b4.z);
      av0.w = siluf((av0.w - m4.w)*r4.w*g4.w + b4.w);
      av1.x = siluf((av1.x - m4.x)*r4.x*g4.x + b4.x);
      av1.y = siluf((av1.y - m4.y)*r4.y*g4.y + b4.y);
      av1.z = siluf((av1.z - m4.z)*r4.z*g4.z + b4.z);
      av1.w = siluf((av1.w - m4.w)*r4.w*g4.w + b4.w);
    }
    ushort4 h4, l4;
    h4.x=bfr(av0.x); l4.x=bfr(av0.x-bf2f16(h4.x));
    h4.y=bfr(av0.y); l4.y=bfr(av0.y-bf2f16(h4.y));
    h4.z=bfr(av0.z); l4.z=bfr(av0.z-bf2f16(h4.z));
    h4.w=bfr(av0.w); l4.w=bfr(av0.w-bf2f16(h4.w));
    *(ushort4*)&Ah[s0]=h4; *(ushort4*)&Al[s0]=l4;
    h4.x=bfr(av1.x); l4.x=bfr(av1.x-bf2f16(h4.x));
    h4.y=bfr(av1.y); l4.y=bfr(av1.y-bf2f16(h4.y));
    h4.z=bfr(av1.z); l4.z=bfr(av1.z-bf2f16(h4.z));
    h4.w=bfr(av1.w); l4.w=bfr(av1.w-bf2f16(h4.w));
    *(ushort4*)&Ah[s1]=h4; *(ushort4*)&Al[s1]=l4;
    h4.x=bfr(b0.x); l4.x=bfr(b0.x-bf2f16(h4.x));
    h4.y=bfr(b0.y); l4.y=bfr(b0.y-bf2f16(h4.y));
    h4.z=bfr(b0.z); l4.z=bfr(b0.z-bf2f16(h4.z));
    h4.w=bfr(b0.w); l4.w=bfr(b0.w-bf2f16(h4.w));
    *(ushort4*)&Bh[s0]=h4; *(ushort4*)&Bl[s0]=l4;
    h4.x=bfr(b1.x); l4.x=bfr(b1.x-bf2f16(h4.x));
    h4.y=bfr(b1.y); l4.y=bfr(b1.y-bf2f16(h4.y));
    h4.z=bfr(b1.z); l4.z=bfr(b1.z-bf2f16(h4.z));
    h4.w=bfr(b1.w); l4.w=bfr(b1.w-bf2f16(h4.w));
    *(ushort4*)&Bh[s1]=h4; *(ushort4*)&Bl[s1]=l4;
    __syncthreads();
    if (k0+32 < K){
      a0 = *(const float4*)(aP0 + k0+32);
      a1 = *(const float4*)(aP1 + k0+32);
      b0 = *(const float4*)(bP0 + k0+32);
      b1 = *(const float4*)(bP1 + k0+32);
    }
    const int soA = ((wv*4 + quad)*16 + (lm^quad))*8;
    s8v ah = *(const s8v*)&Ah[soA];
    s8v al = *(const s8v*)&Al[soA];
    #pragma unroll
    for (int j=0;j<4;j++){
      const int soB = ((j*4 + quad)*16 + (lm^quad))*8;
      s8v bh = *(const s8v*)&Bh[soB];
      s8v bl = *(const s8v*)&Bl[soB];
      acc[j] = __builtin_amdgcn_mfma_f32_16x16x32_bf16(ah, bh, acc[j], 0,0,0);
      acc[j] = __builtin_amdgcn_mfma_f32_16x16x32_bf16(ah, bl, acc[j], 0,0,0);
      acc[j] = __builtin_amdgcn_mfma_f32_16x16x32_bf16(al, bh, acc[j], 0,0,0);
      if (FULL4)
        acc[j] = __builtin_amdgcn_mfma_f32_16x16x32_bf16(al, bl, acc[j], 0,0,0);
    }
    __syncthreads();
  }
  #pragma unroll
  for (int rr=0;rr<4;rr++){
    float* cr = Cb + (long)(bm + wv*16 + quad*4 + rr)*ldcz + bn + lm;
    #pragma unroll
    for (int j=0;j<4;j++) cr[j*16] = acc[j][rr];
  }
  if (doStats){
    #pragma unroll
    for (int j=0;j<4;j++){
      float s=0.f, q=0.f;
      #pragma unroll
      for (int rr=0;rr<4;rr++){ float v = acc[j][rr]; s += v; q += v*v; }
      s += __shfl_xor(s,16,64); s += __shfl_xor(s,32,64);
      q += __shfl_xor(q,16,64); q += __shfl_xor(q,32,64);
      if (quad==0){ atomicAdd(&Ssum[j*16+lm], s); atomicAdd(&Ssq[j*16+lm], q); }
    }
    __syncthreads();
    if (tid < 64){
      int chan = statChanStr*z + bn + tid;
      float* bb = buck + (long)(blockIdx.x & 63)*2*statC;
      atomicAdd(&bb[chan], Ssum[tid]);
      atomicAdd(&bb[statC + chan], Ssq[tid]);
    }
  }
}

__global__ void k_finalize(const float* __restrict__ buck, int C, float invn, float* __restrict__ mr){
  int c = blockIdx.x*256 + threadIdx.x;
  if (c < C){
    float s=0,q=0;
    for (int b=0;b<64;b++){ s += buck[(long)b*2*C + c]; q += buck[(long)b*2*C + C + c]; }
    float m = s*invn;
    float v = fmaxf(q*invn - m*m, 0.f);
    mr[c] = m; mr[C+c] = rsqrtf(v + EPS);
  }
}

// ---------------- BN+leaky on raw qkv -> key, q|v, sq (folds QKV finalize; 8 rows/block) ----------------
__global__ __launch_bounds__(256) void k_apply_qkv(const float* __restrict__ raw, const float* __restrict__ bQKV,
    const float* __restrict__ gq, const float* __restrict__ bq,
    const float* __restrict__ gk, const float* __restrict__ bk,
    const float* __restrict__ gv, const float* __restrict__ bv,
    float* __restrict__ key, float* __restrict__ qv, float* __restrict__ sq){
  __shared__ float mrs[1536];
  __shared__ float red[4];
  const int tid = threadIdx.x;
  const int wv = tid>>6, lane = tid&63;
  for (int c = tid; c < 768; c += 256){
    float s=0.f, q=0.f;
    for (int b=0;b<64;b++){ s += bQKV[(long)b*1536 + c]; q += bQKV[(long)b*1536 + 768 + c]; }
    float m = s*(1.f/4096.f);
    float v = fmaxf(q*(1.f/4096.f) - m*m, 0.f);
    mrs[c] = m; mrs[768+c] = rsqrtf(v + EPS);
  }
  __syncthreads();
  const float gqv = gq[tid], bqv = bq[tid], gkv = gk[tid], bkv = bk[tid], gvv = gv[tid], bvv = bv[tid];
  for (int rr=0; rr<8; rr++){
    const long r = (long)blockIdx.x*8 + rr;
    const float* row = raw + r*768;
    float zq = row[tid], zk = row[256+tid], zv = row[512+tid];
    float yq = leakyf((zq - mrs[tid])*mrs[768+tid]*gqv + bqv);
    float yk = leakyf((zk - mrs[256+tid])*mrs[1024+tid]*gkv + bkv);
    float yv = leakyf((zv - mrs[512+tid])*mrs[1280+tid]*gvv + bvv);
    qv[r*512 + tid] = yq;
    key[r*256 + tid] = yk;
    qv[r*512 + 256 + tid] = yv;
    float kq = yk*yk;
    kq += __shfl_xor(kq,1,64); kq += __shfl_xor(kq,2,64);
    kq += __shfl_xor(kq,4,64); kq += __shfl_xor(kq,8,64);
    kq += __shfl_xor(kq,16,64); kq += __shfl_xor(kq,32,64);
    if (lane==0) red[wv] = kq;
    __syncthreads();
    if (tid==0) sq[r] = red[0]+red[1]+red[2]+red[3];
    __syncthreads();
  }
}

// ---------------- top-K (K=32) per row over both batches; fused z_pb stats epilogue ----------------
__global__ __launch_bounds__(256) void k_topk(const float* __restrict__ G2, const float* __restrict__ sq,
    int* __restrict__ idxb, const float* __restrict__ P, float* __restrict__ bPB){
  __shared__ float dist[4][2048];
  const int wv = threadIdx.x >> 6, lane = threadIdx.x & 63;
  const int row = blockIdx.x*4 + wv;
  const int b = row >> 11, n = row & 2047;
  const float* Grow = G2 + (long)b*4194304 + (long)n*2048;
  const float* sqb = sq + b*2048;
  const float sqn = sqb[n];
  float lmin = 3.4e38f; int lidx = 0;
  for (int j=0;j<32;j++){
    int m = lane + j*64;
    float d = sqn + sqb[m] - 2.f*Grow[m];
    dist[wv][m] = d;
    if (d < lmin){ lmin = d; lidx = m; }
  }
  int* orow = idxb + row*32;
  int myidx[32];
  for (int t=0;t<32;t++){
    float v = lmin; int i = lidx;
    for (int off=32; off; off>>=1){
      float v2 = __shfl_xor(v, off, 64);
      int i2 = __shfl_xor(i, off, 64);
      if (v2 < v || (v2 == v && i2 < i)){ v = v2; i = i2; }
    }
    myidx[t] = i;
    if (lane == 0) orow[t] = i;
    if ((i & 63) == lane){
      dist[wv][i] = 3.4e38f;
      lmin = 3.4e38f; lidx = 0;
      for (int j=0;j<32;j++){
        int m = lane + j*64;
        float d = dist[wv][m];
        if (d < lmin){ lmin = d; lidx = m; }
      }
    }
  }
  // fused z_pb stats: z = P[g] - P[n] over the 32 selected neighbors
  const long base = (long)b << 11;
  const int c4 = lane*4;
  float4 pn = *(const float4*)(P + (long)row*256 + c4);
  float s0=0,s1=0,s2=0,s3=0,q0=0,q1=0,q2=0,q3=0;
  for (int t=0;t<32;t++){
    float4 pg = *(const float4*)(P + (base + myidx[t])*256 + c4);
    float z0 = pg.x - pn.x, z1 = pg.y - pn.y, z2 = pg.z - pn.z, z3 = pg.w - pn.w;
    s0+=z0; q0+=z0*z0; s1+=z1; q1+=z1*z1;
    s2+=z2; q2+=z2*z2; s3+=z3; q3+=z3*z3;
  }
  float* bb = bPB + (long)(blockIdx.x & 63)*512;
  atomicAdd(&bb[c4+0], s0); atomicAdd(&bb[c4+1], s1);
  atomicAdd(&bb[c4+2], s2); atomicAdd(&bb[c4+3], s3);
  atomicAdd(&bb[256+c4+0], q0); atomicAdd(&bb[256+c4+1], q1);
  atomicAdd(&bb[256+c4+2], q2); atomicAdd(&bb[256+c4+3], q3);
}

// ---------------- E1 = (key[g]-q[n]+posb) @ We1^T via MFMA; fused stats ----------------
__global__ __launch_bounds__(256) void k_e1m(
    const float* __restrict__ key, const float* __restrict__ qv, const float* __restrict__ P,
    const int* __restrict__ idx, const float* __restrict__ mrPB,
    const float* __restrict__ gpb, const float* __restrict__ bpb,
    const float* __restrict__ We1, float* __restrict__ E1, float* __restrict__ buckE1)
{
  __shared__ unsigned short Ab[16384];
  __shared__ unsigned short Wb[8192];
  __shared__ float Ssum[32], Ssq[32];
  const int tid = threadIdx.x;
  const int wv = tid>>6, lane = tid&63;
  const int quad = lane>>4, lm = lane&15;
  const int bn0 = blockIdx.x*2;
  if (tid < 32){ Ssum[tid]=0.f; Ssq[tid]=0.f; }
  for (int e = tid; e < 8192; e += 256){
    int d = e >> 8, c = e & 255;
    int off = (((d>>4)*8 + (c>>5))*4 + ((c>>3)&3))*128 + (d&15)*8 + (c&7);
    Wb[off] = bfr(We1[e]);
  }
  {
    const int bn = bn0 + (wv>>1);
    const long base = (long)(bn >> 11) << 11;
    const int c4 = lane*4;
    float4 q4  = *(const float4*)(qv + (long)bn*512 + c4);
    float4 pn4 = *(const float4*)(P + (long)bn*256 + c4);
    float4 mp4 = *(const float4*)(mrPB + c4);
    float4 rp4 = *(const float4*)(mrPB + 256 + c4);
    float4 g4  = *(const float4*)(gpb + c4);
    float4 b4  = *(const float4*)(bpb + c4);
    const int ksc = c4>>5, quadc = (c4>>3)&3, jc = c4&7;
    for (int j = 0; j < 16; ++j){
      const int rloc = wv*16 + j;
      const int kk = rloc & 31;
      const int g = idx[bn*32 + kk];
      float4 kb = *(const float4*)(key + (base+g)*256 + c4);
      float4 pb = *(const float4*)(P + (base+g)*256 + c4);
      float o0 = kb.x - q4.x + leakyf((pb.x - pn4.x - mp4.x)*rp4.x*g4.x + b4.x);
      float o1 = kb.y - q4.y + leakyf((pb.y - pn4.y - mp4.y)*rp4.y*g4.y + b4.y);
      float o2 = kb.z - q4.z + leakyf((pb.z - pn4.z - mp4.z)*rp4.z*g4.z + b4.z);
      float o3 = kb.w - q4.w + leakyf((pb.w - pn4.w - mp4.w)*rp4.w*g4.w + b4.w);
      const int atile = rloc >> 4;
      const int slot = ((rloc & 15) ^ (ksc<<1) ^ quadc) & 15;
      const int off = ((atile*8 + ksc)*4 + quadc)*128 + slot*8 + jc;
      ushort4 u; u.x = bfr(o0); u.y = bfr(o1); u.z = bfr(o2); u.w = bfr(o3);
      *(ushort4*)&Ab[off] = u;
    }
  }
  __syncthreads();
  f4v acc0 = (f4v){0,0,0,0}, acc1 = (f4v){0,0,0,0};
  #pragma unroll
  for (int ks=0; ks<8; ks++){
    const int aslot = (lm ^ (ks<<1) ^ quad) & 15;
    s8v a  = *(const s8v*)&Ab[((wv*8 + ks)*4 + quad)*128 + aslot*8];
    s8v b0 = *(const s8v*)&Wb[((ks)*4 + quad)*128 + lm*8];
    s8v b1 = *(const s8v*)&Wb[((8 + ks)*4 + quad)*128 + lm*8];
    acc0 = __builtin_amdgcn_mfma_f32_16x16x32_bf16(a, b0, acc0, 0,0,0);
    acc1 = __builtin_amdgcn_mfma_f32_16x16x32_bf16(a, b1, acc1, 0,0,0);
  }
  {
    const int bn = bn0 + (wv>>1);
    const int mt = wv & 1;
    #pragma unroll
    for (int rr=0; rr<4; rr++){
      int krow = mt*16 + quad*4 + rr;
      float* o = E1 + ((long)bn*32 + krow)*32;
      o[lm]      = acc0[rr];
      o[16 + lm] = acc1[rr];
    }
  }
  float s0=0,q0=0,s1=0,q1=0;
  #pragma unroll
  for (int rr=0; rr<4; rr++){
    s0 += acc0[rr]; q0 += acc0[rr]*acc0[rr];
    s1 += acc1[rr]; q1 += acc1[rr]*acc1[rr];
  }
  s0 += __shfl_xor(s0,16,64); s0 += __shfl_xor(s0,32,64);
  q0 += __shfl_xor(q0,16,64); q0 += __shfl_xor(q0,32,64);
  s1 += __shfl_xor(s1,16,64); s1 += __shfl_xor(s1,32,64);
  q1 += __shfl_xor(q1,16,64); q1 += __shfl_xor(q1,32,64);
  if (quad == 0){
    atomicAdd(&Ssum[lm], s0);      atomicAdd(&Ssq[lm], q0);
    atomicAdd(&Ssum[16+lm], s1);   atomicAdd(&Ssq[16+lm], q1);
  }
  __syncthreads();
  if (tid < 32){
    float* bb = buckE1 + (long)(blockIdx.x & 63)*64;
    atomicAdd(&bb[tid], Ssum[tid]); atomicAdd(&bb[32+tid], Ssq[tid]);
  }
}

// ---------------- E2 = leaky(bn(E1)) @ We2^T via MFMA, in place; folded E1-finalize; fused stats ----------------
__global__ __launch_bounds__(256) void k_e2m(
    float* __restrict__ E, const float* __restrict__ bE1buck,
    const float* __restrict__ ge1, const float* __restrict__ be1,
    const float* __restrict__ We2, float* __restrict__ buckE2)
{
  __shared__ unsigned short Ab[8192];
  __shared__ unsigned short Wb[1024];
  __shared__ float Ssum[32], Ssq[32];
  __shared__ float mrE1s[64];
  const int tid = threadIdx.x;
  const int wv = tid>>6, lane = tid&63;
  const int quad = lane>>4, lm = lane&15;
  const long r0 = (long)blockIdx.x*256;
  if (tid < 32){
    Ssum[tid]=0.f; Ssq[tid]=0.f;
    float s=0.f, q=0.f;
    for (int b=0;b<64;b++){ s += bE1buck[b*64+tid]; q += bE1buck[b*64+32+tid]; }
    float m = s*(1.f/131072.f);
    float v = fmaxf(q*(1.f/131072.f) - m*m, 0.f);
    mrE1s[tid] = m; mrE1s[32+tid] = rsqrtf(v + EPS);
  }
  for (int e = tid; e < 1024; e += 256){
    int d = e>>5, c = e&31;
    int off = ((d>>4)*4 + ((c>>3)&3))*128 + (d&15)*8 + (c&7);
    Wb[off] = bfr(We2[e]);
  }
  __syncthreads();
  #pragma unroll
  for (int it=0; it<8; it++){
    int e = (tid + it*256)*4;
    int row = e>>5, c = e&31;
    float4 v = *(const float4*)(E + (r0 + row)*32 + c);
    float4 m4 = *(const float4*)&mrE1s[c];
    float4 r4 = *(const float4*)&mrE1s[32+c];
    float4 g4 = *(const float4*)(ge1 + c);
    float4 b4 = *(const float4*)(be1 + c);
    float o0 = leakyf((v.x - m4.x)*r4.x*g4.x + b4.x);
    float o1 = leakyf((v.y - m4.y)*r4.y*g4.y + b4.y);
    float o2 = leakyf((v.z - m4.z)*r4.z*g4.z + b4.z);
    float o3 = leakyf((v.w - m4.w)*r4.w*g4.w + b4.w);
    int quadc = (c>>3)&3, jc = c&7;
    int slot = ((row&15) ^ quadc) & 15;
    int off = ((row>>4)*4 + quadc)*128 + slot*8 + jc;
    ushort4 u; u.x=bfr(o0); u.y=bfr(o1); u.z=bfr(o2); u.w=bfr(o3);
    *(ushort4*)&Ab[off] = u;
  }
  __syncthreads();
  f4v acc0[4], acc1[4];
  #pragma unroll
  for (int i=0;i<4;i++){ acc0[i]=(f4v){0,0,0,0}; acc1[i]=(f4v){0,0,0,0}; }
  const int aslot = (lm ^ quad) & 15;
  s8v b0 = *(const s8v*)&Wb[(quad)*128 + lm*8];
  s8v b1 = *(const s8v*)&Wb[(4 + quad)*128 + lm*8];
  #pragma unroll
  for (int i=0;i<4;i++){
    const int atile = wv*4 + i;
    s8v a = *(const s8v*)&Ab[(atile*4 + quad)*128 + aslot*8];
    acc0[i] = __builtin_amdgcn_mfma_f32_16x16x32_bf16(a, b0, acc0[i], 0,0,0);
    acc1[i] = __builtin_amdgcn_mfma_f32_16x16x32_bf16(a, b1, acc1[i], 0,0,0);
  }
  __syncthreads();
  float s0=0,q0=0,s1=0,q1=0;
  #pragma unroll
  for (int i=0;i<4;i++){
    const int atile = wv*4 + i;
    #pragma unroll
    for (int rr=0; rr<4; rr++){
      long row = r0 + atile*16 + quad*4 + rr;
      float* o = E + row*32;
      o[lm]      = acc0[i][rr];
      o[16 + lm] = acc1[i][rr];
      s0 += acc0[i][rr]; q0 += acc0[i][rr]*acc0[i][rr];
      s1 += acc1[i][rr]; q1 += acc1[i][rr]*acc1[i][rr];
    }
  }
  s0 += __shfl_xor(s0,16,64); s0 += __shfl_xor(s0,32,64);
  q0 += __shfl_xor(q0,16,64); q0 += __shfl_xor(q0,32,64);
  s1 += __shfl_xor(s1,16,64); s1 += __shfl_xor(s1,32,64);
  q1 += __shfl_xor(q1,16,64); q1 += __shfl_xor(q1,32,64);
  if (quad == 0){
    atomicAdd(&Ssum[lm], s0);    atomicAdd(&Ssq[lm], q0);
    atomicAdd(&Ssum[16+lm], s1); atomicAdd(&Ssq[16+lm], q1);
  }
  __syncthreads();
  if (tid < 32){
    float* bb = buckE2 + (long)(blockIdx.x & 63)*64;
    atomicAdd(&bb[tid], Ssum[tid]); atomicAdd(&bb[32+tid], Ssq[tid]);
  }
}

// ---------------- softmax over k + attention + residual (4 bn/block, folded E2-finalize) ----------------
__global__ __launch_bounds__(256) void k_attn(
    const float* __restrict__ E2, const float* __restrict__ bE2buck,
    const float* __restrict__ ge2, const float* __restrict__ be2,
    const float* __restrict__ qv, const float* __restrict__ P, const int* __restrict__ idx,
    const float* __restrict__ mrPB, const float* __restrict__ gpb, const float* __restrict__ bpb,
    const float* __restrict__ xin, float* __restrict__ x2)
{
  __shared__ float L[4][32][33];
  __shared__ float mrE2s[64];
  const int tid = threadIdx.x;
  const int wv = tid>>6, lane = tid&63;
  if (tid < 32){
    float s=0.f, q=0.f;
    for (int b=0;b<64;b++){ s += bE2buck[b*64+tid]; q += bE2buck[b*64+32+tid]; }
    float m = s*(1.f/131072.f);
    float v = fmaxf(q*(1.f/131072.f) - m*m, 0.f);
    mrE2s[tid] = m; mrE2s[32+tid] = rsqrtf(v + EPS);
  }
  __syncthreads();
  const int bn = blockIdx.x*4 + wv;
  const long base = (long)(bn >> 11) << 11;
  for (int qq=0; qq<4; qq++){
    int e = lane*16 + qq*4;
    int k = e >> 5, g0 = e & 31;
    float4 v  = *(const float4*)(E2 + (long)bn*1024 + e);
    float4 m4 = *(const float4*)&mrE2s[g0];
    float4 r4 = *(const float4*)&mrE2s[32+g0];
    float4 g4 = *(const float4*)(ge2 + g0);
    float4 b4 = *(const float4*)(be2 + g0);
    L[wv][k][g0+0] = leakyf((v.x - m4.x)*r4.x*g4.x + b4.x);
    L[wv][k][g0+1] = leakyf((v.y - m4.y)*r4.y*g4.y + b4.y);
    L[wv][k][g0+2] = leakyf((v.z - m4.z)*r4.z*g4.z + b4.z);
    L[wv][k][g0+3] = leakyf((v.w - m4.w)*r4.w*g4.w + b4.w);
  }
  __syncthreads();
  {
    const int g = lane & 31, h = lane >> 5;
    float mx = -3.4e38f;
    for (int j=0;j<16;j++) mx = fmaxf(mx, L[wv][h*16+j][g]);
    mx = fmaxf(mx, __shfl_xor(mx, 32, 64));
    float sm = 0.f, ev[16];
    for (int j=0;j<16;j++){ float e_ = __expf(L[wv][h*16+j][g] - mx); ev[j] = e_; sm += e_; }
    sm += __shfl_xor(sm, 32, 64);
    float inv = 1.f/sm;
    for (int j=0;j<16;j++) L[wv][h*16+j][g] = ev[j]*inv;
  }
  __syncthreads();
  const int c4 = lane*4, gg = lane >> 1;
  float4 pn4 = *(const float4*)(P + (long)bn*256 + c4);
  float4 mp4 = *(const float4*)(mrPB + c4);
  float4 rp4 = *(const float4*)(mrPB + 256 + c4);
  float4 g4 = *(const float4*)(gpb + c4);
  float4 b4 = *(const float4*)(bpb + c4);
  float accv[4] = {0,0,0,0};
  const int* ir = idx + bn*32;
  for (int k=0;k<32;k++){
    int gi = ir[k];
    float4 vv = *(const float4*)(qv + (long)(base+gi)*512 + 256 + c4);
    float4 pp = *(const float4*)(P + (base+gi)*256 + c4);
    float w = L[wv][k][gg];
    float zh0 = (pp.x - pn4.x - mp4.x)*rp4.x*g4.x + b4.x;
    float zh1 = (pp.y - pn4.y - mp4.y)*rp4.y*g4.y + b4.y;
    float zh2 = (pp.z - pn4.z - mp4.z)*rp4.z*g4.z + b4.z;
    float zh3 = (pp.w - pn4.w - mp4.w)*rp4.w*g4.w + b4.w;
    accv[0] = fmaf(vv.x + leakyf(zh0), w, accv[0]);
    accv[1] = fmaf(vv.y + leakyf(zh1), w, accv[1]);
    accv[2] = fmaf(vv.z + leakyf(zh2), w, accv[2]);
    accv[3] = fmaf(vv.w + leakyf(zh3), w, accv[3]);
  }
  float4 x4 = *(const float4*)(xin + (long)bn*256 + c4);
  float4 o;
  o.x = x4.x + accv[0]; o.y = x4.y + accv[1];
  o.z = x4.z + accv[2]; o.w = x4.w + accv[3];
  *(float4*)(x2 + (long)bn*256 + c4) = o;
}

// ---------------- final: out = x2 + silu(bn(Zm2)), folded M2-finalize (8 rows/block) ----------------
__global__ __launch_bounds__(256) void k_final(const float* __restrict__ x2, const float* __restrict__ Zm2,
    const float* __restrict__ bM2buck, const float* __restrict__ gm, const float* __restrict__ bm,
    float* __restrict__ out){
  __shared__ float mrs[512];
  const int tid = threadIdx.x;
  {
    float s=0.f, q=0.f;
    for (int b=0;b<64;b++){ s += bM2buck[(long)b*512 + tid]; q += bM2buck[(long)b*512 + 256 + tid]; }
    float m = s*(1.f/4096.f);
    float v = fmaxf(q*(1.f/4096.f) - m*m, 0.f);
    mrs[tid] = m; mrs[256+tid] = rsqrtf(v + EPS);
  }
  __syncthreads();
  const float gmv = gm[tid], bmv = bm[tid];
  #pragma unroll
  for (int rr=0; rr<8; rr++){
    long r = (long)blockIdx.x*8 + rr;
    float z = Zm2[r*256 + tid];
    float y = (z - mrs[tid])*mrs[256+tid]*gmv + bmv;
    out[r*256 + tid] = x2[r*256 + tid] + siluf(y);
  }
}

extern "C" void kernel_launch(void* const* d_in, const int* in_sizes, int n_in,
                              void* d_out, int out_size, void* d_ws, size_t ws_size,
                              hipStream_t stream){
  (void)in_sizes; (void)n_in; (void)out_size; (void)ws_size;
  const float* x   = (const float*)d_in[0];
  const float* pos = (const float*)d_in[1];
  const float* Wq  = (const float*)d_in[2];
  const float* gq  = (const float*)d_in[3];
  const float* bq  = (const float*)d_in[4];
  const float* Wk  = (const float*)d_in[5];
  const float* gk  = (const float*)d_in[6];
  const float* bk  = (const float*)d_in[7];
  const float* Wv  = (const float*)d_in[8];
  const float* gv  = (const float*)d_in[9];
  const float* bv  = (const float*)d_in[10];
  const float* Wpb = (const float*)d_in[11];
  const float* gpb = (const float*)d_in[12];
  const float* bpb = (const float*)d_in[13];
  const float* We1 = (const float*)d_in[14];
  const float* ge1 = (const float*)d_in[15];
  const float* be1 = (const float*)d_in[16];
  const float* We2 = (const float*)d_in[17];
  const float* ge2 = (const float*)d_in[18];
  const float* be2 = (const float*)d_in[19];
  const float* Wm1 = (const float*)d_in[20];
  const float* gm1 = (const float*)d_in[21];
  const float* bm1 = (const float*)d_in[22];
  const float* Wm2 = (const float*)d_in[23];
  const float* gm2 = (const float*)d_in[24];
  const float* bm2 = (const float*)d_in[25];

  float* w     = (float*)d_ws;
  float* arena = w;                       // 4,194,304: rawQKV / E1->E2 / Zm1+Zm2
  float* key   = w + 4194304;             // 1,048,576
  float* P     = w + 5242880;             // 1,048,576
  float* x2    = w + 6291456;             // 1,048,576
  float* qv    = w + 7340032;             // 2,097,152
  float* sq    = w + 9437184;             // 4,096
  int*   idx   = (int*)(w + 9441280);     // 131,072 ints
  float* buck  = w + 9572352;             // 237,568
  float* mr    = w + 9809920;             // 3,712
  float* G2    = w + 9813632;             // 2 x 4,194,304 (both batch Grams)
  float* bQKV = buck;            float* bPB = buck + 98304;  float* bE1 = buck + 131072;
  float* bE2  = buck + 135168;   float* bM1 = buck + 139264; float* bM2 = buck + 204800;
  float* mrPB = mr + 1536;
  float* Zm1 = arena;
  float* Zm2 = arena + 2097152;

  k_zero<<<928,256,0,stream>>>(buck, 237568);
  // qkv (z=0..2, stats) + P (z=3) in one launch — FULL4: upstream of top-k
  k_gemm<false,true,true><<<dim3(64,4,4),256,0,stream>>>(
      x,256,0, pos,256, nullptr,0.f,0, nullptr,nullptr,
      Wq,Wk,Wv,Wpb,256,0, arena,768,256, P,256, 256, bQKV,768,256);
  k_apply_qkv<<<512,256,0,stream>>>(arena, bQKV, gq,bq,gk,bk,gv,bv, key, qv, sq);
  // both batch Grams in one launch — FULL4: the kNN distances themselves
  k_gemm<false,false,true><<<dim3(32,32,2),256,0,stream>>>(
      key,256,524288, nullptr,0, nullptr,0.f,0, nullptr,nullptr,
      key,key,key,nullptr,256,524288, G2,2048,4194304, nullptr,0, 256, nullptr,0,0);
  // topk over both batches + fused z_pb stats
  k_topk<<<1024,256,0,stream>>>(G2, sq, idx, P, bPB);
  k_finalize<<<1,256,0,stream>>>(bPB, 256, 1.f/131072.f, mrPB);
  k_e1m<<<2048,256,0,stream>>>(key, qv, P, idx, mrPB, gpb, bpb, We1, arena, bE1);
  k_e2m<<<512,256,0,stream>>>(arena, bE1, ge1, be1, We2, bE2);
  k_attn<<<1024,256,0,stream>>>(arena, bE2, ge2, be2, qv, P, idx, mrPB, gpb, bpb, x, x2);
  k_gemm<false,true,false><<<dim3(64,8,1),256,0,stream>>>(
      x2,256,0, nullptr,0, nullptr,0.f,0, nullptr,nullptr,
      Wm1,Wm1,Wm1,nullptr,256,0, Zm1,512,0, nullptr,0, 256, bM1,512,0);
  k_gemm<true,true,false><<<dim3(64,4,1),256,0,stream>>>(
      Zm1,512,0, nullptr,0, bM1,1.f/4096.f,512, gm1,bm1,
      Wm2,Wm2,Wm2,nullptr,512,0, Zm2,256,0, nullptr,0, 512, bM2,256,0);
  k_final<<<512,256,0,stream>>>(x2, Zm2, bM2, gm2, bm2, (float*)d_out);
}

// Round 11
// 346.741 us; speedup vs baseline: 2.1360x; 1.0328x over previous
//
#include <hip/hip_runtime.h>

#define EPS 1e-5f

typedef __attribute__((ext_vector_type(8))) short s8v;
typedef __attribute__((ext_vector_type(4))) float f4v;

__device__ __forceinline__ float leakyf(float z){ return z >= 0.f ? z : 0.2f*z; }
__device__ __forceinline__ float siluf(float y){ return y / (1.f + __expf(-y)); }
__device__ __forceinline__ unsigned f2bfu(float f){
  unsigned u = __float_as_uint(f);
  return (u + 0x7FFFu + ((u>>16)&1u)) >> 16;
}
__device__ __forceinline__ unsigned short bfr(float f){ return (unsigned short)f2bfu(f); }
__device__ __forceinline__ float bf2f16(unsigned short s){ return __uint_as_float(((unsigned)s)<<16); }

// ---------------- zero scratch ----------------
__global__ __launch_bounds__(256) void k_zero(float* __restrict__ p, int n){
  int i = blockIdx.x*256 + threadIdx.x;
  if (i < n) p[i] = 0.f;
}

// ------- NT GEMM via split-bf16 MFMA, 64x64 tile, 4 waves, register prefetch -------
// Az = (z==3 && A3) ? A3 : A + z*aStr ; Bb = {B0..B3}[z] + z*bStr ; Cb per z.
// TRANSA: bn+silu on A-load, stats finalized in-kernel from fAbuck.
// FULL4: include al*bl term (f32-exact — REQUIRED for anything upstream of top-k).
template<bool TRANSA, bool STATS, bool FULL4>
__global__ __launch_bounds__(256) void k_gemm(
    const float* __restrict__ A, int lda, long aStr,
    const float* __restrict__ A3, int lda3,
    const float* __restrict__ fAbuck, float invnA, int CA,
    const float* __restrict__ gA, const float* __restrict__ bA,
    const float* __restrict__ B0, const float* __restrict__ B1,
    const float* __restrict__ B2, const float* __restrict__ B3, int ldb, long bStr,
    float* __restrict__ C, int ldc, long cStr,
    float* __restrict__ C3, int ldc3,
    int K, float* __restrict__ buck, int statC, int statChanStr)
{
  __shared__ unsigned short Ah[2048], Al[2048], Bh[2048], Bl[2048];
  __shared__ float Ssum[STATS?64:4], Ssq[STATS?64:4];
  __shared__ float mrA[TRANSA?1024:4];
  const int z = blockIdx.z;
  const bool zAlt = (A3 != nullptr) && (z == 3);
  const float* Az = zAlt ? A3 : A + (long)z*aStr;
  const int ldaz = zAlt ? lda3 : lda;
  const float* Bb = (z==0?B0 : z==1?B1 : (z==2?B2:B3)) + (long)z*bStr;
  float* Cb = zAlt ? C3 : (C + (long)z*cStr);
  const int ldcz = zAlt ? ldc3 : ldc;
  const bool doStats = STATS && !zAlt;
  const int tid = threadIdx.x;
  const int bm = blockIdx.x*64, bn = blockIdx.y*64;
  const int wv = tid>>6, lane = tid&63;
  const int lm = lane&15, quad = lane>>4;
  if (doStats && tid<64){ Ssum[tid]=0.f; Ssq[tid]=0.f; }
  if (TRANSA){
    for (int c = tid; c < CA; c += 256){
      float s=0.f, q=0.f;
      for (int b=0;b<64;b++){ s += fAbuck[(long)b*2*CA + c]; q += fAbuck[(long)b*2*CA + CA + c]; }
      float m = s*invnA;
      float v = fmaxf(q*invnA - m*m, 0.f);
      mrA[c] = m; mrA[CA + c] = rsqrtf(v + EPS);
    }
    __syncthreads();
  }

  const int r0 = tid>>3, kg = tid&7;
  const int qk = kg>>1, j0 = (kg&1)*4;
  const int s0 = ((((r0>>4)  )*4 + qk)*16 + ((r0&15)^qk))*8 + j0;
  const int s1 = ((((r0>>4)+2)*4 + qk)*16 + ((r0&15)^qk))*8 + j0;
  const float* aP0 = Az + (long)(bm+r0)*ldaz + kg*4;
  const float* aP1 = aP0 + (long)32*ldaz;
  const float* bP0 = Bb + (long)(bn+r0)*ldb + kg*4;
  const float* bP1 = bP0 + (long)32*ldb;

  f4v acc[4];
  #pragma unroll
  for (int j=0;j<4;j++) acc[j] = (f4v){0.f,0.f,0.f,0.f};

  float4 a0 = *(const float4*)(aP0);
  float4 a1 = *(const float4*)(aP1);
  float4 b0 = *(const float4*)(bP0);
  float4 b1 = *(const float4*)(bP1);

  for (int k0=0; k0<K; k0+=32){
    float4 av0 = a0, av1 = a1;
    if (TRANSA){
      float4 m4 = *(const float4*)&mrA[k0 + kg*4];
      float4 r4 = *(const float4*)&mrA[CA + k0 + kg*4];
      float4 g4 = *(const float4*)(gA + k0 + kg*4);
      float4 b4 = *(const float4*)(bA + k0 + kg*4);
      av0.x = siluf((av0.x - m4.x)*r4.x*g4.x + b4.x);
      av0.y = siluf((av0.y - m4.y)*r4.y*g4.y + b4.y);
      av0.z = siluf((av0.z - m4.z)*r4.z*g4.z + b4.z);
      av0.w = siluf((av0.w - m4.w)*r4.w*g4.w + b4.w);
      av1.x = siluf((av1.x - m4.x)*r4.x*g4.x + b4.x);
      av1.y = siluf((av1.y - m4.y)*r4.y*g4.y + b4.y);
      av1.z = siluf((av1.z - m4.z)*r4.z*g4.z + b4.z);
      av1.w = siluf((av1.w - m4.w)*r4.w*g4.w + b4.w);
    }
    ushort4 h4, l4;
    h4.x=bfr(av0.x); l4.x=bfr(av0.x-bf2f16(h4.x));
    h4.y=bfr(av0.y); l4.y=bfr(av0.y-bf2f16(h4.y));
    h4.z=bfr(av0.z); l4.z=bfr(av0.z-bf2f16(h4.z));
    h4.w=bfr(av0.w); l4.w=bfr(av0.w-bf2f16(h4.w));
    *(ushort4*)&Ah[s0]=h4; *(ushort4*)&Al[s0]=l4;
    h4.x=bfr(av1.x); l4.x=bfr(av1.x-bf2f16(h4.x));
    h4.y=bfr(av1.y); l4.y=bfr(av1.y-bf2f16(h4.y));
    h4.z=bfr(av1.z); l4.z=bfr(av1.z-bf2f16(h4.z));
    h4.w=bfr(av1.w); l4.w=bfr(av1.w-bf2f16(h4.w));
    *(ushort4*)&Ah[s1]=h4; *(ushort4*)&Al[s1]=l4;
    h4.x=bfr(b0.x); l4.x=bfr(b0.x-bf2f16(h4.x));
    h4.y=bfr(b0.y); l4.y=bfr(b0.y-bf2f16(h4.y));
    h4.z=bfr(b0.z); l4.z=bfr(b0.z-bf2f16(h4.z));
    h4.w=bfr(b0.w); l4.w=bfr(b0.w-bf2f16(h4.w));
    *(ushort4*)&Bh[s0]=h4; *(ushort4*)&Bl[s0]=l4;
    h4.x=bfr(b1.x); l4.x=bfr(b1.x-bf2f16(h4.x));
    h4.y=bfr(b1.y); l4.y=bfr(b1.y-bf2f16(h4.y));
    h4.z=bfr(b1.z); l4.z=bfr(b1.z-bf2f16(h4.z));
    h4.w=bfr(b1.w); l4.w=bfr(b1.w-bf2f16(h4.w));
    *(ushort4*)&Bh[s1]=h4; *(ushort4*)&Bl[s1]=l4;
    __syncthreads();
    if (k0+32 < K){
      a0 = *(const float4*)(aP0 + k0+32);
      a1 = *(const float4*)(aP1 + k0+32);
      b0 = *(const float4*)(bP0 + k0+32);
      b1 = *(const float4*)(bP1 + k0+32);
    }
    const int soA = ((wv*4 + quad)*16 + (lm^quad))*8;
    s8v ah = *(const s8v*)&Ah[soA];
    s8v al = *(const s8v*)&Al[soA];
    #pragma unroll
    for (int j=0;j<4;j++){
      const int soB = ((j*4 + quad)*16 + (lm^quad))*8;
      s8v bh = *(const s8v*)&Bh[soB];
      s8v bl = *(const s8v*)&Bl[soB];
      acc[j] = __builtin_amdgcn_mfma_f32_16x16x32_bf16(ah, bh, acc[j], 0,0,0);
      acc[j] = __builtin_amdgcn_mfma_f32_16x16x32_bf16(ah, bl, acc[j], 0,0,0);
      acc[j] = __builtin_amdgcn_mfma_f32_16x16x32_bf16(al, bh, acc[j], 0,0,0);
      if (FULL4)
        acc[j] = __builtin_amdgcn_mfma_f32_16x16x32_bf16(al, bl, acc[j], 0,0,0);
    }
    __syncthreads();
  }
  #pragma unroll
  for (int rr=0;rr<4;rr++){
    float* cr = Cb + (long)(bm + wv*16 + quad*4 + rr)*ldcz + bn + lm;
    #pragma unroll
    for (int j=0;j<4;j++) cr[j*16] = acc[j][rr];
  }
  if (doStats){
    #pragma unroll
    for (int j=0;j<4;j++){
      float s=0.f, q=0.f;
      #pragma unroll
      for (int rr=0;rr<4;rr++){ float v = acc[j][rr]; s += v; q += v*v; }
      s += __shfl_xor(s,16,64); s += __shfl_xor(s,32,64);
      q += __shfl_xor(q,16,64); q += __shfl_xor(q,32,64);
      if (quad==0){ atomicAdd(&Ssum[j*16+lm], s); atomicAdd(&Ssq[j*16+lm], q); }
    }
    __syncthreads();
    if (tid < 64){
      int chan = statChanStr*z + bn + tid;
      float* bb = buck + (long)(blockIdx.x & 63)*2*statC;
      atomicAdd(&bb[chan], Ssum[tid]);
      atomicAdd(&bb[statC + chan], Ssq[tid]);
    }
  }
}

__global__ void k_finalize(const float* __restrict__ buck, int C, float invn, float* __restrict__ mr){
  int c = blockIdx.x*256 + threadIdx.x;
  if (c < C){
    float s=0,q=0;
    for (int b=0;b<64;b++){ s += buck[(long)b*2*C + c]; q += buck[(long)b*2*C + C + c]; }
    float m = s*invn;
    float v = fmaxf(q*invn - m*m, 0.f);
    mr[c] = m; mr[C+c] = rsqrtf(v + EPS);
  }
}

// ---------------- BN+leaky on raw qkv -> key, q|v, sq (folds QKV finalize; 8 rows/block) ----------------
__global__ __launch_bounds__(256) void k_apply_qkv(const float* __restrict__ raw, const float* __restrict__ bQKV,
    const float* __restrict__ gq, const float* __restrict__ bq,
    const float* __restrict__ gk, const float* __restrict__ bk,
    const float* __restrict__ gv, const float* __restrict__ bv,
    float* __restrict__ key, float* __restrict__ qv, float* __restrict__ sq){
  __shared__ float mrs[1536];
  __shared__ float red[4];
  const int tid = threadIdx.x;
  const int wv = tid>>6, lane = tid&63;
  for (int c = tid; c < 768; c += 256){
    float s=0.f, q=0.f;
    for (int b=0;b<64;b++){ s += bQKV[(long)b*1536 + c]; q += bQKV[(long)b*1536 + 768 + c]; }
    float m = s*(1.f/4096.f);
    float v = fmaxf(q*(1.f/4096.f) - m*m, 0.f);
    mrs[c] = m; mrs[768+c] = rsqrtf(v + EPS);
  }
  __syncthreads();
  const float gqv = gq[tid], bqv = bq[tid], gkv = gk[tid], bkv = bk[tid], gvv = gv[tid], bvv = bv[tid];
  for (int rr=0; rr<8; rr++){
    const long r = (long)blockIdx.x*8 + rr;
    const float* row = raw + r*768;
    float zq = row[tid], zk = row[256+tid], zv = row[512+tid];
    float yq = leakyf((zq - mrs[tid])*mrs[768+tid]*gqv + bqv);
    float yk = leakyf((zk - mrs[256+tid])*mrs[1024+tid]*gkv + bkv);
    float yv = leakyf((zv - mrs[512+tid])*mrs[1280+tid]*gvv + bvv);
    qv[r*512 + tid] = yq;
    key[r*256 + tid] = yk;
    qv[r*512 + 256 + tid] = yv;
    float kq = yk*yk;
    kq += __shfl_xor(kq,1,64); kq += __shfl_xor(kq,2,64);
    kq += __shfl_xor(kq,4,64); kq += __shfl_xor(kq,8,64);
    kq += __shfl_xor(kq,16,64); kq += __shfl_xor(kq,32,64);
    if (lane==0) red[wv] = kq;
    __syncthreads();
    if (tid==0) sq[r] = red[0]+red[1]+red[2]+red[3];
    __syncthreads();
  }
}

// ---------------- top-K (K=32): per-lane bitonic presort + u64 tournament; fused z_pb stats ----------------
__global__ __launch_bounds__(256) void k_topk(const float* __restrict__ G2, const float* __restrict__ sq,
    int* __restrict__ idxb, const float* __restrict__ P, float* __restrict__ bPB){
  __shared__ float Vs[4*2112];
  __shared__ unsigned short Is[4*2112];
  const int wv = threadIdx.x >> 6, lane = threadIdx.x & 63;
  const int row = blockIdx.x*4 + wv;
  const int b = row >> 11, n = row & 2047;
  const float* Grow = G2 + (long)b*4194304 + (long)n*2048;
  const float* sqb = sq + b*2048;
  const float sqn = sqb[n];
  // keys: (monotonic float bits << 32) | index — ascending u64 == (dist, idx) lexicographic
  unsigned long long key[32];
  #pragma unroll
  for (int j=0;j<32;j++){
    int m = lane + j*64;
    float d = sqn + sqb[m] - 2.f*Grow[m];
    unsigned u = __float_as_uint(d);
    u ^= ((unsigned)((int)u >> 31)) | 0x80000000u;
    key[j] = ((unsigned long long)u << 32) | (unsigned)m;
  }
  // in-register bitonic sort (ascending)
  #pragma unroll
  for (int k=2;k<=32;k<<=1){
    #pragma unroll
    for (int jj=k>>1;jj>0;jj>>=1){
      #pragma unroll
      for (int ii=0;ii<32;ii++){
        int ll = ii ^ jj;
        if (ll > ii){
          bool up = ((ii & k) == 0);
          unsigned long long a = key[ii], c = key[ll];
          bool sw = (a > c) == up;
          key[ii] = sw ? c : a;
          key[ll] = sw ? a : c;
        }
      }
    }
  }
  // spill sorted list (stride-33 padding: conflict-free)
  const int base = wv*2112 + lane*33;
  #pragma unroll
  for (int t=0;t<32;t++){
    Vs[base+t] = __uint_as_float((unsigned)(key[t] >> 32));
    Is[base+t] = (unsigned short)(key[t] & 0xFFFFu);
  }
  unsigned long long hkey = key[0];
  int ptr = 1;
  int* orow = idxb + row*32;
  int myidx[32];
  #pragma unroll
  for (int t=0;t<32;t++){
    unsigned long long v = hkey;
    #pragma unroll
    for (int off=32; off; off>>=1){
      unsigned long long v2 = (unsigned long long)__shfl_xor((long long)v, off, 64);
      if (v2 < v) v = v2;
    }
    int wi = (int)(v & 0xFFFFFFFFull);
    myidx[t] = wi;
    if (lane == 0) orow[t] = wi;
    if (v == hkey){
      if (ptr < 32){
        unsigned uu = __float_as_uint(Vs[base+ptr]);
        hkey = ((unsigned long long)uu << 32) | Is[base+ptr];
      } else {
        hkey = 0xFFFFFFFFFFFFFFFFull;
      }
      ptr++;
    }
  }
  // fused z_pb stats: z = P[g] - P[n] over the 32 selected neighbors
  const long bbase = (long)b << 11;
  const int c4 = lane*4;
  float4 pn = *(const float4*)(P + (long)row*256 + c4);
  float s0=0,s1=0,s2=0,s3=0,q0=0,q1=0,q2=0,q3=0;
  #pragma unroll
  for (int t=0;t<32;t++){
    float4 pg = *(const float4*)(P + (bbase + myidx[t])*256 + c4);
    float z0 = pg.x - pn.x, z1 = pg.y - pn.y, z2 = pg.z - pn.z, z3 = pg.w - pn.w;
    s0+=z0; q0+=z0*z0; s1+=z1; q1+=z1*z1;
    s2+=z2; q2+=z2*z2; s3+=z3; q3+=z3*z3;
  }
  float* bb = bPB + (long)(blockIdx.x & 63)*512;
  atomicAdd(&bb[c4+0], s0); atomicAdd(&bb[c4+1], s1);
  atomicAdd(&bb[c4+2], s2); atomicAdd(&bb[c4+3], s3);
  atomicAdd(&bb[256+c4+0], q0); atomicAdd(&bb[256+c4+1], q1);
  atomicAdd(&bb[256+c4+2], q2); atomicAdd(&bb[256+c4+3], q3);
}

// ---------------- E1 = (key[g]-q[n]+posb) @ We1^T via MFMA; fused stats ----------------
__global__ __launch_bounds__(256) void k_e1m(
    const float* __restrict__ key, const float* __restrict__ qv, const float* __restrict__ P,
    const int* __restrict__ idx, const float* __restrict__ mrPB,
    const float* __restrict__ gpb, const float* __restrict__ bpb,
    const float* __restrict__ We1, float* __restrict__ E1, float* __restrict__ buckE1)
{
  __shared__ unsigned short Ab[16384];
  __shared__ unsigned short Wb[8192];
  __shared__ float Ssum[32], Ssq[32];
  const int tid = threadIdx.x;
  const int wv = tid>>6, lane = tid&63;
  const int quad = lane>>4, lm = lane&15;
  const int bn0 = blockIdx.x*2;
  if (tid < 32){ Ssum[tid]=0.f; Ssq[tid]=0.f; }
  for (int e = tid; e < 8192; e += 256){
    int d = e >> 8, c = e & 255;
    int off = (((d>>4)*8 + (c>>5))*4 + ((c>>3)&3))*128 + (d&15)*8 + (c&7);
    Wb[off] = bfr(We1[e]);
  }
  {
    const int bn = bn0 + (wv>>1);
    const long base = (long)(bn >> 11) << 11;
    const int c4 = lane*4;
    float4 q4  = *(const float4*)(qv + (long)bn*512 + c4);
    float4 pn4 = *(const float4*)(P + (long)bn*256 + c4);
    float4 mp4 = *(const float4*)(mrPB + c4);
    float4 rp4 = *(const float4*)(mrPB + 256 + c4);
    float4 g4  = *(const float4*)(gpb + c4);
    float4 b4  = *(const float4*)(bpb + c4);
    const int ksc = c4>>5, quadc = (c4>>3)&3, jc = c4&7;
    for (int j = 0; j < 16; ++j){
      const int rloc = wv*16 + j;
      const int kk = rloc & 31;
      const int g = idx[bn*32 + kk];
      float4 kb = *(const float4*)(key + (base+g)*256 + c4);
      float4 pb = *(const float4*)(P + (base+g)*256 + c4);
      float o0 = kb.x - q4.x + leakyf((pb.x - pn4.x - mp4.x)*rp4.x*g4.x + b4.x);
      float o1 = kb.y - q4.y + leakyf((pb.y - pn4.y - mp4.y)*rp4.y*g4.y + b4.y);
      float o2 = kb.z - q4.z + leakyf((pb.z - pn4.z - mp4.z)*rp4.z*g4.z + b4.z);
      float o3 = kb.w - q4.w + leakyf((pb.w - pn4.w - mp4.w)*rp4.w*g4.w + b4.w);
      const int atile = rloc >> 4;
      const int slot = ((rloc & 15) ^ (ksc<<1) ^ quadc) & 15;
      const int off = ((atile*8 + ksc)*4 + quadc)*128 + slot*8 + jc;
      ushort4 u; u.x = bfr(o0); u.y = bfr(o1); u.z = bfr(o2); u.w = bfr(o3);
      *(ushort4*)&Ab[off] = u;
    }
  }
  __syncthreads();
  f4v acc0 = (f4v){0,0,0,0}, acc1 = (f4v){0,0,0,0};
  #pragma unroll
  for (int ks=0; ks<8; ks++){
    const int aslot = (lm ^ (ks<<1) ^ quad) & 15;
    s8v a  = *(const s8v*)&Ab[((wv*8 + ks)*4 + quad)*128 + aslot*8];
    s8v b0 = *(const s8v*)&Wb[((ks)*4 + quad)*128 + lm*8];
    s8v b1 = *(const s8v*)&Wb[((8 + ks)*4 + quad)*128 + lm*8];
    acc0 = __builtin_amdgcn_mfma_f32_16x16x32_bf16(a, b0, acc0, 0,0,0);
    acc1 = __builtin_amdgcn_mfma_f32_16x16x32_bf16(a, b1, acc1, 0,0,0);
  }
  {
    const int bn = bn0 + (wv>>1);
    const int mt = wv & 1;
    #pragma unroll
    for (int rr=0; rr<4; rr++){
      int krow = mt*16 + quad*4 + rr;
      float* o = E1 + ((long)bn*32 + krow)*32;
      o[lm]      = acc0[rr];
      o[16 + lm] = acc1[rr];
    }
  }
  float s0=0,q0=0,s1=0,q1=0;
  #pragma unroll
  for (int rr=0; rr<4; rr++){
    s0 += acc0[rr]; q0 += acc0[rr]*acc0[rr];
    s1 += acc1[rr]; q1 += acc1[rr]*acc1[rr];
  }
  s0 += __shfl_xor(s0,16,64); s0 += __shfl_xor(s0,32,64);
  q0 += __shfl_xor(q0,16,64); q0 += __shfl_xor(q0,32,64);
  s1 += __shfl_xor(s1,16,64); s1 += __shfl_xor(s1,32,64);
  q1 += __shfl_xor(q1,16,64); q1 += __shfl_xor(q1,32,64);
  if (quad == 0){
    atomicAdd(&Ssum[lm], s0);      atomicAdd(&Ssq[lm], q0);
    atomicAdd(&Ssum[16+lm], s1);   atomicAdd(&Ssq[16+lm], q1);
  }
  __syncthreads();
  if (tid < 32){
    float* bb = buckE1 + (long)(blockIdx.x & 63)*64;
    atomicAdd(&bb[tid], Ssum[tid]); atomicAdd(&bb[32+tid], Ssq[tid]);
  }
}

// ---------------- E2 = leaky(bn(E1)) @ We2^T via MFMA, in place; folded E1-finalize; fused stats ----------------
__global__ __launch_bounds__(256) void k_e2m(
    float* __restrict__ E, const float* __restrict__ bE1buck,
    const float* __restrict__ ge1, const float* __restrict__ be1,
    const float* __restrict__ We2, float* __restrict__ buckE2)
{
  __shared__ unsigned short Ab[8192];
  __shared__ unsigned short Wb[1024];
  __shared__ float Ssum[32], Ssq[32];
  __shared__ float mrE1s[64];
  const int tid = threadIdx.x;
  const int wv = tid>>6, lane = tid&63;
  const int quad = lane>>4, lm = lane&15;
  const long r0 = (long)blockIdx.x*256;
  if (tid < 32){
    Ssum[tid]=0.f; Ssq[tid]=0.f;
    float s=0.f, q=0.f;
    for (int b=0;b<64;b++){ s += bE1buck[b*64+tid]; q += bE1buck[b*64+32+tid]; }
    float m = s*(1.f/131072.f);
    float v = fmaxf(q*(1.f/131072.f) - m*m, 0.f);
    mrE1s[tid] = m; mrE1s[32+tid] = rsqrtf(v + EPS);
  }
  for (int e = tid; e < 1024; e += 256){
    int d = e>>5, c = e&31;
    int off = ((d>>4)*4 + ((c>>3)&3))*128 + (d&15)*8 + (c&7);
    Wb[off] = bfr(We2[e]);
  }
  __syncthreads();
  #pragma unroll
  for (int it=0; it<8; it++){
    int e = (tid + it*256)*4;
    int row = e>>5, c = e&31;
    float4 v = *(const float4*)(E + (r0 + row)*32 + c);
    float4 m4 = *(const float4*)&mrE1s[c];
    float4 r4 = *(const float4*)&mrE1s[32+c];
    float4 g4 = *(const float4*)(ge1 + c);
    float4 b4 = *(const float4*)(be1 + c);
    float o0 = leakyf((v.x - m4.x)*r4.x*g4.x + b4.x);
    float o1 = leakyf((v.y - m4.y)*r4.y*g4.y + b4.y);
    float o2 = leakyf((v.z - m4.z)*r4.z*g4.z + b4.z);
    float o3 = leakyf((v.w - m4.w)*r4.w*g4.w + b4.w);
    int quadc = (c>>3)&3, jc = c&7;
    int slot = ((row&15) ^ quadc) & 15;
    int off = ((row>>4)*4 + quadc)*128 + slot*8 + jc;
    ushort4 u; u.x=bfr(o0); u.y=bfr(o1); u.z=bfr(o2); u.w=bfr(o3);
    *(ushort4*)&Ab[off] = u;
  }
  __syncthreads();
  f4v acc0[4], acc1[4];
  #pragma unroll
  for (int i=0;i<4;i++){ acc0[i]=(f4v){0,0,0,0}; acc1[i]=(f4v){0,0,0,0}; }
  const int aslot = (lm ^ quad) & 15;
  s8v b0 = *(const s8v*)&Wb[(quad)*128 + lm*8];
  s8v b1 = *(const s8v*)&Wb[(4 + quad)*128 + lm*8];
  #pragma unroll
  for (int i=0;i<4;i++){
    const int atile = wv*4 + i;
    s8v a = *(const s8v*)&Ab[(atile*4 + quad)*128 + aslot*8];
    acc0[i] = __builtin_amdgcn_mfma_f32_16x16x32_bf16(a, b0, acc0[i], 0,0,0);
    acc1[i] = __builtin_amdgcn_mfma_f32_16x16x32_bf16(a, b1, acc1[i], 0,0,0);
  }
  __syncthreads();
  float s0=0,q0=0,s1=0,q1=0;
  #pragma unroll
  for (int i=0;i<4;i++){
    const int atile = wv*4 + i;
    #pragma unroll
    for (int rr=0; rr<4; rr++){
      long row = r0 + atile*16 + quad*4 + rr;
      float* o = E + row*32;
      o[lm]      = acc0[i][rr];
      o[16 + lm] = acc1[i][rr];
      s0 += acc0[i][rr]; q0 += acc0[i][rr]*acc0[i][rr];
      s1 += acc1[i][rr]; q1 += acc1[i][rr]*acc1[i][rr];
    }
  }
  s0 += __shfl_xor(s0,16,64); s0 += __shfl_xor(s0,32,64);
  q0 += __shfl_xor(q0,16,64); q0 += __shfl_xor(q0,32,64);
  s1 += __shfl_xor(s1,16,64); s1 += __shfl_xor(s1,32,64);
  q1 += __shfl_xor(q1,16,64); q1 += __shfl_xor(q1,32,64);
  if (quad == 0){
    atomicAdd(&Ssum[lm], s0);    atomicAdd(&Ssq[lm], q0);
    atomicAdd(&Ssum[16+lm], s1); atomicAdd(&Ssq[16+lm], q1);
  }
  __syncthreads();
  if (tid < 32){
    float* bb = buckE2 + (long)(blockIdx.x & 63)*64;
    atomicAdd(&bb[tid], Ssum[tid]); atomicAdd(&bb[32+tid], Ssq[tid]);
  }
}

// ---------------- softmax over k + attention + residual (4 bn/block, folded E2-finalize) ----------------
__global__ __launch_bounds__(256) void k_attn(
    const float* __restrict__ E2, const float* __restrict__ bE2buck,
    const float* __restrict__ ge2, const float* __restrict__ be2,
    const float* __restrict__ qv, const float* __restrict__ P, const int* __restrict__ idx,
    const float* __restrict__ mrPB, const float* __restrict__ gpb, const float* __restrict__ bpb,
    const float* __restrict__ xin, float* __restrict__ x2)
{
  __shared__ float L[4][32][33];
  __shared__ float mrE2s[64];
  const int tid = threadIdx.x;
  const int wv = tid>>6, lane = tid&63;
  if (tid < 32){
    float s=0.f, q=0.f;
    for (int b=0;b<64;b++){ s += bE2buck[b*64+tid]; q += bE2buck[b*64+32+tid]; }
    float m = s*(1.f/131072.f);
    float v = fmaxf(q*(1.f/131072.f) - m*m, 0.f);
    mrE2s[tid] = m; mrE2s[32+tid] = rsqrtf(v + EPS);
  }
  __syncthreads();
  const int bn = blockIdx.x*4 + wv;
  const long base = (long)(bn >> 11) << 11;
  for (int qq=0; qq<4; qq++){
    int e = lane*16 + qq*4;
    int k = e >> 5, g0 = e & 31;
    float4 v  = *(const float4*)(E2 + (long)bn*1024 + e);
    float4 m4 = *(const float4*)&mrE2s[g0];
    float4 r4 = *(const float4*)&mrE2s[32+g0];
    float4 g4 = *(const float4*)(ge2 + g0);
    float4 b4 = *(const float4*)(be2 + g0);
    L[wv][k][g0+0] = leakyf((v.x - m4.x)*r4.x*g4.x + b4.x);
    L[wv][k][g0+1] = leakyf((v.y - m4.y)*r4.y*g4.y + b4.y);
    L[wv][k][g0+2] = leakyf((v.z - m4.z)*r4.z*g4.z + b4.z);
    L[wv][k][g0+3] = leakyf((v.w - m4.w)*r4.w*g4.w + b4.w);
  }
  __syncthreads();
  {
    const int g = lane & 31, h = lane >> 5;
    float mx = -3.4e38f;
    for (int j=0;j<16;j++) mx = fmaxf(mx, L[wv][h*16+j][g]);
    mx = fmaxf(mx, __shfl_xor(mx, 32, 64));
    float sm = 0.f, ev[16];
    for (int j=0;j<16;j++){ float e_ = __expf(L[wv][h*16+j][g] - mx); ev[j] = e_; sm += e_; }
    sm += __shfl_xor(sm, 32, 64);
    float inv = 1.f/sm;
    for (int j=0;j<16;j++) L[wv][h*16+j][g] = ev[j]*inv;
  }
  __syncthreads();
  const int c4 = lane*4, gg = lane >> 1;
  float4 pn4 = *(const float4*)(P + (long)bn*256 + c4);
  float4 mp4 = *(const float4*)(mrPB + c4);
  float4 rp4 = *(const float4*)(mrPB + 256 + c4);
  float4 g4 = *(const float4*)(gpb + c4);
  float4 b4 = *(const float4*)(bpb + c4);
  float accv[4] = {0,0,0,0};
  const int* ir = idx + bn*32;
  for (int k=0;k<32;k++){
    int gi = ir[k];
    float4 vv = *(const float4*)(qv + (long)(base+gi)*512 + 256 + c4);
    float4 pp = *(const float4*)(P + (base+gi)*256 + c4);
    float w = L[wv][k][gg];
    float zh0 = (pp.x - pn4.x - mp4.x)*rp4.x*g4.x + b4.x;
    float zh1 = (pp.y - pn4.y - mp4.y)*rp4.y*g4.y + b4.y;
    float zh2 = (pp.z - pn4.z - mp4.z)*rp4.z*g4.z + b4.z;
    float zh3 = (pp.w - pn4.w - mp4.w)*rp4.w*g4.w + b4.w;
    accv[0] = fmaf(vv.x + leakyf(zh0), w, accv[0]);
    accv[1] = fmaf(vv.y + leakyf(zh1), w, accv[1]);
    accv[2] = fmaf(vv.z + leakyf(zh2), w, accv[2]);
    accv[3] = fmaf(vv.w + leakyf(zh3), w, accv[3]);
  }
  float4 x4 = *(const float4*)(xin + (long)bn*256 + c4);
  float4 o;
  o.x = x4.x + accv[0]; o.y = x4.y + accv[1];
  o.z = x4.z + accv[2]; o.w = x4.w + accv[3];
  *(float4*)(x2 + (long)bn*256 + c4) = o;
}

// ---------------- final: out = x2 + silu(bn(Zm2)), folded M2-finalize (8 rows/block) ----------------
__global__ __launch_bounds__(256) void k_final(const float* __restrict__ x2, const float* __restrict__ Zm2,
    const float* __restrict__ bM2buck, const float* __restrict__ gm, const float* __restrict__ bm,
    float* __restrict__ out){
  __shared__ float mrs[512];
  const int tid = threadIdx.x;
  {
    float s=0.f, q=0.f;
    for (int b=0;b<64;b++){ s += bM2buck[(long)b*512 + tid]; q += bM2buck[(long)b*512 + 256 + tid]; }
    float m = s*(1.f/4096.f);
    float v = fmaxf(q*(1.f/4096.f) - m*m, 0.f);
    mrs[tid] = m; mrs[256+tid] = rsqrtf(v + EPS);
  }
  __syncthreads();
  const float gmv = gm[tid], bmv = bm[tid];
  #pragma unroll
  for (int rr=0; rr<8; rr++){
    long r = (long)blockIdx.x*8 + rr;
    float z = Zm2[r*256 + tid];
    float y = (z - mrs[tid])*mrs[256+tid]*gmv + bmv;
    out[r*256 + tid] = x2[r*256 + tid] + siluf(y);
  }
}

extern "C" void kernel_launch(void* const* d_in, const int* in_sizes, int n_in,
                              void* d_out, int out_size, void* d_ws, size_t ws_size,
                              hipStream_t stream){
  (void)in_sizes; (void)n_in; (void)out_size; (void)ws_size;
  const float* x   = (const float*)d_in[0];
  const float* pos = (const float*)d_in[1];
  const float* Wq  = (const float*)d_in[2];
  const float* gq  = (const float*)d_in[3];
  const float* bq  = (const float*)d_in[4];
  const float* Wk  = (const float*)d_in[5];
  const float* gk  = (const float*)d_in[6];
  const float* bk  = (const float*)d_in[7];
  const float* Wv  = (const float*)d_in[8];
  const float* gv  = (const float*)d_in[9];
  const float* bv  = (const float*)d_in[10];
  const float* Wpb = (const float*)d_in[11];
  const float* gpb = (const float*)d_in[12];
  const float* bpb = (const float*)d_in[13];
  const float* We1 = (const float*)d_in[14];
  const float* ge1 = (const float*)d_in[15];
  const float* be1 = (const float*)d_in[16];
  const float* We2 = (const float*)d_in[17];
  const float* ge2 = (const float*)d_in[18];
  const float* be2 = (const float*)d_in[19];
  const float* Wm1 = (const float*)d_in[20];
  const float* gm1 = (const float*)d_in[21];
  const float* bm1 = (const float*)d_in[22];
  const float* Wm2 = (const float*)d_in[23];
  const float* gm2 = (const float*)d_in[24];
  const float* bm2 = (const float*)d_in[25];

  float* w     = (float*)d_ws;
  float* arena = w;                       // 4,194,304: rawQKV / E1->E2 / Zm1+Zm2
  float* key   = w + 4194304;             // 1,048,576
  float* P     = w + 5242880;             // 1,048,576
  float* x2    = w + 6291456;             // 1,048,576
  float* qv    = w + 7340032;             // 2,097,152
  float* sq    = w + 9437184;             // 4,096
  int*   idx   = (int*)(w + 9441280);     // 131,072 ints
  float* buck  = w + 9572352;             // 237,568
  float* mr    = w + 9809920;             // 3,712
  float* G2    = w + 9813632;             // 2 x 4,194,304 (both batch Grams)
  float* bQKV = buck;            float* bPB = buck + 98304;  float* bE1 = buck + 131072;
  float* bE2  = buck + 135168;   float* bM1 = buck + 139264; float* bM2 = buck + 204800;
  float* mrPB = mr + 1536;
  float* Zm1 = arena;
  float* Zm2 = arena + 2097152;

  k_zero<<<928,256,0,stream>>>(buck, 237568);
  // qkv (z=0..2, stats) + P (z=3) in one launch — FULL4: upstream of top-k
  k_gemm<false,true,true><<<dim3(64,4,4),256,0,stream>>>(
      x,256,0, pos,256, nullptr,0.f,0, nullptr,nullptr,
      Wq,Wk,Wv,Wpb,256,0, arena,768,256, P,256, 256, bQKV,768,256);
  k_apply_qkv<<<512,256,0,stream>>>(arena, bQKV, gq,bq,gk,bk,gv,bv, key, qv, sq);
  // both batch Grams in one launch — FULL4: the kNN distances themselves
  k_gemm<false,false,true><<<dim3(32,32,2),256,0,stream>>>(
      key,256,524288, nullptr,0, nullptr,0.f,0, nullptr,nullptr,
      key,key,key,nullptr,256,524288, G2,2048,4194304, nullptr,0, 256, nullptr,0,0);
  // topk over both batches + fused z_pb stats
  k_topk<<<1024,256,0,stream>>>(G2, sq, idx, P, bPB);
  k_finalize<<<1,256,0,stream>>>(bPB, 256, 1.f/131072.f, mrPB);
  k_e1m<<<2048,256,0,stream>>>(key, qv, P, idx, mrPB, gpb, bpb, We1, arena, bE1);
  k_e2m<<<512,256,0,stream>>>(arena, bE1, ge1, be1, We2, bE2);
  k_attn<<<1024,256,0,stream>>>(arena, bE2, ge2, be2, qv, P, idx, mrPB, gpb, bpb, x, x2);
  k_gemm<false,true,false><<<dim3(64,8,1),256,0,stream>>>(
      x2,256,0, nullptr,0, nullptr,0.f,0, nullptr,nullptr,
      Wm1,Wm1,Wm1,nullptr,256,0, Zm1,512,0, nullptr,0, 256, bM1,512,0);
  k_gemm<true,true,false><<<dim3(64,4,1),256,0,stream>>>(
      Zm1,512,0, nullptr,0, bM1,1.f/4096.f,512, gm1,bm1,
      Wm2,Wm2,Wm2,nullptr,512,0, Zm2,256,0, nullptr,0, 512, bM2,256,0);
  k_final<<<512,256,0,stream>>>(x2, Zm2, bM2, gm2, bm2, (float*)d_out);
}

// Round 12
// 344.192 us; speedup vs baseline: 2.1518x; 1.0074x over previous
//
#include <hip/hip_runtime.h>

#define EPS 1e-5f

typedef __attribute__((ext_vector_type(8))) short s8v;
typedef __attribute__((ext_vector_type(4))) float f4v;

__device__ __forceinline__ float leakyf(float z){ return z >= 0.f ? z : 0.2f*z; }
__device__ __forceinline__ float siluf(float y){ return y / (1.f + __expf(-y)); }
__device__ __forceinline__ unsigned f2bfu(float f){
  unsigned u = __float_as_uint(f);
  return (u + 0x7FFFu + ((u>>16)&1u)) >> 16;
}
__device__ __forceinline__ unsigned short bfr(float f){ return (unsigned short)f2bfu(f); }
__device__ __forceinline__ float bf2f16(unsigned short s){ return __uint_as_float(((unsigned)s)<<16); }

// ---------------- zero scratch ----------------
__global__ __launch_bounds__(256) void k_zero(float* __restrict__ p, int n){
  int i = blockIdx.x*256 + threadIdx.x;
  if (i < n) p[i] = 0.f;
}

// ------- NT GEMM via split-bf16 MFMA, 64x64 tile, 4 waves, register prefetch -------
// Az = (z==3 && A3) ? A3 : A + z*aStr ; Bb = {B0..B3}[z] + z*bStr ; Cb per z.
// TRANSA: bn+silu on A-load, stats finalized in-kernel from fAbuck.
// FULL4: include al*bl term (f32-exact — REQUIRED for anything upstream of top-k).
template<bool TRANSA, bool STATS, bool FULL4>
__global__ __launch_bounds__(256) void k_gemm(
    const float* __restrict__ A, int lda, long aStr,
    const float* __restrict__ A3, int lda3,
    const float* __restrict__ fAbuck, float invnA, int CA,
    const float* __restrict__ gA, const float* __restrict__ bA,
    const float* __restrict__ B0, const float* __restrict__ B1,
    const float* __restrict__ B2, const float* __restrict__ B3, int ldb, long bStr,
    float* __restrict__ C, int ldc, long cStr,
    float* __restrict__ C3, int ldc3,
    int K, float* __restrict__ buck, int statC, int statChanStr)
{
  __shared__ unsigned short Ah[2048], Al[2048], Bh[2048], Bl[2048];
  __shared__ float Ssum[STATS?64:4], Ssq[STATS?64:4];
  __shared__ float mrA[TRANSA?1024:4];
  const int z = blockIdx.z;
  const bool zAlt = (A3 != nullptr) && (z == 3);
  const float* Az = zAlt ? A3 : A + (long)z*aStr;
  const int ldaz = zAlt ? lda3 : lda;
  const float* Bb = (z==0?B0 : z==1?B1 : (z==2?B2:B3)) + (long)z*bStr;
  float* Cb = zAlt ? C3 : (C + (long)z*cStr);
  const int ldcz = zAlt ? ldc3 : ldc;
  const bool doStats = STATS && !zAlt;
  const int tid = threadIdx.x;
  const int bm = blockIdx.x*64, bn = blockIdx.y*64;
  const int wv = tid>>6, lane = tid&63;
  const int lm = lane&15, quad = lane>>4;
  if (doStats && tid<64){ Ssum[tid]=0.f; Ssq[tid]=0.f; }
  if (TRANSA){
    for (int c = tid; c < CA; c += 256){
      float s=0.f, q=0.f;
      for (int b=0;b<64;b++){ s += fAbuck[(long)b*2*CA + c]; q += fAbuck[(long)b*2*CA + CA + c]; }
      float m = s*invnA;
      float v = fmaxf(q*invnA - m*m, 0.f);
      mrA[c] = m; mrA[CA + c] = rsqrtf(v + EPS);
    }
    __syncthreads();
  }

  const int r0 = tid>>3, kg = tid&7;
  const int qk = kg>>1, j0 = (kg&1)*4;
  const int s0 = ((((r0>>4)  )*4 + qk)*16 + ((r0&15)^qk))*8 + j0;
  const int s1 = ((((r0>>4)+2)*4 + qk)*16 + ((r0&15)^qk))*8 + j0;
  const float* aP0 = Az + (long)(bm+r0)*ldaz + kg*4;
  const float* aP1 = aP0 + (long)32*ldaz;
  const float* bP0 = Bb + (long)(bn+r0)*ldb + kg*4;
  const float* bP1 = bP0 + (long)32*ldb;

  f4v acc[4];
  #pragma unroll
  for (int j=0;j<4;j++) acc[j] = (f4v){0.f,0.f,0.f,0.f};

  float4 a0 = *(const float4*)(aP0);
  float4 a1 = *(const float4*)(aP1);
  float4 b0 = *(const float4*)(bP0);
  float4 b1 = *(const float4*)(bP1);

  for (int k0=0; k0<K; k0+=32){
    float4 av0 = a0, av1 = a1;
    if (TRANSA){
      float4 m4 = *(const float4*)&mrA[k0 + kg*4];
      float4 r4 = *(const float4*)&mrA[CA + k0 + kg*4];
      float4 g4 = *(const float4*)(gA + k0 + kg*4);
      float4 b4 = *(const float4*)(bA + k0 + kg*4);
      av0.x = siluf((av0.x - m4.x)*r4.x*g4.x + b4.x);
      av0.y = siluf((av0.y - m4.y)*r4.y*g4.y + b4.y);
      av0.z = siluf((av0.z - m4.z)*r4.z*g4.z + b4.z);
      av0.w = siluf((av0.w - m4.w)*r4.w*g4.w + b4.w);
      av1.x = siluf((av1.x - m4.x)*r4.x*g4.x + b4.x);
      av1.y = siluf((av1.y - m4.y)*r4.y*g4.y + b4.y);
      av1.z = siluf((av1.z - m4.z)*r4.z*g4.z + b4.z);
      av1.w = siluf((av1.w - m4.w)*r4.w*g4.w + b4.w);
    }
    ushort4 h4, l4;
    h4.x=bfr(av0.x); l4.x=bfr(av0.x-bf2f16(h4.x));
    h4.y=bfr(av0.y); l4.y=bfr(av0.y-bf2f16(h4.y));
    h4.z=bfr(av0.z); l4.z=bfr(av0.z-bf2f16(h4.z));
    h4.w=bfr(av0.w); l4.w=bfr(av0.w-bf2f16(h4.w));
    *(ushort4*)&Ah[s0]=h4; *(ushort4*)&Al[s0]=l4;
    h4.x=bfr(av1.x); l4.x=bfr(av1.x-bf2f16(h4.x));
    h4.y=bfr(av1.y); l4.y=bfr(av1.y-bf2f16(h4.y));
    h4.z=bfr(av1.z); l4.z=bfr(av1.z-bf2f16(h4.z));
    h4.w=bfr(av1.w); l4.w=bfr(av1.w-bf2f16(h4.w));
    *(ushort4*)&Ah[s1]=h4; *(ushort4*)&Al[s1]=l4;
    h4.x=bfr(b0.x); l4.x=bfr(b0.x-bf2f16(h4.x));
    h4.y=bfr(b0.y); l4.y=bfr(b0.y-bf2f16(h4.y));
    h4.z=bfr(b0.z); l4.z=bfr(b0.z-bf2f16(h4.z));
    h4.w=bfr(b0.w); l4.w=bfr(b0.w-bf2f16(h4.w));
    *(ushort4*)&Bh[s0]=h4; *(ushort4*)&Bl[s0]=l4;
    h4.x=bfr(b1.x); l4.x=bfr(b1.x-bf2f16(h4.x));
    h4.y=bfr(b1.y); l4.y=bfr(b1.y-bf2f16(h4.y));
    h4.z=bfr(b1.z); l4.z=bfr(b1.z-bf2f16(h4.z));
    h4.w=bfr(b1.w); l4.w=bfr(b1.w-bf2f16(h4.w));
    *(ushort4*)&Bh[s1]=h4; *(ushort4*)&Bl[s1]=l4;
    __syncthreads();
    if (k0+32 < K){
      a0 = *(const float4*)(aP0 + k0+32);
      a1 = *(const float4*)(aP1 + k0+32);
      b0 = *(const float4*)(bP0 + k0+32);
      b1 = *(const float4*)(bP1 + k0+32);
    }
    const int soA = ((wv*4 + quad)*16 + (lm^quad))*8;
    s8v ah = *(const s8v*)&Ah[soA];
    s8v al = *(const s8v*)&Al[soA];
    #pragma unroll
    for (int j=0;j<4;j++){
      const int soB = ((j*4 + quad)*16 + (lm^quad))*8;
      s8v bh = *(const s8v*)&Bh[soB];
      s8v bl = *(const s8v*)&Bl[soB];
      acc[j] = __builtin_amdgcn_mfma_f32_16x16x32_bf16(ah, bh, acc[j], 0,0,0);
      acc[j] = __builtin_amdgcn_mfma_f32_16x16x32_bf16(ah, bl, acc[j], 0,0,0);
      acc[j] = __builtin_amdgcn_mfma_f32_16x16x32_bf16(al, bh, acc[j], 0,0,0);
      if (FULL4)
        acc[j] = __builtin_amdgcn_mfma_f32_16x16x32_bf16(al, bl, acc[j], 0,0,0);
    }
    __syncthreads();
  }
  #pragma unroll
  for (int rr=0;rr<4;rr++){
    float* cr = Cb + (long)(bm + wv*16 + quad*4 + rr)*ldcz + bn + lm;
    #pragma unroll
    for (int j=0;j<4;j++) cr[j*16] = acc[j][rr];
  }
  if (doStats){
    #pragma unroll
    for (int j=0;j<4;j++){
      float s=0.f, q=0.f;
      #pragma unroll
      for (int rr=0;rr<4;rr++){ float v = acc[j][rr]; s += v; q += v*v; }
      s += __shfl_xor(s,16,64); s += __shfl_xor(s,32,64);
      q += __shfl_xor(q,16,64); q += __shfl_xor(q,32,64);
      if (quad==0){ atomicAdd(&Ssum[j*16+lm], s); atomicAdd(&Ssq[j*16+lm], q); }
    }
    __syncthreads();
    if (tid < 64){
      int chan = statChanStr*z + bn + tid;
      float* bb = buck + (long)(blockIdx.x & 63)*2*statC;
      atomicAdd(&bb[chan], Ssum[tid]);
      atomicAdd(&bb[statC + chan], Ssq[tid]);
    }
  }
}

__global__ void k_finalize(const float* __restrict__ buck, int C, float invn, float* __restrict__ mr){
  int c = blockIdx.x*256 + threadIdx.x;
  if (c < C){
    float s=0,q=0;
    for (int b=0;b<64;b++){ s += buck[(long)b*2*C + c]; q += buck[(long)b*2*C + C + c]; }
    float m = s*invn;
    float v = fmaxf(q*invn - m*m, 0.f);
    mr[c] = m; mr[C+c] = rsqrtf(v + EPS);
  }
}

// ---------------- BN+leaky on raw qkv -> key, q|v, sq (folds QKV finalize; 8 rows/block) ----------------
__global__ __launch_bounds__(256) void k_apply_qkv(const float* __restrict__ raw, const float* __restrict__ bQKV,
    const float* __restrict__ gq, const float* __restrict__ bq,
    const float* __restrict__ gk, const float* __restrict__ bk,
    const float* __restrict__ gv, const float* __restrict__ bv,
    float* __restrict__ key, float* __restrict__ qv, float* __restrict__ sq){
  __shared__ float mrs[1536];
  __shared__ float red[4];
  const int tid = threadIdx.x;
  const int wv = tid>>6, lane = tid&63;
  for (int c = tid; c < 768; c += 256){
    float s=0.f, q=0.f;
    for (int b=0;b<64;b++){ s += bQKV[(long)b*1536 + c]; q += bQKV[(long)b*1536 + 768 + c]; }
    float m = s*(1.f/4096.f);
    float v = fmaxf(q*(1.f/4096.f) - m*m, 0.f);
    mrs[c] = m; mrs[768+c] = rsqrtf(v + EPS);
  }
  __syncthreads();
  const float gqv = gq[tid], bqv = bq[tid], gkv = gk[tid], bkv = bk[tid], gvv = gv[tid], bvv = bv[tid];
  for (int rr=0; rr<8; rr++){
    const long r = (long)blockIdx.x*8 + rr;
    const float* row = raw + r*768;
    float zq = row[tid], zk = row[256+tid], zv = row[512+tid];
    float yq = leakyf((zq - mrs[tid])*mrs[768+tid]*gqv + bqv);
    float yk = leakyf((zk - mrs[256+tid])*mrs[1024+tid]*gkv + bkv);
    float yv = leakyf((zv - mrs[512+tid])*mrs[1280+tid]*gvv + bvv);
    qv[r*512 + tid] = yq;
    key[r*256 + tid] = yk;
    qv[r*512 + 256 + tid] = yv;
    float kq = yk*yk;
    kq += __shfl_xor(kq,1,64); kq += __shfl_xor(kq,2,64);
    kq += __shfl_xor(kq,4,64); kq += __shfl_xor(kq,8,64);
    kq += __shfl_xor(kq,16,64); kq += __shfl_xor(kq,32,64);
    if (lane==0) red[wv] = kq;
    __syncthreads();
    if (tid==0) sq[r] = red[0]+red[1]+red[2]+red[3];
    __syncthreads();
  }
}

// ---------------- top-K (K=32): per-lane min-4 buffer + u64 tournament; fused z_pb stats ----------------
// Keys: (monotonic dist bits << 32) | m  — unique, ascending == (dist, idx) lexicographic.
// Each lane buffers its 4 smallest; rescan (rare: lane owns >=5 winners) reads LDS dist bits.
__global__ __launch_bounds__(256) void k_topk(const float* __restrict__ G2, const float* __restrict__ sq,
    int* __restrict__ idxb, const float* __restrict__ P, float* __restrict__ bPB){
  __shared__ unsigned Ds[4][2048];   // monotonic dist bits, slot == index m (32 KB)
  __shared__ int Ws[4][32];          // per-wave winner list
  const int wv = threadIdx.x >> 6, lane = threadIdx.x & 63;
  const int row = blockIdx.x*4 + wv;
  const int b = row >> 11, n = row & 2047;
  const float* Grow = G2 + (long)b*4194304 + (long)n*2048;
  const float* sqb = sq + b*2048;
  const float sqn = sqb[n];
  const unsigned long long SEN = 0xFFFFFFFFFFFFFFFFull;
  unsigned long long k0=SEN,k1=SEN,k2=SEN,k3=SEN;
  #pragma unroll
  for (int j=0;j<32;j++){
    int m = lane + j*64;
    float d = sqn + sqb[m] - 2.f*Grow[m];
    unsigned u = __float_as_uint(d);
    u ^= ((unsigned)((int)u >> 31)) | 0x80000000u;
    Ds[wv][m] = u;
    unsigned long long kk = ((unsigned long long)u << 32) | (unsigned)m;
    if (kk < k3){
      k3 = kk;
      if (k3 < k2){ unsigned long long t_=k2; k2=k3; k3=t_; }
      if (k2 < k1){ unsigned long long t_=k1; k1=k2; k2=t_; }
      if (k1 < k0){ unsigned long long t_=k0; k0=k1; k1=t_; }
    }
  }
  int* orow = idxb + row*32;
  for (int t=0;t<32;t++){
    unsigned long long v = k0;
    #pragma unroll
    for (int off=32; off; off>>=1){
      unsigned long long v2 = (unsigned long long)__shfl_xor((long long)v, off, 64);
      if (v2 < v) v = v2;
    }
    int wi = (int)(v & 0xFFFFFFFFull);
    if (lane == 0){ orow[t] = wi; Ws[wv][t] = wi; }
    if (v == k0){               // unique owner (keys unique)
      Ds[wv][wi] = 0xFFFFFFFFu; // mark popped (finite dists never map to all-ones)
      k0=k1; k1=k2; k2=k3; k3=SEN;
      if (k0 == SEN){
        // rare refill: rebuild 4 smallest among unpopped slots of this lane
        for (int j=0;j<32;j++){
          int m = lane + j*64;
          unsigned u = Ds[wv][m];
          if (u != 0xFFFFFFFFu){
            unsigned long long kk = ((unsigned long long)u << 32) | (unsigned)m;
            if (kk < k3){
              k3 = kk;
              if (k3 < k2){ unsigned long long t_=k2; k2=k3; k3=t_; }
              if (k2 < k1){ unsigned long long t_=k1; k1=k2; k2=t_; }
              if (k1 < k0){ unsigned long long t_=k0; k0=k1; k1=t_; }
            }
          }
        }
      }
    }
  }
  // fused z_pb stats: z = P[g] - P[n] over the 32 selected neighbors
  const long bbase = (long)b << 11;
  const int c4 = lane*4;
  float4 pn = *(const float4*)(P + (long)row*256 + c4);
  float s0=0,s1=0,s2=0,s3=0,q0=0,q1=0,q2=0,q3=0;
  #pragma unroll
  for (int t=0;t<32;t++){
    float4 pg = *(const float4*)(P + (bbase + Ws[wv][t])*256 + c4);
    float z0 = pg.x - pn.x, z1 = pg.y - pn.y, z2 = pg.z - pn.z, z3 = pg.w - pn.w;
    s0+=z0; q0+=z0*z0; s1+=z1; q1+=z1*z1;
    s2+=z2; q2+=z2*z2; s3+=z3; q3+=z3*z3;
  }
  float* bb = bPB + (long)(blockIdx.x & 63)*512;
  atomicAdd(&bb[c4+0], s0); atomicAdd(&bb[c4+1], s1);
  atomicAdd(&bb[c4+2], s2); atomicAdd(&bb[c4+3], s3);
  atomicAdd(&bb[256+c4+0], q0); atomicAdd(&bb[256+c4+1], q1);
  atomicAdd(&bb[256+c4+2], q2); atomicAdd(&bb[256+c4+3], q3);
}

// ---------------- E1 = (key[g]-q[n]+posb) @ We1^T via MFMA; fused stats ----------------
__global__ __launch_bounds__(256) void k_e1m(
    const float* __restrict__ key, const float* __restrict__ qv, const float* __restrict__ P,
    const int* __restrict__ idx, const float* __restrict__ mrPB,
    const float* __restrict__ gpb, const float* __restrict__ bpb,
    const float* __restrict__ We1, float* __restrict__ E1, float* __restrict__ buckE1)
{
  __shared__ unsigned short Ab[16384];
  __shared__ unsigned short Wb[8192];
  __shared__ float Ssum[32], Ssq[32];
  const int tid = threadIdx.x;
  const int wv = tid>>6, lane = tid&63;
  const int quad = lane>>4, lm = lane&15;
  const int bn0 = blockIdx.x*2;
  if (tid < 32){ Ssum[tid]=0.f; Ssq[tid]=0.f; }
  for (int e = tid; e < 8192; e += 256){
    int d = e >> 8, c = e & 255;
    int off = (((d>>4)*8 + (c>>5))*4 + ((c>>3)&3))*128 + (d&15)*8 + (c&7);
    Wb[off] = bfr(We1[e]);
  }
  {
    const int bn = bn0 + (wv>>1);
    const long base = (long)(bn >> 11) << 11;
    const int c4 = lane*4;
    float4 q4  = *(const float4*)(qv + (long)bn*512 + c4);
    float4 pn4 = *(const float4*)(P + (long)bn*256 + c4);
    float4 mp4 = *(const float4*)(mrPB + c4);
    float4 rp4 = *(const float4*)(mrPB + 256 + c4);
    float4 g4  = *(const float4*)(gpb + c4);
    float4 b4  = *(const float4*)(bpb + c4);
    const int ksc = c4>>5, quadc = (c4>>3)&3, jc = c4&7;
    for (int j = 0; j < 16; ++j){
      const int rloc = wv*16 + j;
      const int kk = rloc & 31;
      const int g = idx[bn*32 + kk];
      float4 kb = *(const float4*)(key + (base+g)*256 + c4);
      float4 pb = *(const float4*)(P + (base+g)*256 + c4);
      float o0 = kb.x - q4.x + leakyf((pb.x - pn4.x - mp4.x)*rp4.x*g4.x + b4.x);
      float o1 = kb.y - q4.y + leakyf((pb.y - pn4.y - mp4.y)*rp4.y*g4.y + b4.y);
      float o2 = kb.z - q4.z + leakyf((pb.z - pn4.z - mp4.z)*rp4.z*g4.z + b4.z);
      float o3 = kb.w - q4.w + leakyf((pb.w - pn4.w - mp4.w)*rp4.w*g4.w + b4.w);
      const int atile = rloc >> 4;
      const int slot = ((rloc & 15) ^ (ksc<<1) ^ quadc) & 15;
      const int off = ((atile*8 + ksc)*4 + quadc)*128 + slot*8 + jc;
      ushort4 u; u.x = bfr(o0); u.y = bfr(o1); u.z = bfr(o2); u.w = bfr(o3);
      *(ushort4*)&Ab[off] = u;
    }
  }
  __syncthreads();
  f4v acc0 = (f4v){0,0,0,0}, acc1 = (f4v){0,0,0,0};
  #pragma unroll
  for (int ks=0; ks<8; ks++){
    const int aslot = (lm ^ (ks<<1) ^ quad) & 15;
    s8v a  = *(const s8v*)&Ab[((wv*8 + ks)*4 + quad)*128 + aslot*8];
    s8v b0 = *(const s8v*)&Wb[((ks)*4 + quad)*128 + lm*8];
    s8v b1 = *(const s8v*)&Wb[((8 + ks)*4 + quad)*128 + lm*8];
    acc0 = __builtin_amdgcn_mfma_f32_16x16x32_bf16(a, b0, acc0, 0,0,0);
    acc1 = __builtin_amdgcn_mfma_f32_16x16x32_bf16(a, b1, acc1, 0,0,0);
  }
  {
    const int bn = bn0 + (wv>>1);
    const int mt = wv & 1;
    #pragma unroll
    for (int rr=0; rr<4; rr++){
      int krow = mt*16 + quad*4 + rr;
      float* o = E1 + ((long)bn*32 + krow)*32;
      o[lm]      = acc0[rr];
      o[16 + lm] = acc1[rr];
    }
  }
  float s0=0,q0=0,s1=0,q1=0;
  #pragma unroll
  for (int rr=0; rr<4; rr++){
    s0 += acc0[rr]; q0 += acc0[rr]*acc0[rr];
    s1 += acc1[rr]; q1 += acc1[rr]*acc1[rr];
  }
  s0 += __shfl_xor(s0,16,64); s0 += __shfl_xor(s0,32,64);
  q0 += __shfl_xor(q0,16,64); q0 += __shfl_xor(q0,32,64);
  s1 += __shfl_xor(s1,16,64); s1 += __shfl_xor(s1,32,64);
  q1 += __shfl_xor(q1,16,64); q1 += __shfl_xor(q1,32,64);
  if (quad == 0){
    atomicAdd(&Ssum[lm], s0);      atomicAdd(&Ssq[lm], q0);
    atomicAdd(&Ssum[16+lm], s1);   atomicAdd(&Ssq[16+lm], q1);
  }
  __syncthreads();
  if (tid < 32){
    float* bb = buckE1 + (long)(blockIdx.x & 63)*64;
    atomicAdd(&bb[tid], Ssum[tid]); atomicAdd(&bb[32+tid], Ssq[tid]);
  }
}

// ---------------- E2 = leaky(bn(E1)) @ We2^T via MFMA, in place; folded E1-finalize; fused stats ----------------
__global__ __launch_bounds__(256) void k_e2m(
    float* __restrict__ E, const float* __restrict__ bE1buck,
    const float* __restrict__ ge1, const float* __restrict__ be1,
    const float* __restrict__ We2, float* __restrict__ buckE2)
{
  __shared__ unsigned short Ab[8192];
  __shared__ unsigned short Wb[1024];
  __shared__ float Ssum[32], Ssq[32];
  __shared__ float mrE1s[64];
  const int tid = threadIdx.x;
  const int wv = tid>>6, lane = tid&63;
  const int quad = lane>>4, lm = lane&15;
  const long r0 = (long)blockIdx.x*256;
  if (tid < 32){
    Ssum[tid]=0.f; Ssq[tid]=0.f;
    float s=0.f, q=0.f;
    for (int b=0;b<64;b++){ s += bE1buck[b*64+tid]; q += bE1buck[b*64+32+tid]; }
    float m = s*(1.f/131072.f);
    float v = fmaxf(q*(1.f/131072.f) - m*m, 0.f);
    mrE1s[tid] = m; mrE1s[32+tid] = rsqrtf(v + EPS);
  }
  for (int e = tid; e < 1024; e += 256){
    int d = e>>5, c = e&31;
    int off = ((d>>4)*4 + ((c>>3)&3))*128 + (d&15)*8 + (c&7);
    Wb[off] = bfr(We2[e]);
  }
  __syncthreads();
  #pragma unroll
  for (int it=0; it<8; it++){
    int e = (tid + it*256)*4;
    int row = e>>5, c = e&31;
    float4 v = *(const float4*)(E + (r0 + row)*32 + c);
    float4 m4 = *(const float4*)&mrE1s[c];
    float4 r4 = *(const float4*)&mrE1s[32+c];
    float4 g4 = *(const float4*)(ge1 + c);
    float4 b4 = *(const float4*)(be1 + c);
    float o0 = leakyf((v.x - m4.x)*r4.x*g4.x + b4.x);
    float o1 = leakyf((v.y - m4.y)*r4.y*g4.y + b4.y);
    float o2 = leakyf((v.z - m4.z)*r4.z*g4.z + b4.z);
    float o3 = leakyf((v.w - m4.w)*r4.w*g4.w + b4.w);
    int quadc = (c>>3)&3, jc = c&7;
    int slot = ((row&15) ^ quadc) & 15;
    int off = ((row>>4)*4 + quadc)*128 + slot*8 + jc;
    ushort4 u; u.x=bfr(o0); u.y=bfr(o1); u.z=bfr(o2); u.w=bfr(o3);
    *(ushort4*)&Ab[off] = u;
  }
  __syncthreads();
  f4v acc0[4], acc1[4];
  #pragma unroll
  for (int i=0;i<4;i++){ acc0[i]=(f4v){0,0,0,0}; acc1[i]=(f4v){0,0,0,0}; }
  const int aslot = (lm ^ quad) & 15;
  s8v b0 = *(const s8v*)&Wb[(quad)*128 + lm*8];
  s8v b1 = *(const s8v*)&Wb[(4 + quad)*128 + lm*8];
  #pragma unroll
  for (int i=0;i<4;i++){
    const int atile = wv*4 + i;
    s8v a = *(const s8v*)&Ab[(atile*4 + quad)*128 + aslot*8];
    acc0[i] = __builtin_amdgcn_mfma_f32_16x16x32_bf16(a, b0, acc0[i], 0,0,0);
    acc1[i] = __builtin_amdgcn_mfma_f32_16x16x32_bf16(a, b1, acc1[i], 0,0,0);
  }
  __syncthreads();
  float s0=0,q0=0,s1=0,q1=0;
  #pragma unroll
  for (int i=0;i<4;i++){
    const int atile = wv*4 + i;
    #pragma unroll
    for (int rr=0; rr<4; rr++){
      long row = r0 + atile*16 + quad*4 + rr;
      float* o = E + row*32;
      o[lm]      = acc0[i][rr];
      o[16 + lm] = acc1[i][rr];
      s0 += acc0[i][rr]; q0 += acc0[i][rr]*acc0[i][rr];
      s1 += acc1[i][rr]; q1 += acc1[i][rr]*acc1[i][rr];
    }
  }
  s0 += __shfl_xor(s0,16,64); s0 += __shfl_xor(s0,32,64);
  q0 += __shfl_xor(q0,16,64); q0 += __shfl_xor(q0,32,64);
  s1 += __shfl_xor(s1,16,64); s1 += __shfl_xor(s1,32,64);
  q1 += __shfl_xor(q1,16,64); q1 += __shfl_xor(q1,32,64);
  if (quad == 0){
    atomicAdd(&Ssum[lm], s0);    atomicAdd(&Ssq[lm], q0);
    atomicAdd(&Ssum[16+lm], s1); atomicAdd(&Ssq[16+lm], q1);
  }
  __syncthreads();
  if (tid < 32){
    float* bb = buckE2 + (long)(blockIdx.x & 63)*64;
    atomicAdd(&bb[tid], Ssum[tid]); atomicAdd(&bb[32+tid], Ssq[tid]);
  }
}

// ---------------- softmax over k + attention + residual (4 bn/block, folded E2-finalize) ----------------
__global__ __launch_bounds__(256) void k_attn(
    const float* __restrict__ E2, const float* __restrict__ bE2buck,
    const float* __restrict__ ge2, const float* __restrict__ be2,
    const float* __restrict__ qv, const float* __restrict__ P, const int* __restrict__ idx,
    const float* __restrict__ mrPB, const float* __restrict__ gpb, const float* __restrict__ bpb,
    const float* __restrict__ xin, float* __restrict__ x2)
{
  __shared__ float L[4][32][33];
  __shared__ float mrE2s[64];
  const int tid = threadIdx.x;
  const int wv = tid>>6, lane = tid&63;
  if (tid < 32){
    float s=0.f, q=0.f;
    for (int b=0;b<64;b++){ s += bE2buck[b*64+tid]; q += bE2buck[b*64+32+tid]; }
    float m = s*(1.f/131072.f);
    float v = fmaxf(q*(1.f/131072.f) - m*m, 0.f);
    mrE2s[tid] = m; mrE2s[32+tid] = rsqrtf(v + EPS);
  }
  __syncthreads();
  const int bn = blockIdx.x*4 + wv;
  const long base = (long)(bn >> 11) << 11;
  for (int qq=0; qq<4; qq++){
    int e = lane*16 + qq*4;
    int k = e >> 5, g0 = e & 31;
    float4 v  = *(const float4*)(E2 + (long)bn*1024 + e);
    float4 m4 = *(const float4*)&mrE2s[g0];
    float4 r4 = *(const float4*)&mrE2s[32+g0];
    float4 g4 = *(const float4*)(ge2 + g0);
    float4 b4 = *(const float4*)(be2 + g0);
    L[wv][k][g0+0] = leakyf((v.x - m4.x)*r4.x*g4.x + b4.x);
    L[wv][k][g0+1] = leakyf((v.y - m4.y)*r4.y*g4.y + b4.y);
    L[wv][k][g0+2] = leakyf((v.z - m4.z)*r4.z*g4.z + b4.z);
    L[wv][k][g0+3] = leakyf((v.w - m4.w)*r4.w*g4.w + b4.w);
  }
  __syncthreads();
  {
    const int g = lane & 31, h = lane >> 5;
    float mx = -3.4e38f;
    for (int j=0;j<16;j++) mx = fmaxf(mx, L[wv][h*16+j][g]);
    mx = fmaxf(mx, __shfl_xor(mx, 32, 64));
    float sm = 0.f, ev[16];
    for (int j=0;j<16;j++){ float e_ = __expf(L[wv][h*16+j][g] - mx); ev[j] = e_; sm += e_; }
    sm += __shfl_xor(sm, 32, 64);
    float inv = 1.f/sm;
    for (int j=0;j<16;j++) L[wv][h*16+j][g] = ev[j]*inv;
  }
  __syncthreads();
  const int c4 = lane*4, gg = lane >> 1;
  float4 pn4 = *(const float4*)(P + (long)bn*256 + c4);
  float4 mp4 = *(const float4*)(mrPB + c4);
  float4 rp4 = *(const float4*)(mrPB + 256 + c4);
  float4 g4 = *(const float4*)(gpb + c4);
  float4 b4 = *(const float4*)(bpb + c4);
  float accv[4] = {0,0,0,0};
  const int* ir = idx + bn*32;
  for (int k=0;k<32;k++){
    int gi = ir[k];
    float4 vv = *(const float4*)(qv + (long)(base+gi)*512 + 256 + c4);
    float4 pp = *(const float4*)(P + (base+gi)*256 + c4);
    float w = L[wv][k][gg];
    float zh0 = (pp.x - pn4.x - mp4.x)*rp4.x*g4.x + b4.x;
    float zh1 = (pp.y - pn4.y - mp4.y)*rp4.y*g4.y + b4.y;
    float zh2 = (pp.z - pn4.z - mp4.z)*rp4.z*g4.z + b4.z;
    float zh3 = (pp.w - pn4.w - mp4.w)*rp4.w*g4.w + b4.w;
    accv[0] = fmaf(vv.x + leakyf(zh0), w, accv[0]);
    accv[1] = fmaf(vv.y + leakyf(zh1), w, accv[1]);
    accv[2] = fmaf(vv.z + leakyf(zh2), w, accv[2]);
    accv[3] = fmaf(vv.w + leakyf(zh3), w, accv[3]);
  }
  float4 x4 = *(const float4*)(xin + (long)bn*256 + c4);
  float4 o;
  o.x = x4.x + accv[0]; o.y = x4.y + accv[1];
  o.z = x4.z + accv[2]; o.w = x4.w + accv[3];
  *(float4*)(x2 + (long)bn*256 + c4) = o;
}

// ---------------- final: out = x2 + silu(bn(Zm2)), folded M2-finalize (8 rows/block) ----------------
__global__ __launch_bounds__(256) void k_final(const float* __restrict__ x2, const float* __restrict__ Zm2,
    const float* __restrict__ bM2buck, const float* __restrict__ gm, const float* __restrict__ bm,
    float* __restrict__ out){
  __shared__ float mrs[512];
  const int tid = threadIdx.x;
  {
    float s=0.f, q=0.f;
    for (int b=0;b<64;b++){ s += bM2buck[(long)b*512 + tid]; q += bM2buck[(long)b*512 + 256 + tid]; }
    float m = s*(1.f/4096.f);
    float v = fmaxf(q*(1.f/4096.f) - m*m, 0.f);
    mrs[tid] = m; mrs[256+tid] = rsqrtf(v + EPS);
  }
  __syncthreads();
  const float gmv = gm[tid], bmv = bm[tid];
  #pragma unroll
  for (int rr=0; rr<8; rr++){
    long r = (long)blockIdx.x*8 + rr;
    float z = Zm2[r*256 + tid];
    float y = (z - mrs[tid])*mrs[256+tid]*gmv + bmv;
    out[r*256 + tid] = x2[r*256 + tid] + siluf(y);
  }
}

extern "C" void kernel_launch(void* const* d_in, const int* in_sizes, int n_in,
                              void* d_out, int out_size, void* d_ws, size_t ws_size,
                              hipStream_t stream){
  (void)in_sizes; (void)n_in; (void)out_size; (void)ws_size;
  const float* x   = (const float*)d_in[0];
  const float* pos = (const float*)d_in[1];
  const float* Wq  = (const float*)d_in[2];
  const float* gq  = (const float*)d_in[3];
  const float* bq  = (const float*)d_in[4];
  const float* Wk  = (const float*)d_in[5];
  const float* gk  = (const float*)d_in[6];
  const float* bk  = (const float*)d_in[7];
  const float* Wv  = (const float*)d_in[8];
  const float* gv  = (const float*)d_in[9];
  const float* bv  = (const float*)d_in[10];
  const float* Wpb = (const float*)d_in[11];
  const float* gpb = (const float*)d_in[12];
  const float* bpb = (const float*)d_in[13];
  const float* We1 = (const float*)d_in[14];
  const float* ge1 = (const float*)d_in[15];
  const float* be1 = (const float*)d_in[16];
  const float* We2 = (const float*)d_in[17];
  const float* ge2 = (const float*)d_in[18];
  const float* be2 = (const float*)d_in[19];
  const float* Wm1 = (const float*)d_in[20];
  const float* gm1 = (const float*)d_in[21];
  const float* bm1 = (const float*)d_in[22];
  const float* Wm2 = (const float*)d_in[23];
  const float* gm2 = (const float*)d_in[24];
  const float* bm2 = (const float*)d_in[25];

  float* w     = (float*)d_ws;
  float* arena = w;                       // 4,194,304: rawQKV / E1->E2 / Zm1+Zm2
  float* key   = w + 4194304;             // 1,048,576
  float* P     = w + 5242880;             // 1,048,576
  float* x2    = w + 6291456;             // 1,048,576
  float* qv    = w + 7340032;             // 2,097,152
  float* sq    = w + 9437184;             // 4,096
  int*   idx   = (int*)(w + 9441280);     // 131,072 ints
  float* buck  = w + 9572352;             // 237,568
  float* mr    = w + 9809920;             // 3,712
  float* G2    = w + 9813632;             // 2 x 4,194,304 (both batch Grams)
  float* bQKV = buck;            float* bPB = buck + 98304;  float* bE1 = buck + 131072;
  float* bE2  = buck + 135168;   float* bM1 = buck + 139264; float* bM2 = buck + 204800;
  float* mrPB = mr + 1536;
  float* Zm1 = arena;
  float* Zm2 = arena + 2097152;

  k_zero<<<928,256,0,stream>>>(buck, 237568);
  // qkv (z=0..2, stats) + P (z=3) in one launch — FULL4: upstream of top-k
  k_gemm<false,true,true><<<dim3(64,4,4),256,0,stream>>>(
      x,256,0, pos,256, nullptr,0.f,0, nullptr,nullptr,
      Wq,Wk,Wv,Wpb,256,0, arena,768,256, P,256, 256, bQKV,768,256);
  k_apply_qkv<<<512,256,0,stream>>>(arena, bQKV, gq,bq,gk,bk,gv,bv, key, qv, sq);
  // both batch Grams in one launch — FULL4: the kNN distances themselves
  k_gemm<false,false,true><<<dim3(32,32,2),256,0,stream>>>(
      key,256,524288, nullptr,0, nullptr,0.f,0, nullptr,nullptr,
      key,key,key,nullptr,256,524288, G2,2048,4194304, nullptr,0, 256, nullptr,0,0);
  // topk over both batches + fused z_pb stats
  k_topk<<<1024,256,0,stream>>>(G2, sq, idx, P, bPB);
  k_finalize<<<1,256,0,stream>>>(bPB, 256, 1.f/131072.f, mrPB);
  k_e1m<<<2048,256,0,stream>>>(key, qv, P, idx, mrPB, gpb, bpb, We1, arena, bE1);
  k_e2m<<<512,256,0,stream>>>(arena, bE1, ge1, be1, We2, bE2);
  k_attn<<<1024,256,0,stream>>>(arena, bE2, ge2, be2, qv, P, idx, mrPB, gpb, bpb, x, x2);
  k_gemm<false,true,false><<<dim3(64,8,1),256,0,stream>>>(
      x2,256,0, nullptr,0, nullptr,0.f,0, nullptr,nullptr,
      Wm1,Wm1,Wm1,nullptr,256,0, Zm1,512,0, nullptr,0, 256, bM1,512,0);
  k_gemm<true,true,false><<<dim3(64,4,1),256,0,stream>>>(
      Zm1,512,0, nullptr,0, bM1,1.f/4096.f,512, gm1,bm1,
      Wm2,Wm2,Wm2,nullptr,512,0, Zm2,256,0, nullptr,0, 512, bM2,256,0);
  k_final<<<512,256,0,stream>>>(x2, Zm2, bM2, gm2, bm2, (float*)d_out);
}